// Round 1
// baseline (483.230 us; speedup 1.0000x reference)
//
#include <hip/hip_runtime.h>
#include <cmath>

#define B_ 8
#define C_ 256
#define N_ 4096
#define EPS_ 1e-8f

// ---------------- K1: column sum-of-squares -> normalization factors ----------------
// fq[b,n] = m ? 1/(||x[:,n]||+eps) : 0   (q_hat = x * fq)
// fs[b,n] = m ? 0 : 1/(||x[:,n]||+eps)   (s_hat = x * fs)
__global__ __launch_bounds__(256) void k_norms(const float* __restrict__ x, const float* __restrict__ mask,
                                               float* __restrict__ fq, float* __restrict__ fs) {
  int b = blockIdx.x >> 6;
  int n0 = (blockIdx.x & 63) << 6;
  int ln = threadIdx.x & 63, cg = threadIdx.x >> 6;
  int n = n0 + ln;
  const float* xp = x + ((size_t)(b * C_ + cg * 64) << 12) + n;
  float ss = 0.f;
#pragma unroll 8
  for (int c = 0; c < 64; ++c) { float v = xp[(size_t)c << 12]; ss += v * v; }
  __shared__ float red[4][64];
  red[cg][ln] = ss;
  __syncthreads();
  if (cg == 0) {
    float s = red[0][ln] + red[1][ln] + red[2][ln] + red[3][ln];
    float inv = 1.f / (sqrtf(s) + EPS_);
    float m = mask[(b << 12) + n];
    fq[(b << 12) + n] = m * inv;
    fs[(b << 12) + n] = (1.f - m) * inv;
  }
}

// ---------------- K2: fore_wv[b,0] = max_n sim[b,n,0]; valid[b]; need[b] ----------------
__global__ __launch_bounds__(256) void k_valid(const float* __restrict__ x, const float* __restrict__ mask,
                                               const float* __restrict__ fq, const float* __restrict__ fs,
                                               float* __restrict__ valid, int* __restrict__ need) {
  int b = blockIdx.x;
  int tid = threadIdx.x;
  __shared__ float s0[C_];
  float fs0 = fs[b << 12];
  s0[tid] = x[((size_t)(b * C_ + tid)) << 12] * fs0;  // x[b,c,0]*fs0
  __syncthreads();
  float best = -INFINITY;
  for (int n = tid; n < N_; n += 256) {
    const float* xp = x + ((size_t)b * C_ << 12) + n;
    float acc = 0.f;
#pragma unroll 4
    for (int c = 0; c < C_; ++c) acc += xp[(size_t)c << 12] * s0[c];
    acc *= fq[(b << 12) + n];  // zero rows -> exactly 0
    best = fmaxf(best, acc);
  }
  __shared__ float red[256];
  red[tid] = best;
  __syncthreads();
  for (int s = 128; s; s >>= 1) { if (tid < s) red[tid] = fmaxf(red[tid], red[tid + s]); __syncthreads(); }
  if (tid == 0) {
    float fore = red[0];
    float v = (fore > 0.5f) ? mask[b << 12] : 0.f;  // * fm[b,0] (mask is exactly 0/1)
    valid[b] = v;
    need[b] = (v != 0.f || b == B_ - 1) ? 1 : 0;
  }
}

// ---------------- K3: sim row max/argmax, partial over m-chunks (data-dependent skip) ----------------
__global__ __launch_bounds__(256) void k_sim(const float* __restrict__ x, const float* __restrict__ fq,
                                             const float* __restrict__ fs, const int* __restrict__ need,
                                             float* __restrict__ partV, int* __restrict__ partI) {
  int b = blockIdx.z;
  if (!need[b]) return;
  int mc = blockIdx.x;           // 8 chunks of 512 m
  int n0 = blockIdx.y << 6;      // 64 rows
  int tid = threadIdx.x;
  int tx = tid & 15, ty = tid >> 4;
  int lk = ty;                   // load row 0..15
  int ln4 = tx << 2;             // load col 0..60

  __shared__ float As[16][68];
  __shared__ float Bs[16][68];
  __shared__ float fqs[64], fss[64];
  __shared__ float rv[64][17];
  __shared__ int ri[64][17];

  if (tid < 64) fqs[tid] = fq[(b << 12) + n0 + tid];

  float bestv[4]; int besti[4];
#pragma unroll
  for (int i = 0; i < 4; ++i) { bestv[i] = -INFINITY; besti[i] = 0; }

  const size_t xb = ((size_t)b * C_) << 12;

  for (int ms = 0; ms < 8; ++ms) {
    int m0 = (mc << 9) + (ms << 6);
    if (tid < 64) fss[tid] = fs[(b << 12) + m0 + tid];
    float cacc[4][4];
#pragma unroll
    for (int i = 0; i < 4; ++i)
#pragma unroll
      for (int j = 0; j < 4; ++j) cacc[i][j] = 0.f;
    __syncthreads();
    for (int kt = 0; kt < C_; kt += 16) {
      float4 va = *reinterpret_cast<const float4*>(x + xb + ((size_t)(kt + lk) << 12) + n0 + ln4);
      float4 vb = *reinterpret_cast<const float4*>(x + xb + ((size_t)(kt + lk) << 12) + m0 + ln4);
      va.x *= fqs[ln4]; va.y *= fqs[ln4 + 1]; va.z *= fqs[ln4 + 2]; va.w *= fqs[ln4 + 3];
      vb.x *= fss[ln4]; vb.y *= fss[ln4 + 1]; vb.z *= fss[ln4 + 2]; vb.w *= fss[ln4 + 3];
      *reinterpret_cast<float4*>(&As[lk][ln4]) = va;
      *reinterpret_cast<float4*>(&Bs[lk][ln4]) = vb;
      __syncthreads();
#pragma unroll
      for (int k = 0; k < 16; ++k) {
        float a0 = As[k][(ty << 2) + 0], a1 = As[k][(ty << 2) + 1], a2 = As[k][(ty << 2) + 2], a3 = As[k][(ty << 2) + 3];
        float b0 = Bs[k][(tx << 2) + 0], b1 = Bs[k][(tx << 2) + 1], b2 = Bs[k][(tx << 2) + 2], b3 = Bs[k][(tx << 2) + 3];
        cacc[0][0] += a0 * b0; cacc[0][1] += a0 * b1; cacc[0][2] += a0 * b2; cacc[0][3] += a0 * b3;
        cacc[1][0] += a1 * b0; cacc[1][1] += a1 * b1; cacc[1][2] += a1 * b2; cacc[1][3] += a1 * b3;
        cacc[2][0] += a2 * b0; cacc[2][1] += a2 * b1; cacc[2][2] += a2 * b2; cacc[2][3] += a2 * b3;
        cacc[3][0] += a3 * b0; cacc[3][1] += a3 * b1; cacc[3][2] += a3 * b2; cacc[3][3] += a3 * b3;
      }
      __syncthreads();
    }
    // update running best (columns strictly ascending per thread; tie -> smaller index)
#pragma unroll
    for (int j = 0; j < 4; ++j) {
      int col = m0 + (tx << 2) + j;
#pragma unroll
      for (int i = 0; i < 4; ++i) {
        float v = cacc[i][j];
        if (v > bestv[i] || (v == bestv[i] && col < besti[i])) { bestv[i] = v; besti[i] = col; }
      }
    }
  }
#pragma unroll
  for (int i = 0; i < 4; ++i) { rv[(ty << 2) + i][tx] = bestv[i]; ri[(ty << 2) + i][tx] = besti[i]; }
  __syncthreads();
  if (tid < 64) {
    float bv = rv[tid][0]; int bi = ri[tid][0];
#pragma unroll
    for (int t = 1; t < 16; ++t) {
      float v = rv[tid][t]; int ii = ri[tid][t];
      if (v > bv || (v == bv && ii < bi)) { bv = v; bi = ii; }
    }
    size_t po = (((size_t)((b << 6) + blockIdx.y)) << 9) + ((size_t)mc << 6) + tid;
    partV[po] = bv; partI[po] = bi;
  }
}

// ---------------- K3b: reduce partials over m-chunks ----------------
__global__ __launch_bounds__(256) void k_red(const float* __restrict__ partV, const int* __restrict__ partI,
                                             const int* __restrict__ need, float* __restrict__ wv,
                                             int* __restrict__ idxv) {
  int bn = blockIdx.x * 256 + threadIdx.x;  // B*N
  int b = bn >> 12;
  if (!need[b]) return;
  int n = bn & 4095; int nt = n >> 6, r = n & 63;
  float bv = -INFINITY; int bi = 0;
  for (int mcn = 0; mcn < 8; ++mcn) {
    size_t po = (((size_t)((b << 6) + nt)) << 9) + ((size_t)mcn << 6) + r;
    float v = partV[po]; int ii = partI[po];
    if (v > bv || (v == bv && ii < bi)) { bv = v; bi = ii; }
  }
  wv[bn] = bv; idxv[bn] = bi;
}

// ---------------- K4: softmax scalars per valid batch ----------------
__global__ __launch_bounds__(256) void k_soft(const float* __restrict__ wv, const float* __restrict__ valid,
                                              float* __restrict__ smx, float* __restrict__ sden) {
  int b = blockIdx.x;
  if (valid[b] == 0.f) return;
  int tid = threadIdx.x;
  __shared__ float red[256];
  float mx = -INFINITY;
  for (int n = tid; n < N_; n += 256) mx = fmaxf(mx, wv[(b << 12) + n]);
  red[tid] = mx; __syncthreads();
  for (int s = 128; s; s >>= 1) { if (tid < s) red[tid] = fmaxf(red[tid], red[tid + s]); __syncthreads(); }
  mx = red[0]; __syncthreads();
  float sm = 0.f;
  for (int n = tid; n < N_; n += 256) sm += expf(wv[(b << 12) + n] - mx);
  red[tid] = sm; __syncthreads();
  for (int s = 128; s; s >>= 1) { if (tid < s) red[tid] += red[tid + s]; __syncthreads(); }
  if (tid == 0) { smx[b] = mx; sden[b] = red[0]; }
}

// ---------------- K5: base output (valid==0 path, always correct base) ----------------
// out[b,c,n] = m ? x*fq : x
__global__ __launch_bounds__(256) void k_out(const float* __restrict__ x, const float* __restrict__ mask,
                                             const float* __restrict__ fq, float* __restrict__ out) {
  int id = blockIdx.x * 256 + threadIdx.x;  // B*N*4
  int n = id & 4095; int cg = (id >> 12) & 3; int b = id >> 14;
  float f = fq[(b << 12) + n];
  float mn = mask[(b << 12) + n];
  float scale = (mn != 0.f) ? f : 1.f;
  const float* xp = x + ((size_t)(b * C_ + cg * 64) << 12) + n;
  float* op = out + ((size_t)(b * C_ + cg * 64) << 12) + n;
#pragma unroll 4
  for (int c = 0; c < 64; ++c) op[(size_t)c << 12] = xp[(size_t)c << 12] * scale;
}

// ---------------- K5b: 1x1-conv hybrid overwrite for valid batches (gated, rare) ----------------
__global__ __launch_bounds__(256) void k_hybrid(const float* __restrict__ x, const float* __restrict__ mask,
                                                const float* __restrict__ fq, const float* __restrict__ fs,
                                                const float* __restrict__ Wc, const float* __restrict__ bc,
                                                const int* __restrict__ idxv, const float* __restrict__ wv,
                                                const float* __restrict__ smx, const float* __restrict__ sden,
                                                const float* __restrict__ valid, float* __restrict__ out) {
  int b = blockIdx.z;
  if (valid[b] == 0.f) return;
  int n = blockIdx.x * 256 + threadIdx.x;
  int o0 = blockIdx.y * 16;
  int bn = (b << 12) + n;
  float mn = mask[bn];
  if (mn == 0.f) return;  // unmasked positions keep out = x
  int j = idxv[bn];
  float w = expf(wv[bn] - smx[b]) / sden[b];
  float fsj = fs[(b << 12) + j];
  float fqn = fq[bn];
  const float* xb = x + (((size_t)b * C_) << 12);
  for (int oo = 0; oo < 16; ++oo) {
    int o = o0 + oo;
    const float* wr = Wc + o * 2 * C_;
    float a1 = 0.f, a2 = 0.f;
    for (int i = 0; i < C_; ++i) {
      a1 += wr[i] * xb[((size_t)i << 12) + j];
      a2 += wr[C_ + i] * xb[((size_t)i << 12) + n];
    }
    out[((size_t)(b * C_ + o) << 12) + n] = bc[o] + a1 * (fsj * w) + a2 * fqn;
  }
}

// ---------------- K6a: mark set of idx[B-1,:] ----------------
__global__ __launch_bounds__(256) void k_mark(const int* __restrict__ idxv, int* __restrict__ mark) {
  int t = threadIdx.x;
  for (int i = t; i < N_; i += 256) mark[i] = 0;
  __syncthreads();
  for (int i = t; i < N_; i += 256) mark[idxv[((B_ - 1) << 12) + i]] = 1;
}

// ---------------- K6b: attmap nearest x8 upsample ----------------
__global__ __launch_bounds__(256) void k_att(const int* __restrict__ mark, float* __restrict__ att) {
  int id = blockIdx.x * 256 + threadIdx.x;  // 524288 float4 groups
  int x4 = (id & 127) << 2;
  int y = (id >> 7) & 511;
  int b = id >> 16;
  float v = mark[((y >> 3) << 6) + (x4 >> 3)] ? 1.f : 0.f;
  float4 vv = make_float4(v, v, v, v);
  *reinterpret_cast<float4*>(att + (((size_t)b) << 18) + (y << 9) + x4) = vv;
}

extern "C" void kernel_launch(void* const* d_in, const int* in_sizes, int n_in,
                              void* d_out, int out_size, void* d_ws, size_t ws_size,
                              hipStream_t stream) {
  const float* x = (const float*)d_in[0];
  const float* mask = (const float*)d_in[1];
  const float* Wc = (const float*)d_in[2];
  const float* bc = (const float*)d_in[3];
  float* out = (float*)d_out;
  float* att = out + (size_t)B_ * C_ * N_;

  float* wsf = (float*)d_ws;
  float* fq = wsf;                        // 32768
  float* fs = wsf + 32768;                // 32768
  float* wv = wsf + 65536;                // 32768
  int* idxv = (int*)(wsf + 98304);        // 32768
  float* partV = wsf + 131072;            // 262144
  int* partI = (int*)(wsf + 393216);      // 262144
  float* valid = wsf + 655360;            // 8
  int* need = (int*)(wsf + 655368);       // 8
  float* smx = wsf + 655376;              // 8
  float* sden = wsf + 655384;             // 8
  int* mark = (int*)(wsf + 655392);       // 4096

  k_norms<<<512, 256, 0, stream>>>(x, mask, fq, fs);
  k_valid<<<B_, 256, 0, stream>>>(x, mask, fq, fs, valid, need);
  k_sim<<<dim3(8, 64, B_), 256, 0, stream>>>(x, fq, fs, need, partV, partI);
  k_red<<<128, 256, 0, stream>>>(partV, partI, need, wv, idxv);
  k_soft<<<B_, 256, 0, stream>>>(wv, valid, smx, sden);
  k_out<<<512, 256, 0, stream>>>(x, mask, fq, out);
  k_hybrid<<<dim3(16, 16, B_), 256, 0, stream>>>(x, mask, fq, fs, Wc, bc, idxv, wv, smx, sden, valid, out);
  k_mark<<<1, 256, 0, stream>>>(idxv, mark);
  k_att<<<2048, 256, 0, stream>>>(mark, att);
}

// Round 2
// 187.245 us; speedup vs baseline: 2.5807x; 2.5807x over previous
//
#include <hip/hip_runtime.h>
#include <cmath>

#define B_ 8
#define C_ 256
#define N_ 4096
#define EPS_ 1e-8f

// ---------------- K1: column sum-of-squares -> normalization factors ----------------
__global__ __launch_bounds__(256) void k_norms(const float* __restrict__ x, const float* __restrict__ mask,
                                               float* __restrict__ fq, float* __restrict__ fs) {
  int b = blockIdx.x >> 6;
  int n0 = (blockIdx.x & 63) << 6;
  int ln = threadIdx.x & 63, cg = threadIdx.x >> 6;
  int n = n0 + ln;
  const float* xp = x + ((size_t)(b * C_ + cg * 64) << 12) + n;
  float ss = 0.f;
#pragma unroll 8
  for (int c = 0; c < 64; ++c) { float v = xp[(size_t)c << 12]; ss += v * v; }
  __shared__ float red[4][64];
  red[cg][ln] = ss;
  __syncthreads();
  if (cg == 0) {
    float s = red[0][ln] + red[1][ln] + red[2][ln] + red[3][ln];
    float inv = 1.f / (sqrtf(s) + EPS_);
    float m = mask[(b << 12) + n];
    fq[(b << 12) + n] = m * inv;
    fs[(b << 12) + n] = (1.f - m) * inv;
  }
}

// ---------------- K2a: parallel partial max of sim[b,n,0] over n-chunks ----------------
__global__ __launch_bounds__(256) void k_valid_part(const float* __restrict__ x, const float* __restrict__ fq,
                                                    const float* __restrict__ fs, float* __restrict__ partMax) {
  int b = blockIdx.y;
  int tid = threadIdx.x;
  int n = blockIdx.x * 256 + tid;
  __shared__ float s0[C_];
  float fs0 = fs[b << 12];
  s0[tid] = x[((size_t)(b * C_ + tid)) << 12] * fs0;  // x[b,c,0]*fs0
  __syncthreads();
  const float* xp = x + ((size_t)b * C_ << 12) + n;
  float acc = 0.f;
#pragma unroll 8
  for (int c = 0; c < C_; ++c) acc += xp[(size_t)c << 12] * s0[c];
  acc *= fq[(b << 12) + n];  // masked-out rows -> exactly 0
  __shared__ float red[256];
  red[tid] = acc;
  __syncthreads();
  for (int s = 128; s; s >>= 1) { if (tid < s) red[tid] = fmaxf(red[tid], red[tid + s]); __syncthreads(); }
  if (tid == 0) partMax[b * 16 + blockIdx.x] = red[0];
}

// ---------------- K2b: finish valid/need ----------------
__global__ __launch_bounds__(128) void k_valid_fin(const float* __restrict__ partMax, const float* __restrict__ mask,
                                                   float* __restrict__ valid, int* __restrict__ need) {
  int tid = threadIdx.x;  // 128 = 8 batches x 16 parts
  int b = tid >> 4, i = tid & 15;
  __shared__ float red[128];
  red[tid] = partMax[tid];
  __syncthreads();
  for (int s = 8; s; s >>= 1) { if (i < s) red[tid] = fmaxf(red[tid], red[tid + s]); __syncthreads(); }
  if (i == 0) {
    float fore = red[tid];
    float v = (fore > 0.5f) ? mask[b << 12] : 0.f;  // * fm[b,0] (mask is exactly 0/1)
    valid[b] = v;
    need[b] = (v != 0.f || b == B_ - 1) ? 1 : 0;
  }
}

// ---------------- K3: sim row max/argmax, partial over m-chunks (data-dependent skip) ----------------
__global__ __launch_bounds__(256) void k_sim(const float* __restrict__ x, const float* __restrict__ fq,
                                             const float* __restrict__ fs, const int* __restrict__ need,
                                             float* __restrict__ partV, int* __restrict__ partI) {
  int b = blockIdx.z;
  if (!need[b]) return;
  int mc = blockIdx.x;           // 8 chunks of 512 m
  int n0 = blockIdx.y << 6;      // 64 rows
  int tid = threadIdx.x;
  int tx = tid & 15, ty = tid >> 4;
  int lk = ty;                   // load row 0..15
  int ln4 = tx << 2;             // load col 0..60

  __shared__ float As[16][68];
  __shared__ float Bs[16][68];
  __shared__ float fqs[64], fss[64];
  __shared__ float rv[64][17];
  __shared__ int ri[64][17];

  if (tid < 64) fqs[tid] = fq[(b << 12) + n0 + tid];

  float bestv[4]; int besti[4];
#pragma unroll
  for (int i = 0; i < 4; ++i) { bestv[i] = -INFINITY; besti[i] = 0; }

  const size_t xb = ((size_t)b * C_) << 12;

  for (int ms = 0; ms < 8; ++ms) {
    int m0 = (mc << 9) + (ms << 6);
    if (tid < 64) fss[tid] = fs[(b << 12) + m0 + tid];
    float cacc[4][4];
#pragma unroll
    for (int i = 0; i < 4; ++i)
#pragma unroll
      for (int j = 0; j < 4; ++j) cacc[i][j] = 0.f;
    __syncthreads();
    for (int kt = 0; kt < C_; kt += 16) {
      float4 va = *reinterpret_cast<const float4*>(x + xb + ((size_t)(kt + lk) << 12) + n0 + ln4);
      float4 vb = *reinterpret_cast<const float4*>(x + xb + ((size_t)(kt + lk) << 12) + m0 + ln4);
      va.x *= fqs[ln4]; va.y *= fqs[ln4 + 1]; va.z *= fqs[ln4 + 2]; va.w *= fqs[ln4 + 3];
      vb.x *= fss[ln4]; vb.y *= fss[ln4 + 1]; vb.z *= fss[ln4 + 2]; vb.w *= fss[ln4 + 3];
      *reinterpret_cast<float4*>(&As[lk][ln4]) = va;
      *reinterpret_cast<float4*>(&Bs[lk][ln4]) = vb;
      __syncthreads();
#pragma unroll
      for (int k = 0; k < 16; ++k) {
        float a0 = As[k][(ty << 2) + 0], a1 = As[k][(ty << 2) + 1], a2 = As[k][(ty << 2) + 2], a3 = As[k][(ty << 2) + 3];
        float b0 = Bs[k][(tx << 2) + 0], b1 = Bs[k][(tx << 2) + 1], b2 = Bs[k][(tx << 2) + 2], b3 = Bs[k][(tx << 2) + 3];
        cacc[0][0] += a0 * b0; cacc[0][1] += a0 * b1; cacc[0][2] += a0 * b2; cacc[0][3] += a0 * b3;
        cacc[1][0] += a1 * b0; cacc[1][1] += a1 * b1; cacc[1][2] += a1 * b2; cacc[1][3] += a1 * b3;
        cacc[2][0] += a2 * b0; cacc[2][1] += a2 * b1; cacc[2][2] += a2 * b2; cacc[2][3] += a2 * b3;
        cacc[3][0] += a3 * b0; cacc[3][1] += a3 * b1; cacc[3][2] += a3 * b2; cacc[3][3] += a3 * b3;
      }
      __syncthreads();
    }
#pragma unroll
    for (int j = 0; j < 4; ++j) {
      int col = m0 + (tx << 2) + j;
#pragma unroll
      for (int i = 0; i < 4; ++i) {
        float v = cacc[i][j];
        if (v > bestv[i] || (v == bestv[i] && col < besti[i])) { bestv[i] = v; besti[i] = col; }
      }
    }
  }
#pragma unroll
  for (int i = 0; i < 4; ++i) { rv[(ty << 2) + i][tx] = bestv[i]; ri[(ty << 2) + i][tx] = besti[i]; }
  __syncthreads();
  if (tid < 64) {
    float bv = rv[tid][0]; int bi = ri[tid][0];
#pragma unroll
    for (int t = 1; t < 16; ++t) {
      float v = rv[tid][t]; int ii = ri[tid][t];
      if (v > bv || (v == bv && ii < bi)) { bv = v; bi = ii; }
    }
    size_t po = (((size_t)((b << 6) + blockIdx.y)) << 9) + ((size_t)mc << 6) + tid;
    partV[po] = bv; partI[po] = bi;
  }
}

// ---------------- K3b: reduce partials over m-chunks ----------------
__global__ __launch_bounds__(256) void k_red(const float* __restrict__ partV, const int* __restrict__ partI,
                                             const int* __restrict__ need, float* __restrict__ wv,
                                             int* __restrict__ idxv) {
  int bn = blockIdx.x * 256 + threadIdx.x;  // B*N
  int b = bn >> 12;
  if (!need[b]) return;
  int n = bn & 4095; int nt = n >> 6, r = n & 63;
  float bv = -INFINITY; int bi = 0;
  for (int mcn = 0; mcn < 8; ++mcn) {
    size_t po = (((size_t)((b << 6) + nt)) << 9) + ((size_t)mcn << 6) + r;
    float v = partV[po]; int ii = partI[po];
    if (v > bv || (v == bv && ii < bi)) { bv = v; bi = ii; }
  }
  wv[bn] = bv; idxv[bn] = bi;
}

// ---------------- K4: softmax scalars per valid batch ----------------
__global__ __launch_bounds__(256) void k_soft(const float* __restrict__ wv, const float* __restrict__ valid,
                                              float* __restrict__ smx, float* __restrict__ sden) {
  int b = blockIdx.x;
  if (valid[b] == 0.f) return;
  int tid = threadIdx.x;
  __shared__ float red[256];
  float mx = -INFINITY;
  for (int n = tid; n < N_; n += 256) mx = fmaxf(mx, wv[(b << 12) + n]);
  red[tid] = mx; __syncthreads();
  for (int s = 128; s; s >>= 1) { if (tid < s) red[tid] = fmaxf(red[tid], red[tid + s]); __syncthreads(); }
  mx = red[0]; __syncthreads();
  float sm = 0.f;
  for (int n = tid; n < N_; n += 256) sm += expf(wv[(b << 12) + n] - mx);
  red[tid] = sm; __syncthreads();
  for (int s = 128; s; s >>= 1) { if (tid < s) red[tid] += red[tid + s]; __syncthreads(); }
  if (tid == 0) { smx[b] = mx; sden[b] = red[0]; }
}

// ---------------- K5: base output ----------------
__global__ __launch_bounds__(256) void k_out(const float* __restrict__ x, const float* __restrict__ mask,
                                             const float* __restrict__ fq, float* __restrict__ out) {
  int id = blockIdx.x * 256 + threadIdx.x;  // B*N*4
  int n = id & 4095; int cg = (id >> 12) & 3; int b = id >> 14;
  float f = fq[(b << 12) + n];
  float mn = mask[(b << 12) + n];
  float scale = (mn != 0.f) ? f : 1.f;
  const float* xp = x + ((size_t)(b * C_ + cg * 64) << 12) + n;
  float* op = out + ((size_t)(b * C_ + cg * 64) << 12) + n;
#pragma unroll 4
  for (int c = 0; c < 64; ++c) op[(size_t)c << 12] = xp[(size_t)c << 12] * scale;
}

// ---------------- K5b: 1x1-conv hybrid overwrite for valid batches (gated, rare) ----------------
__global__ __launch_bounds__(256) void k_hybrid(const float* __restrict__ x, const float* __restrict__ mask,
                                                const float* __restrict__ fq, const float* __restrict__ fs,
                                                const float* __restrict__ Wc, const float* __restrict__ bc,
                                                const int* __restrict__ idxv, const float* __restrict__ wv,
                                                const float* __restrict__ smx, const float* __restrict__ sden,
                                                const float* __restrict__ valid, float* __restrict__ out) {
  int b = blockIdx.z;
  if (valid[b] == 0.f) return;
  int n = blockIdx.x * 256 + threadIdx.x;
  int o0 = blockIdx.y * 16;
  int bn = (b << 12) + n;
  float mn = mask[bn];
  if (mn == 0.f) return;  // unmasked positions keep out = x
  int j = idxv[bn];
  float w = expf(wv[bn] - smx[b]) / sden[b];
  float fsj = fs[(b << 12) + j];
  float fqn = fq[bn];
  const float* xb = x + (((size_t)b * C_) << 12);
  for (int oo = 0; oo < 16; ++oo) {
    int o = o0 + oo;
    const float* wr = Wc + o * 2 * C_;
    float a1 = 0.f, a2 = 0.f;
    for (int i = 0; i < C_; ++i) {
      a1 += wr[i] * xb[((size_t)i << 12) + j];
      a2 += wr[C_ + i] * xb[((size_t)i << 12) + n];
    }
    out[((size_t)(b * C_ + o) << 12) + n] = bc[o] + a1 * (fsj * w) + a2 * fqn;
  }
}

// ---------------- K6a: mark set of idx[B-1,:] ----------------
__global__ __launch_bounds__(256) void k_mark(const int* __restrict__ idxv, int* __restrict__ mark) {
  int t = threadIdx.x;
  for (int i = t; i < N_; i += 256) mark[i] = 0;
  __syncthreads();
  for (int i = t; i < N_; i += 256) mark[idxv[((B_ - 1) << 12) + i]] = 1;
}

// ---------------- K6b: attmap nearest x8 upsample ----------------
__global__ __launch_bounds__(256) void k_att(const int* __restrict__ mark, float* __restrict__ att) {
  int id = blockIdx.x * 256 + threadIdx.x;  // 524288 float4 groups
  int x4 = (id & 127) << 2;
  int y = (id >> 7) & 511;
  int b = id >> 16;
  float v = mark[((y >> 3) << 6) + (x4 >> 3)] ? 1.f : 0.f;
  float4 vv = make_float4(v, v, v, v);
  *reinterpret_cast<float4*>(att + (((size_t)b) << 18) + (y << 9) + x4) = vv;
}

extern "C" void kernel_launch(void* const* d_in, const int* in_sizes, int n_in,
                              void* d_out, int out_size, void* d_ws, size_t ws_size,
                              hipStream_t stream) {
  const float* x = (const float*)d_in[0];
  const float* mask = (const float*)d_in[1];
  const float* Wc = (const float*)d_in[2];
  const float* bc = (const float*)d_in[3];
  float* out = (float*)d_out;
  float* att = out + (size_t)B_ * C_ * N_;

  float* wsf = (float*)d_ws;
  float* fq = wsf;                        // 32768
  float* fs = wsf + 32768;                // 32768
  float* wv = wsf + 65536;                // 32768
  int* idxv = (int*)(wsf + 98304);        // 32768
  float* partV = wsf + 131072;            // 262144
  int* partI = (int*)(wsf + 393216);      // 262144
  float* valid = wsf + 655360;            // 8
  int* need = (int*)(wsf + 655368);       // 8
  float* smx = wsf + 655376;              // 8
  float* sden = wsf + 655384;             // 8
  int* mark = (int*)(wsf + 655392);       // 4096
  float* partMax = wsf + 659488;          // 128

  k_norms<<<512, 256, 0, stream>>>(x, mask, fq, fs);
  k_valid_part<<<dim3(16, B_), 256, 0, stream>>>(x, fq, fs, partMax);
  k_valid_fin<<<1, 128, 0, stream>>>(partMax, mask, valid, need);
  k_sim<<<dim3(8, 64, B_), 256, 0, stream>>>(x, fq, fs, need, partV, partI);
  k_red<<<128, 256, 0, stream>>>(partV, partI, need, wv, idxv);
  k_soft<<<B_, 256, 0, stream>>>(wv, valid, smx, sden);
  k_out<<<512, 256, 0, stream>>>(x, mask, fq, out);
  k_hybrid<<<dim3(16, 16, B_), 256, 0, stream>>>(x, mask, fq, fs, Wc, bc, idxv, wv, smx, sden, valid, out);
  k_mark<<<1, 256, 0, stream>>>(idxv, mark);
  k_att<<<2048, 256, 0, stream>>>(mark, att);
}

// Round 4
// 107.748 us; speedup vs baseline: 4.4848x; 1.7378x over previous
//
#include <hip/hip_runtime.h>
#include <cmath>

#define B_ 8
#define C_ 256
#define N_ 4096
#define EPS_ 1e-8f

typedef _Float16 half8 __attribute__((ext_vector_type(8)));
typedef float f32x4 __attribute__((ext_vector_type(4)));
typedef unsigned short ushort8 __attribute__((ext_vector_type(8)));

__device__ __forceinline__ void gload_lds16(const void* g, void* l) {
  __builtin_amdgcn_global_load_lds((const __attribute__((address_space(1))) unsigned int*)g,
                                   (__attribute__((address_space(3))) unsigned int*)l, 16, 0, 0);
}

// ---------------- K1: column sum-of-squares -> normalization factors ----------------
__global__ __launch_bounds__(256) void k_norms(const float* __restrict__ x, const float* __restrict__ mask,
                                               float* __restrict__ fq, float* __restrict__ fs) {
  int b = blockIdx.x >> 6;
  int n0 = (blockIdx.x & 63) << 6;
  int ln = threadIdx.x & 63, cg = threadIdx.x >> 6;
  int n = n0 + ln;
  const float* xp = x + ((size_t)(b * C_ + cg * 64) << 12) + n;
  float ss = 0.f;
#pragma unroll 8
  for (int c = 0; c < 64; ++c) { float v = xp[(size_t)c << 12]; ss += v * v; }
  __shared__ float red[4][64];
  red[cg][ln] = ss;
  __syncthreads();
  if (cg == 0) {
    float s = red[0][ln] + red[1][ln] + red[2][ln] + red[3][ln];
    float inv = 1.f / (sqrtf(s) + EPS_);
    float m = mask[(b << 12) + n];
    fq[(b << 12) + n] = m * inv;
    fs[(b << 12) + n] = (1.f - m) * inv;
  }
}

// ---------------- K2a: parallel partial max of sim[b,n,0] over n-chunks ----------------
__global__ __launch_bounds__(256) void k_valid_part(const float* __restrict__ x, const float* __restrict__ fq,
                                                    const float* __restrict__ fs, float* __restrict__ partMax) {
  int b = blockIdx.y;
  int tid = threadIdx.x;
  int n = blockIdx.x * 256 + tid;
  __shared__ float s0[C_];
  float fs0 = fs[b << 12];
  s0[tid] = x[((size_t)(b * C_ + tid)) << 12] * fs0;
  __syncthreads();
  const float* xp = x + ((size_t)b * C_ << 12) + n;
  float acc = 0.f;
#pragma unroll 8
  for (int c = 0; c < C_; ++c) acc += xp[(size_t)c << 12] * s0[c];
  acc *= fq[(b << 12) + n];
  __shared__ float red[256];
  red[tid] = acc;
  __syncthreads();
  for (int s = 128; s; s >>= 1) { if (tid < s) red[tid] = fmaxf(red[tid], red[tid + s]); __syncthreads(); }
  if (tid == 0) partMax[b * 16 + blockIdx.x] = red[0];
}

// ---------------- K2b: finish valid/need ----------------
__global__ __launch_bounds__(128) void k_valid_fin(const float* __restrict__ partMax, const float* __restrict__ mask,
                                                   float* __restrict__ valid, int* __restrict__ need) {
  int tid = threadIdx.x;
  int b = tid >> 4, i = tid & 15;
  __shared__ float red[128];
  red[tid] = partMax[tid];
  __syncthreads();
  for (int s = 8; s; s >>= 1) { if (i < s) red[tid] = fmaxf(red[tid], red[tid + s]); __syncthreads(); }
  if (i == 0) {
    float fore = red[tid];
    float v = (fore > 0.5f) ? mask[b << 12] : 0.f;
    valid[b] = v;
    need[b] = (v != 0.f || b == B_ - 1) ? 1 : 0;
  }
}

// ---------------- K_prep7: scaled (x64), transposed, fp16 hi/lo-split, pre-swizzled arrays for b=7 ----
// hi = fp16(64*q), lo = fp16((64*q - hi)*2048); sim = (hi.hi + cross/2048)/4096.
// Column chunk (8 halves = 16B) stored at chunk index ((c>>3)&3) ^ ((n>>1)&3) within each 64B segment.
__global__ __launch_bounds__(256) void k_prep7(const float* __restrict__ x, const float* __restrict__ fq,
                                               const float* __restrict__ fs,
                                               unsigned short* __restrict__ qhi, unsigned short* __restrict__ qlo,
                                               unsigned short* __restrict__ shi, unsigned short* __restrict__ slo) {
  int nb = blockIdx.x, cb = blockIdx.y;   // 64 n-tiles x 4 c-tiles
  int n0 = nb << 6, c0 = cb << 6;
  int t = threadIdx.x;
  __shared__ float xt[64][68];
  const float* xb = x + (((size_t)(7 * C_ + c0)) << 12) + n0;
  int cr = t >> 4, n4 = (t & 15) << 2;
#pragma unroll
  for (int p = 0; p < 4; ++p) {
    float4 v = *reinterpret_cast<const float4*>(xb + (((size_t)(p * 16 + cr)) << 12) + n4);
    *reinterpret_cast<float4*>(&xt[p * 16 + cr][n4]) = v;
  }
  __syncthreads();
  int nl = t >> 2;          // 0..63
  int cq = (t & 3) << 4;    // 0,16,32,48
  int n = n0 + nl;
  float fqn = fq[(7 << 12) + n] * 64.0f;
  float fsn = fs[(7 << 12) + n] * 64.0f;
  unsigned short oqh[16], oql[16], osh[16], osl[16];
#pragma unroll
  for (int i = 0; i < 16; ++i) {
    float xv = xt[cq + i][nl];
    float qv = xv * fqn;
    _Float16 qh = (_Float16)qv;
    _Float16 ql = (_Float16)((qv - (float)qh) * 2048.0f);
    float sv = xv * fsn;
    _Float16 sh = (_Float16)sv;
    _Float16 sl = (_Float16)((sv - (float)sh) * 2048.0f);
    oqh[i] = __builtin_bit_cast(unsigned short, qh);
    oql[i] = __builtin_bit_cast(unsigned short, ql);
    osh[i] = __builtin_bit_cast(unsigned short, sh);
    osl[i] = __builtin_bit_cast(unsigned short, sl);
  }
  int swz = (n >> 1) & 3;
  size_t rowbase = ((size_t)n) << 8;  // 256 shorts per row
#pragma unroll
  for (int j = 0; j < 2; ++j) {
    int c = c0 + cq + j * 8;
    size_t off = rowbase + (size_t)((c >> 5) << 5) + (size_t)((((c >> 3) & 3) ^ swz) << 3);
    *reinterpret_cast<ushort8*>(qhi + off) = *reinterpret_cast<const ushort8*>(&oqh[j * 8]);
    *reinterpret_cast<ushort8*>(qlo + off) = *reinterpret_cast<const ushort8*>(&oql[j * 8]);
    *reinterpret_cast<ushort8*>(shi + off) = *reinterpret_cast<const ushort8*>(&osh[j * 8]);
    *reinterpret_cast<ushort8*>(slo + off) = *reinterpret_cast<const ushort8*>(&osl[j * 8]);
  }
}

// ---------------- K_sim7: MFMA sim + row argmax for b=7 (128x128 tiles, fp16 split) ----------------
__global__ __launch_bounds__(256, 2) void k_sim7(const unsigned short* __restrict__ qhi, const unsigned short* __restrict__ qlo,
                                                 const unsigned short* __restrict__ shi, const unsigned short* __restrict__ slo,
                                                 float* __restrict__ partV, int* __restrict__ partI) {
  int mt = blockIdx.x, nt = blockIdx.y;
  int tid = threadIdx.x;
  int w = tid >> 6, lane = tid & 63;
  int wy = w >> 1, wx = w & 1;
  __shared__ __align__(16) unsigned short smem[16384];  // 32KB: Ahi|Alo|Bhi|Blo, 4096 shorts each

  f32x4 acc_h[4][4], acc_c[4][4];
#pragma unroll
  for (int i = 0; i < 4; ++i)
#pragma unroll
    for (int j = 0; j < 4; ++j) {
      acc_h[i][j] = (f32x4){0.f, 0.f, 0.f, 0.f};
      acc_c[i][j] = (f32x4){0.f, 0.f, 0.f, 0.f};
    }

  const unsigned short* gsrc = (w == 0) ? qhi : (w == 1) ? qlo : (w == 2) ? shi : slo;
  int n0 = ((w < 2) ? nt : mt) << 7;
  int lrow = lane >> 2, lch = lane & 3;
  int s = lane >> 4, c16 = lane & 15;

  for (int kt = 0; kt < 8; ++kt) {
    __syncthreads();
#pragma unroll
    for (int seg = 0; seg < 8; ++seg) {
      const unsigned short* g = gsrc + (((size_t)(n0 + (seg << 4) + lrow)) << 8) + (kt << 5) + (lch << 3);
      gload_lds16(g, &smem[(w << 12) + (seg << 9)]);
    }
    __syncthreads();
    half8 ah[4], al[4], bh[4], bl[4];
#pragma unroll
    for (int f = 0; f < 4; ++f) {
      int ra = (wy << 6) + (f << 4) + c16;
      int oa = ra * 32 + ((s ^ ((ra >> 1) & 3)) << 3);
      ah[f] = *reinterpret_cast<const half8*>(&smem[oa]);
      al[f] = *reinterpret_cast<const half8*>(&smem[4096 + oa]);
      int rb = (wx << 6) + (f << 4) + c16;
      int ob = rb * 32 + ((s ^ ((rb >> 1) & 3)) << 3);
      bh[f] = *reinterpret_cast<const half8*>(&smem[8192 + ob]);
      bl[f] = *reinterpret_cast<const half8*>(&smem[12288 + ob]);
    }
#pragma unroll
    for (int fi = 0; fi < 4; ++fi)
#pragma unroll
      for (int fj = 0; fj < 4; ++fj) {
        acc_h[fi][fj] = __builtin_amdgcn_mfma_f32_16x16x32_f16(ah[fi], bh[fj], acc_h[fi][fj], 0, 0, 0);
        acc_c[fi][fj] = __builtin_amdgcn_mfma_f32_16x16x32_f16(ah[fi], bl[fj], acc_c[fi][fj], 0, 0, 0);
        acc_c[fi][fj] = __builtin_amdgcn_mfma_f32_16x16x32_f16(al[fi], bh[fj], acc_c[fi][fj], 0, 0, 0);
      }
  }
  __syncthreads();
  // per-row argmax: C/D layout col=lane&15, row=(lane>>4)*4+reg
  float* redV = reinterpret_cast<float*>(smem);          // [128][2]
  int* redI = reinterpret_cast<int*>(smem + 512);        // [128][2]
  int g16 = lane >> 4;
#pragma unroll
  for (int fi = 0; fi < 4; ++fi)
#pragma unroll
    for (int r = 0; r < 4; ++r) {
      float bv = -INFINITY; int bi = 0x7fffffff;
#pragma unroll
      for (int fj = 0; fj < 4; ++fj) {
        float v = (acc_h[fi][fj][r] + acc_c[fi][fj][r] * (1.0f / 2048.0f)) * (1.0f / 4096.0f);
        int colg = (mt << 7) + (wx << 6) + (fj << 4) + c16;
        if (v > bv) { bv = v; bi = colg; }  // cols ascend with fj: strict > keeps first
      }
#pragma unroll
      for (int d = 1; d < 16; d <<= 1) {
        float ov = __shfl_xor(bv, d, 64);
        int oi = __shfl_xor(bi, d, 64);
        if (ov > bv || (ov == bv && oi < bi)) { bv = ov; bi = oi; }
      }
      if (c16 == 0) {
        int row = (wy << 6) + (fi << 4) + (g16 << 2) + r;
        redV[row * 2 + wx] = bv;
        redI[row * 2 + wx] = bi;
      }
    }
  __syncthreads();
  if (tid < 128) {
    float v0 = redV[tid * 2], v1 = redV[tid * 2 + 1];
    int i0 = redI[tid * 2], i1 = redI[tid * 2 + 1];
    if (v1 > v0 || (v1 == v0 && i1 < i0)) { v0 = v1; i0 = i1; }
    int n = (nt << 7) + tid;
    partV[(((size_t)n) << 5) + mt] = v0;
    partI[(((size_t)n) << 5) + mt] = i0;
  }
}

// ---------------- K_red7: reduce 32 m-tiles for b=7 ----------------
__global__ __launch_bounds__(256) void k_red7(const float* __restrict__ partV, const int* __restrict__ partI,
                                              float* __restrict__ wv, int* __restrict__ idxv) {
  int n = blockIdx.x * 256 + threadIdx.x;
  float bv = -INFINITY; int bi = 0x7fffffff;
#pragma unroll 8
  for (int mtv = 0; mtv < 32; ++mtv) {
    float v = partV[(((size_t)n) << 5) + mtv];
    int i = partI[(((size_t)n) << 5) + mtv];
    if (v > bv || (v == bv && i < bi)) { bv = v; bi = i; }
  }
  wv[(7 << 12) + n] = bv; idxv[(7 << 12) + n] = bi;
}

// ---------------- K3: legacy fp32 sim for b<7 (gated by need; ~never runs) ----------------
__global__ __launch_bounds__(256) void k_sim(const float* __restrict__ x, const float* __restrict__ fq,
                                             const float* __restrict__ fs, const int* __restrict__ need,
                                             float* __restrict__ partV, int* __restrict__ partI) {
  int b = blockIdx.z;
  if (!need[b]) return;
  int mc = blockIdx.x;
  int n0 = blockIdx.y << 6;
  int tid = threadIdx.x;
  int tx = tid & 15, ty = tid >> 4;
  int lk = ty, ln4 = tx << 2;

  __shared__ float As[16][68];
  __shared__ float Bs[16][68];
  __shared__ float fqs[64], fss[64];
  __shared__ float rv[64][17];
  __shared__ int ri[64][17];

  if (tid < 64) fqs[tid] = fq[(b << 12) + n0 + tid];

  float bestv[4]; int besti[4];
#pragma unroll
  for (int i = 0; i < 4; ++i) { bestv[i] = -INFINITY; besti[i] = 0; }

  const size_t xb = ((size_t)b * C_) << 12;

  for (int ms = 0; ms < 8; ++ms) {
    int m0 = (mc << 9) + (ms << 6);
    if (tid < 64) fss[tid] = fs[(b << 12) + m0 + tid];
    float cacc[4][4];
#pragma unroll
    for (int i = 0; i < 4; ++i)
#pragma unroll
      for (int j = 0; j < 4; ++j) cacc[i][j] = 0.f;
    __syncthreads();
    for (int kt = 0; kt < C_; kt += 16) {
      float4 va = *reinterpret_cast<const float4*>(x + xb + ((size_t)(kt + lk) << 12) + n0 + ln4);
      float4 vb = *reinterpret_cast<const float4*>(x + xb + ((size_t)(kt + lk) << 12) + m0 + ln4);
      va.x *= fqs[ln4]; va.y *= fqs[ln4 + 1]; va.z *= fqs[ln4 + 2]; va.w *= fqs[ln4 + 3];
      vb.x *= fss[ln4]; vb.y *= fss[ln4 + 1]; vb.z *= fss[ln4 + 2]; vb.w *= fss[ln4 + 3];
      *reinterpret_cast<float4*>(&As[lk][ln4]) = va;
      *reinterpret_cast<float4*>(&Bs[lk][ln4]) = vb;
      __syncthreads();
#pragma unroll
      for (int k = 0; k < 16; ++k) {
        float a0 = As[k][(ty << 2) + 0], a1 = As[k][(ty << 2) + 1], a2 = As[k][(ty << 2) + 2], a3 = As[k][(ty << 2) + 3];
        float b0 = Bs[k][(tx << 2) + 0], b1 = Bs[k][(tx << 2) + 1], b2 = Bs[k][(tx << 2) + 2], b3 = Bs[k][(tx << 2) + 3];
        cacc[0][0] += a0 * b0; cacc[0][1] += a0 * b1; cacc[0][2] += a0 * b2; cacc[0][3] += a0 * b3;
        cacc[1][0] += a1 * b0; cacc[1][1] += a1 * b1; cacc[1][2] += a1 * b2; cacc[1][3] += a1 * b3;
        cacc[2][0] += a2 * b0; cacc[2][1] += a2 * b1; cacc[2][2] += a2 * b2; cacc[2][3] += a2 * b3;
        cacc[3][0] += a3 * b0; cacc[3][1] += a3 * b1; cacc[3][2] += a3 * b2; cacc[3][3] += a3 * b3;
      }
      __syncthreads();
    }
#pragma unroll
    for (int j = 0; j < 4; ++j) {
      int col = m0 + (tx << 2) + j;
#pragma unroll
      for (int i = 0; i < 4; ++i) {
        float v = cacc[i][j];
        if (v > bestv[i] || (v == bestv[i] && col < besti[i])) { bestv[i] = v; besti[i] = col; }
      }
    }
  }
#pragma unroll
  for (int i = 0; i < 4; ++i) { rv[(ty << 2) + i][tx] = bestv[i]; ri[(ty << 2) + i][tx] = besti[i]; }
  __syncthreads();
  if (tid < 64) {
    float bv = rv[tid][0]; int bi = ri[tid][0];
#pragma unroll
    for (int t = 1; t < 16; ++t) {
      float v = rv[tid][t]; int ii = ri[tid][t];
      if (v > bv || (v == bv && ii < bi)) { bv = v; bi = ii; }
    }
    size_t po = (((size_t)((b << 6) + blockIdx.y)) << 9) + ((size_t)mc << 6) + tid;
    partV[po] = bv; partI[po] = bi;
  }
}

// ---------------- K3b: legacy reduce (b<7, gated) ----------------
__global__ __launch_bounds__(256) void k_red(const float* __restrict__ partV, const int* __restrict__ partI,
                                             const int* __restrict__ need, float* __restrict__ wv,
                                             int* __restrict__ idxv) {
  int bn = blockIdx.x * 256 + threadIdx.x;  // (B_-1)*N
  int b = bn >> 12;
  if (!need[b]) return;
  int n = bn & 4095; int nt = n >> 6, r = n & 63;
  float bv = -INFINITY; int bi = 0;
  for (int mcn = 0; mcn < 8; ++mcn) {
    size_t po = (((size_t)((b << 6) + nt)) << 9) + ((size_t)mcn << 6) + r;
    float v = partV[po]; int ii = partI[po];
    if (v > bv || (v == bv && ii < bi)) { bv = v; bi = ii; }
  }
  wv[bn] = bv; idxv[bn] = bi;
}

// ---------------- K4: softmax scalars per valid batch ----------------
__global__ __launch_bounds__(256) void k_soft(const float* __restrict__ wv, const float* __restrict__ valid,
                                              float* __restrict__ smx, float* __restrict__ sden) {
  int b = blockIdx.x;
  if (valid[b] == 0.f) return;
  int tid = threadIdx.x;
  __shared__ float red[256];
  float mx = -INFINITY;
  for (int n = tid; n < N_; n += 256) mx = fmaxf(mx, wv[(b << 12) + n]);
  red[tid] = mx; __syncthreads();
  for (int s = 128; s; s >>= 1) { if (tid < s) red[tid] = fmaxf(red[tid], red[tid + s]); __syncthreads(); }
  mx = red[0]; __syncthreads();
  float sm = 0.f;
  for (int n = tid; n < N_; n += 256) sm += expf(wv[(b << 12) + n] - mx);
  red[tid] = sm; __syncthreads();
  for (int s = 128; s; s >>= 1) { if (tid < s) red[tid] += red[tid + s]; __syncthreads(); }
  if (tid == 0) { smx[b] = mx; sden[b] = red[0]; }
}

// ---------------- K5: base output ----------------
__global__ __launch_bounds__(256) void k_out(const float* __restrict__ x, const float* __restrict__ mask,
                                             const float* __restrict__ fq, float* __restrict__ out) {
  int id = blockIdx.x * 256 + threadIdx.x;
  int n = id & 4095; int cg = (id >> 12) & 3; int b = id >> 14;
  float f = fq[(b << 12) + n];
  float mn = mask[(b << 12) + n];
  float scale = (mn != 0.f) ? f : 1.f;
  const float* xp = x + ((size_t)(b * C_ + cg * 64) << 12) + n;
  float* op = out + ((size_t)(b * C_ + cg * 64) << 12) + n;
#pragma unroll 4
  for (int c = 0; c < 64; ++c) op[(size_t)c << 12] = xp[(size_t)c << 12] * scale;
}

// ---------------- K5b: 1x1-conv hybrid overwrite for valid batches (gated, rare) ----------------
__global__ __launch_bounds__(256) void k_hybrid(const float* __restrict__ x, const float* __restrict__ mask,
                                                const float* __restrict__ fq, const float* __restrict__ fs,
                                                const float* __restrict__ Wc, const float* __restrict__ bc,
                                                const int* __restrict__ idxv, const float* __restrict__ wv,
                                                const float* __restrict__ smx, const float* __restrict__ sden,
                                                const float* __restrict__ valid, float* __restrict__ out) {
  int b = blockIdx.z;
  if (valid[b] == 0.f) return;
  int n = blockIdx.x * 256 + threadIdx.x;
  int o0 = blockIdx.y * 16;
  int bn = (b << 12) + n;
  float mn = mask[bn];
  if (mn == 0.f) return;
  int j = idxv[bn];
  float w = expf(wv[bn] - smx[b]) / sden[b];
  float fsj = fs[(b << 12) + j];
  float fqn = fq[bn];
  const float* xb = x + (((size_t)b * C_) << 12);
  for (int oo = 0; oo < 16; ++oo) {
    int o = o0 + oo;
    const float* wr = Wc + o * 2 * C_;
    float a1 = 0.f, a2 = 0.f;
    for (int i = 0; i < C_; ++i) {
      a1 += wr[i] * xb[((size_t)i << 12) + j];
      a2 += wr[C_ + i] * xb[((size_t)i << 12) + n];
    }
    out[((size_t)(b * C_ + o) << 12) + n] = bc[o] + a1 * (fsj * w) + a2 * fqn;
  }
}

// ---------------- K6a: mark set of idx[B-1,:] ----------------
__global__ __launch_bounds__(256) void k_mark(const int* __restrict__ idxv, int* __restrict__ mark) {
  int t = threadIdx.x;
  for (int i = t; i < N_; i += 256) mark[i] = 0;
  __syncthreads();
  for (int i = t; i < N_; i += 256) mark[idxv[((B_ - 1) << 12) + i]] = 1;
}

// ---------------- K6b: attmap nearest x8 upsample ----------------
__global__ __launch_bounds__(256) void k_att(const int* __restrict__ mark, float* __restrict__ att) {
  int id = blockIdx.x * 256 + threadIdx.x;
  int x4 = (id & 127) << 2;
  int y = (id >> 7) & 511;
  int b = id >> 16;
  float v = mark[((y >> 3) << 6) + (x4 >> 3)] ? 1.f : 0.f;
  float4 vv = make_float4(v, v, v, v);
  *reinterpret_cast<float4*>(att + (((size_t)b) << 18) + (y << 9) + x4) = vv;
}

extern "C" void kernel_launch(void* const* d_in, const int* in_sizes, int n_in,
                              void* d_out, int out_size, void* d_ws, size_t ws_size,
                              hipStream_t stream) {
  const float* x = (const float*)d_in[0];
  const float* mask = (const float*)d_in[1];
  const float* Wc = (const float*)d_in[2];
  const float* bc = (const float*)d_in[3];
  float* out = (float*)d_out;
  float* att = out + (size_t)B_ * C_ * N_;

  float* wsf = (float*)d_ws;
  float* fq = wsf;                          // 32768
  float* fs = wsf + 32768;                  // 32768
  float* wv = wsf + 65536;                  // 32768
  int* idxv = (int*)(wsf + 98304);          // 32768
  float* partV = wsf + 131072;              // 262144 (legacy)
  int* partI = (int*)(wsf + 393216);        // 262144 (legacy)
  float* valid = wsf + 655360;              // 8
  int* need = (int*)(wsf + 655368);         // 8
  float* smx = wsf + 655376;                // 8
  float* sden = wsf + 655384;               // 8
  int* mark = (int*)(wsf + 655392);         // 4096
  float* partMax = wsf + 659488;            // 128
  float* p7V = wsf + 659616;                // 131072 -> ends 790688
  int* p7I = (int*)(wsf + 790688);          // 131072 -> ends 921760
  unsigned short* qhi = (unsigned short*)(wsf + 921760);   // 524288 floats (2MB) each
  unsigned short* qlo = (unsigned short*)(wsf + 1446048);
  unsigned short* shi = (unsigned short*)(wsf + 1970336);
  unsigned short* slo = (unsigned short*)(wsf + 2494624);  // end: 3018912 floats (~11.5MB)

  k_norms<<<512, 256, 0, stream>>>(x, mask, fq, fs);
  k_valid_part<<<dim3(16, B_), 256, 0, stream>>>(x, fq, fs, partMax);
  k_valid_fin<<<1, 128, 0, stream>>>(partMax, mask, valid, need);
  k_prep7<<<dim3(64, 4), 256, 0, stream>>>(x, fq, fs, qhi, qlo, shi, slo);
  k_sim7<<<dim3(32, 32), 256, 0, stream>>>(qhi, qlo, shi, slo, p7V, p7I);
  k_red7<<<16, 256, 0, stream>>>(p7V, p7I, wv, idxv);
  k_sim<<<dim3(8, 64, B_ - 1), 256, 0, stream>>>(x, fq, fs, need, partV, partI);
  k_red<<<112, 256, 0, stream>>>(partV, partI, need, wv, idxv);
  k_soft<<<B_, 256, 0, stream>>>(wv, valid, smx, sden);
  k_out<<<512, 256, 0, stream>>>(x, mask, fq, out);
  k_hybrid<<<dim3(16, 16, B_), 256, 0, stream>>>(x, mask, fq, fs, Wc, bc, idxv, wv, smx, sden, valid, out);
  k_mark<<<1, 256, 0, stream>>>(idxv, mark);
  k_att<<<2048, 256, 0, stream>>>(mark, att);
}

// Round 5
// 85.419 us; speedup vs baseline: 5.6572x; 1.2614x over previous
//
#include <hip/hip_runtime.h>
#include <cmath>

#define B_ 8
#define C_ 256
#define N_ 4096
#define EPS_ 1e-8f

typedef _Float16 half8 __attribute__((ext_vector_type(8)));
typedef float f32x4 __attribute__((ext_vector_type(4)));
typedef unsigned short ushort8 __attribute__((ext_vector_type(8)));

__device__ __forceinline__ void gload_lds16(const void* g, void* l) {
  __builtin_amdgcn_global_load_lds((const __attribute__((address_space(1))) unsigned int*)g,
                                   (__attribute__((address_space(3))) unsigned int*)l, 16, 0, 0);
}

// ---------------- K_base: fused norms + valid-partial + base output ----------------
// One pass over x: fq/fs, sim[b,n,0] partial max, out = m ? x*inv : x.
__global__ __launch_bounds__(256) void k_base(const float* __restrict__ x, const float* __restrict__ mask,
                                              float* __restrict__ fq, float* __restrict__ fs,
                                              float* __restrict__ out, float* __restrict__ partMax) {
  int b = blockIdx.y, n0 = blockIdx.x << 6;
  int t = threadIdx.x;
  int ln = t & 63, cg = t >> 6;
  __shared__ float sred[256];
  __shared__ float s0[256];
  __shared__ float rss[4][64], rdp[4][64];
  __shared__ float scaleS[64], simv[64];
  __shared__ float bcast[2];
  const size_t xbase = ((size_t)b * C_) << 12;
  // norm of column 0 (redundant per block; cheap)
  float xc0 = x[xbase + ((size_t)t << 12)];
  sred[t] = xc0 * xc0;
  __syncthreads();
  for (int s = 128; s; s >>= 1) { if (t < s) sred[t] += sred[t + s]; __syncthreads(); }
  if (t == 0) { bcast[0] = 1.f / (sqrtf(sred[0]) + EPS_); bcast[1] = mask[b << 12]; }
  __syncthreads();
  float fs0 = (1.f - bcast[1]) * bcast[0];
  s0[t] = xc0 * fs0;
  __syncthreads();
  int n = n0 + ln;
  const float* xp = x + xbase + (((size_t)cg) << 18) + n;
  float xv[64];
  float ss = 0.f, dp = 0.f;
#pragma unroll
  for (int c = 0; c < 64; ++c) {
    float v = xp[(size_t)c << 12];
    xv[c] = v;
    ss += v * v;
    dp += v * s0[(cg << 6) + c];
  }
  rss[cg][ln] = ss; rdp[cg][ln] = dp;
  __syncthreads();
  if (cg == 0) {
    float sst = rss[0][ln] + rss[1][ln] + rss[2][ln] + rss[3][ln];
    float dpt = rdp[0][ln] + rdp[1][ln] + rdp[2][ln] + rdp[3][ln];
    float inv = 1.f / (sqrtf(sst) + EPS_);
    float m = mask[(b << 12) + n];
    float fqv = m * inv;
    fq[(b << 12) + n] = fqv;
    fs[(b << 12) + n] = (1.f - m) * inv;
    scaleS[ln] = (m != 0.f) ? inv : 1.f;
    simv[ln] = dpt * fqv;  // masked rows -> exactly 0
  }
  __syncthreads();
  float sc = scaleS[ln];
  float* op = out + xbase + (((size_t)cg) << 18) + n;
#pragma unroll
  for (int c = 0; c < 64; ++c) op[(size_t)c << 12] = xv[c] * sc;
  __syncthreads();
  if (t < 32) simv[t] = fmaxf(simv[t], simv[t + 32]);
  __syncthreads();
  if (t < 16) simv[t] = fmaxf(simv[t], simv[t + 16]);
  __syncthreads();
  if (t < 8) simv[t] = fmaxf(simv[t], simv[t + 8]);
  __syncthreads();
  if (t < 4) simv[t] = fmaxf(simv[t], simv[t + 4]);
  __syncthreads();
  if (t < 2) simv[t] = fmaxf(simv[t], simv[t + 2]);
  __syncthreads();
  if (t == 0) partMax[(b << 6) + blockIdx.x] = fmaxf(simv[0], simv[1]);
}

// ---------------- K2b: finish valid/need (512 partials) ----------------
__global__ __launch_bounds__(512) void k_valid_fin(const float* __restrict__ partMax, const float* __restrict__ mask,
                                                   float* __restrict__ valid, int* __restrict__ need) {
  int t = threadIdx.x;
  __shared__ float red[512];
  red[t] = partMax[t];
  __syncthreads();
  for (int s = 32; s; s >>= 1) { if ((t & 63) < s) red[t] = fmaxf(red[t], red[t + s]); __syncthreads(); }
  if ((t & 63) == 0) {
    int b = t >> 6;
    float fore = red[t];
    float v = (fore > 0.5f) ? mask[b << 12] : 0.f;
    valid[b] = v;
    need[b] = (v != 0.f || b == B_ - 1) ? 1 : 0;
  }
}

// ---------------- K_prep7: scaled (x64), transposed, fp16 hi/lo-split, pre-swizzled arrays for b=7 ----
__global__ __launch_bounds__(256) void k_prep7(const float* __restrict__ x, const float* __restrict__ fq,
                                               const float* __restrict__ fs,
                                               unsigned short* __restrict__ qhi, unsigned short* __restrict__ qlo,
                                               unsigned short* __restrict__ shi, unsigned short* __restrict__ slo) {
  int nb = blockIdx.x, cb = blockIdx.y;
  int n0 = nb << 6, c0 = cb << 6;
  int t = threadIdx.x;
  __shared__ float xt[64][68];
  const float* xb = x + (((size_t)(7 * C_ + c0)) << 12) + n0;
  int cr = t >> 4, n4 = (t & 15) << 2;
#pragma unroll
  for (int p = 0; p < 4; ++p) {
    float4 v = *reinterpret_cast<const float4*>(xb + (((size_t)(p * 16 + cr)) << 12) + n4);
    *reinterpret_cast<float4*>(&xt[p * 16 + cr][n4]) = v;
  }
  __syncthreads();
  int nl = t >> 2;
  int cq = (t & 3) << 4;
  int n = n0 + nl;
  float fqn = fq[(7 << 12) + n] * 64.0f;
  float fsn = fs[(7 << 12) + n] * 64.0f;
  unsigned short oqh[16], oql[16], osh[16], osl[16];
#pragma unroll
  for (int i = 0; i < 16; ++i) {
    float xv = xt[cq + i][nl];
    float qv = xv * fqn;
    _Float16 qh = (_Float16)qv;
    _Float16 ql = (_Float16)((qv - (float)qh) * 2048.0f);
    float sv = xv * fsn;
    _Float16 sh = (_Float16)sv;
    _Float16 sl = (_Float16)((sv - (float)sh) * 2048.0f);
    oqh[i] = __builtin_bit_cast(unsigned short, qh);
    oql[i] = __builtin_bit_cast(unsigned short, ql);
    osh[i] = __builtin_bit_cast(unsigned short, sh);
    osl[i] = __builtin_bit_cast(unsigned short, sl);
  }
  int swz = (n >> 1) & 3;
  size_t rowbase = ((size_t)n) << 8;
#pragma unroll
  for (int j = 0; j < 2; ++j) {
    int c = c0 + cq + j * 8;
    size_t off = rowbase + (size_t)((c >> 5) << 5) + (size_t)((((c >> 3) & 3) ^ swz) << 3);
    *reinterpret_cast<ushort8*>(qhi + off) = *reinterpret_cast<const ushort8*>(&oqh[j * 8]);
    *reinterpret_cast<ushort8*>(qlo + off) = *reinterpret_cast<const ushort8*>(&oql[j * 8]);
    *reinterpret_cast<ushort8*>(shi + off) = *reinterpret_cast<const ushort8*>(&osh[j * 8]);
    *reinterpret_cast<ushort8*>(slo + off) = *reinterpret_cast<const ushort8*>(&osl[j * 8]);
  }
}

// ---------------- K_sim7: MFMA sim + row argmax for b=7 (2-phase double-buffered pipeline) ---------
__global__ __launch_bounds__(256, 2) void k_sim7(const unsigned short* __restrict__ qhi, const unsigned short* __restrict__ qlo,
                                                 const unsigned short* __restrict__ shi, const unsigned short* __restrict__ slo,
                                                 float* __restrict__ partV, int* __restrict__ partI) {
  int mt = blockIdx.x, nt = blockIdx.y;
  int tid = threadIdx.x;
  int w = tid >> 6, lane = tid & 63;
  int wy = w >> 1, wx = w & 1;
  __shared__ __align__(16) unsigned short smem[2][16384];  // 2 x 32KB double buffer

  f32x4 acc_h[4][4], acc_c[4][4];
#pragma unroll
  for (int i = 0; i < 4; ++i)
#pragma unroll
    for (int j = 0; j < 4; ++j) {
      acc_h[i][j] = (f32x4){0.f, 0.f, 0.f, 0.f};
      acc_c[i][j] = (f32x4){0.f, 0.f, 0.f, 0.f};
    }

  const unsigned short* gsrc = (w == 0) ? qhi : (w == 1) ? qlo : (w == 2) ? shi : slo;
  int n0 = ((w < 2) ? nt : mt) << 7;
  int lrow = lane >> 2, lch = lane & 3;
  int s = lane >> 4, c16 = lane & 15;

#define STAGE7(buf, kt)                                                                              \
  _Pragma("unroll")                                                                                  \
  for (int seg = 0; seg < 8; ++seg) {                                                                \
    const unsigned short* g = gsrc + (((size_t)(n0 + (seg << 4) + lrow)) << 8) + ((kt) << 5) + (lch << 3); \
    gload_lds16(g, &smem[buf][(w << 12) + (seg << 9)]);                                              \
  }

  STAGE7(0, 0);
  asm volatile("s_waitcnt vmcnt(0)" ::: "memory");
  __builtin_amdgcn_s_barrier();
  __builtin_amdgcn_sched_barrier(0);

  int cur = 0;
  for (int kt = 0; kt < 8; ++kt) {
    if (kt < 7) { STAGE7(cur ^ 1, kt + 1); }
    const unsigned short* sm = &smem[cur][0];
    half8 ah[4], al[4], bh[4], bl[4];
#pragma unroll
    for (int f = 0; f < 4; ++f) {
      int ra = (wy << 6) + (f << 4) + c16;
      int oa = ra * 32 + ((s ^ ((ra >> 1) & 3)) << 3);
      ah[f] = *reinterpret_cast<const half8*>(&sm[oa]);
      al[f] = *reinterpret_cast<const half8*>(&sm[4096 + oa]);
      int rb = (wx << 6) + (f << 4) + c16;
      int ob = rb * 32 + ((s ^ ((rb >> 1) & 3)) << 3);
      bh[f] = *reinterpret_cast<const half8*>(&sm[8192 + ob]);
      bl[f] = *reinterpret_cast<const half8*>(&sm[12288 + ob]);
    }
#pragma unroll
    for (int fi = 0; fi < 4; ++fi)
#pragma unroll
      for (int fj = 0; fj < 4; ++fj) {
        acc_h[fi][fj] = __builtin_amdgcn_mfma_f32_16x16x32_f16(ah[fi], bh[fj], acc_h[fi][fj], 0, 0, 0);
        acc_c[fi][fj] = __builtin_amdgcn_mfma_f32_16x16x32_f16(ah[fi], bl[fj], acc_c[fi][fj], 0, 0, 0);
        acc_c[fi][fj] = __builtin_amdgcn_mfma_f32_16x16x32_f16(al[fi], bh[fj], acc_c[fi][fj], 0, 0, 0);
      }
    asm volatile("s_waitcnt vmcnt(0) lgkmcnt(0)" ::: "memory");
    __builtin_amdgcn_s_barrier();
    __builtin_amdgcn_sched_barrier(0);
    cur ^= 1;
  }
#undef STAGE7
  // per-row argmax: C/D layout col=lane&15, row=(lane>>4)*4+reg
  float* redV = reinterpret_cast<float*>(&smem[0][0]);       // [128][2]
  int* redI = reinterpret_cast<int*>(&smem[0][512]);         // [128][2]
  int g16 = lane >> 4;
#pragma unroll
  for (int fi = 0; fi < 4; ++fi)
#pragma unroll
    for (int r = 0; r < 4; ++r) {
      float bv = -INFINITY; int bi = 0x7fffffff;
#pragma unroll
      for (int fj = 0; fj < 4; ++fj) {
        float v = (acc_h[fi][fj][r] + acc_c[fi][fj][r] * (1.0f / 2048.0f)) * (1.0f / 4096.0f);
        int colg = (mt << 7) + (wx << 6) + (fj << 4) + c16;
        if (v > bv) { bv = v; bi = colg; }
      }
#pragma unroll
      for (int d = 1; d < 16; d <<= 1) {
        float ov = __shfl_xor(bv, d, 64);
        int oi = __shfl_xor(bi, d, 64);
        if (ov > bv || (ov == bv && oi < bi)) { bv = ov; bi = oi; }
      }
      if (c16 == 0) {
        int row = (wy << 6) + (fi << 4) + (g16 << 2) + r;
        redV[row * 2 + wx] = bv;
        redI[row * 2 + wx] = bi;
      }
    }
  __syncthreads();
  if (tid < 128) {
    float v0 = redV[tid * 2], v1 = redV[tid * 2 + 1];
    int i0 = redI[tid * 2], i1 = redI[tid * 2 + 1];
    if (v1 > v0 || (v1 == v0 && i1 < i0)) { v0 = v1; i0 = i1; }
    int n = (nt << 7) + tid;
    partV[(((size_t)n) << 5) + mt] = v0;
    partI[(((size_t)n) << 5) + mt] = i0;
  }
}

// ---------------- K_red7: reduce 32 m-tiles for b=7 ----------------
__global__ __launch_bounds__(256) void k_red7(const float* __restrict__ partV, const int* __restrict__ partI,
                                              float* __restrict__ wv, int* __restrict__ idxv) {
  int n = blockIdx.x * 256 + threadIdx.x;
  float bv = -INFINITY; int bi = 0x7fffffff;
#pragma unroll 8
  for (int mtv = 0; mtv < 32; ++mtv) {
    float v = partV[(((size_t)n) << 5) + mtv];
    int i = partI[(((size_t)n) << 5) + mtv];
    if (v > bv || (v == bv && i < bi)) { bv = v; bi = i; }
  }
  wv[(7 << 12) + n] = bv; idxv[(7 << 12) + n] = bi;
}

// ---------------- K3: legacy fp32 sim for b<7 (gated by need; ~never runs) ----------------
__global__ __launch_bounds__(256) void k_sim(const float* __restrict__ x, const float* __restrict__ fq,
                                             const float* __restrict__ fs, const int* __restrict__ need,
                                             float* __restrict__ partV, int* __restrict__ partI) {
  int b = blockIdx.z;
  if (!need[b]) return;
  int mc = blockIdx.x;
  int n0 = blockIdx.y << 6;
  int tid = threadIdx.x;
  int tx = tid & 15, ty = tid >> 4;
  int lk = ty, ln4 = tx << 2;

  __shared__ float As[16][68];
  __shared__ float Bs[16][68];
  __shared__ float fqs[64], fss[64];
  __shared__ float rv[64][17];
  __shared__ int ri[64][17];

  if (tid < 64) fqs[tid] = fq[(b << 12) + n0 + tid];

  float bestv[4]; int besti[4];
#pragma unroll
  for (int i = 0; i < 4; ++i) { bestv[i] = -INFINITY; besti[i] = 0; }

  const size_t xb = ((size_t)b * C_) << 12;

  for (int ms = 0; ms < 8; ++ms) {
    int m0 = (mc << 9) + (ms << 6);
    if (tid < 64) fss[tid] = fs[(b << 12) + m0 + tid];
    float cacc[4][4];
#pragma unroll
    for (int i = 0; i < 4; ++i)
#pragma unroll
      for (int j = 0; j < 4; ++j) cacc[i][j] = 0.f;
    __syncthreads();
    for (int kt = 0; kt < C_; kt += 16) {
      float4 va = *reinterpret_cast<const float4*>(x + xb + ((size_t)(kt + lk) << 12) + n0 + ln4);
      float4 vb = *reinterpret_cast<const float4*>(x + xb + ((size_t)(kt + lk) << 12) + m0 + ln4);
      va.x *= fqs[ln4]; va.y *= fqs[ln4 + 1]; va.z *= fqs[ln4 + 2]; va.w *= fqs[ln4 + 3];
      vb.x *= fss[ln4]; vb.y *= fss[ln4 + 1]; vb.z *= fss[ln4 + 2]; vb.w *= fss[ln4 + 3];
      *reinterpret_cast<float4*>(&As[lk][ln4]) = va;
      *reinterpret_cast<float4*>(&Bs[lk][ln4]) = vb;
      __syncthreads();
#pragma unroll
      for (int k = 0; k < 16; ++k) {
        float a0 = As[k][(ty << 2) + 0], a1 = As[k][(ty << 2) + 1], a2 = As[k][(ty << 2) + 2], a3 = As[k][(ty << 2) + 3];
        float b0 = Bs[k][(tx << 2) + 0], b1 = Bs[k][(tx << 2) + 1], b2 = Bs[k][(tx << 2) + 2], b3 = Bs[k][(tx << 2) + 3];
        cacc[0][0] += a0 * b0; cacc[0][1] += a0 * b1; cacc[0][2] += a0 * b2; cacc[0][3] += a0 * b3;
        cacc[1][0] += a1 * b0; cacc[1][1] += a1 * b1; cacc[1][2] += a1 * b2; cacc[1][3] += a1 * b3;
        cacc[2][0] += a2 * b0; cacc[2][1] += a2 * b1; cacc[2][2] += a2 * b2; cacc[2][3] += a2 * b3;
        cacc[3][0] += a3 * b0; cacc[3][1] += a3 * b1; cacc[3][2] += a3 * b2; cacc[3][3] += a3 * b3;
      }
      __syncthreads();
    }
#pragma unroll
    for (int j = 0; j < 4; ++j) {
      int col = m0 + (tx << 2) + j;
#pragma unroll
      for (int i = 0; i < 4; ++i) {
        float v = cacc[i][j];
        if (v > bestv[i] || (v == bestv[i] && col < besti[i])) { bestv[i] = v; besti[i] = col; }
      }
    }
  }
#pragma unroll
  for (int i = 0; i < 4; ++i) { rv[(ty << 2) + i][tx] = bestv[i]; ri[(ty << 2) + i][tx] = besti[i]; }
  __syncthreads();
  if (tid < 64) {
    float bv = rv[tid][0]; int bi = ri[tid][0];
#pragma unroll
    for (int t = 1; t < 16; ++t) {
      float v = rv[tid][t]; int ii = ri[tid][t];
      if (v > bv || (v == bv && ii < bi)) { bv = v; bi = ii; }
    }
    size_t po = (((size_t)((b << 6) + blockIdx.y)) << 9) + ((size_t)mc << 6) + tid;
    partV[po] = bv; partI[po] = bi;
  }
}

// ---------------- K3b: legacy reduce (b<7, gated) ----------------
__global__ __launch_bounds__(256) void k_red(const float* __restrict__ partV, const int* __restrict__ partI,
                                             const int* __restrict__ need, float* __restrict__ wv,
                                             int* __restrict__ idxv) {
  int bn = blockIdx.x * 256 + threadIdx.x;
  int b = bn >> 12;
  if (!need[b]) return;
  int n = bn & 4095; int nt = n >> 6, r = n & 63;
  float bv = -INFINITY; int bi = 0;
  for (int mcn = 0; mcn < 8; ++mcn) {
    size_t po = (((size_t)((b << 6) + nt)) << 9) + ((size_t)mcn << 6) + r;
    float v = partV[po]; int ii = partI[po];
    if (v > bv || (v == bv && ii < bi)) { bv = v; bi = ii; }
  }
  wv[bn] = bv; idxv[bn] = bi;
}

// ---------------- K4: softmax scalars per valid batch ----------------
__global__ __launch_bounds__(256) void k_soft(const float* __restrict__ wv, const float* __restrict__ valid,
                                              float* __restrict__ smx, float* __restrict__ sden) {
  int b = blockIdx.x;
  if (valid[b] == 0.f) return;
  int tid = threadIdx.x;
  __shared__ float red[256];
  float mx = -INFINITY;
  for (int n = tid; n < N_; n += 256) mx = fmaxf(mx, wv[(b << 12) + n]);
  red[tid] = mx; __syncthreads();
  for (int s = 128; s; s >>= 1) { if (tid < s) red[tid] = fmaxf(red[tid], red[tid + s]); __syncthreads(); }
  mx = red[0]; __syncthreads();
  float sm = 0.f;
  for (int n = tid; n < N_; n += 256) sm += expf(wv[(b << 12) + n] - mx);
  red[tid] = sm; __syncthreads();
  for (int s = 128; s; s >>= 1) { if (tid < s) red[tid] += red[tid + s]; __syncthreads(); }
  if (tid == 0) { smx[b] = mx; sden[b] = red[0]; }
}

// ---------------- K5b: 1x1-conv hybrid overwrite for valid batches (gated, rare) ----------------
__global__ __launch_bounds__(256) void k_hybrid(const float* __restrict__ x, const float* __restrict__ mask,
                                                const float* __restrict__ fq, const float* __restrict__ fs,
                                                const float* __restrict__ Wc, const float* __restrict__ bc,
                                                const int* __restrict__ idxv, const float* __restrict__ wv,
                                                const float* __restrict__ smx, const float* __restrict__ sden,
                                                const float* __restrict__ valid, float* __restrict__ out) {
  int b = blockIdx.z;
  if (valid[b] == 0.f) return;
  int n = blockIdx.x * 256 + threadIdx.x;
  int o0 = blockIdx.y * 16;
  int bn = (b << 12) + n;
  float mn = mask[bn];
  if (mn == 0.f) return;
  int j = idxv[bn];
  float w = expf(wv[bn] - smx[b]) / sden[b];
  float fsj = fs[(b << 12) + j];
  float fqn = fq[bn];
  const float* xb = x + (((size_t)b * C_) << 12);
  for (int oo = 0; oo < 16; ++oo) {
    int o = o0 + oo;
    const float* wr = Wc + o * 2 * C_;
    float a1 = 0.f, a2 = 0.f;
    for (int i = 0; i < C_; ++i) {
      a1 += wr[i] * xb[((size_t)i << 12) + j];
      a2 += wr[C_ + i] * xb[((size_t)i << 12) + n];
    }
    out[((size_t)(b * C_ + o) << 12) + n] = bc[o] + a1 * (fsj * w) + a2 * fqn;
  }
}

// ---------------- K6a: mark set of idx[B-1,:] ----------------
__global__ __launch_bounds__(256) void k_mark(const int* __restrict__ idxv, int* __restrict__ mark) {
  int t = threadIdx.x;
  for (int i = t; i < N_; i += 256) mark[i] = 0;
  __syncthreads();
  for (int i = t; i < N_; i += 256) mark[idxv[((B_ - 1) << 12) + i]] = 1;
}

// ---------------- K6b: attmap nearest x8 upsample ----------------
__global__ __launch_bounds__(256) void k_att(const int* __restrict__ mark, float* __restrict__ att) {
  int id = blockIdx.x * 256 + threadIdx.x;
  int x4 = (id & 127) << 2;
  int y = (id >> 7) & 511;
  int b = id >> 16;
  float v = mark[((y >> 3) << 6) + (x4 >> 3)] ? 1.f : 0.f;
  float4 vv = make_float4(v, v, v, v);
  *reinterpret_cast<float4*>(att + (((size_t)b) << 18) + (y << 9) + x4) = vv;
}

extern "C" void kernel_launch(void* const* d_in, const int* in_sizes, int n_in,
                              void* d_out, int out_size, void* d_ws, size_t ws_size,
                              hipStream_t stream) {
  const float* x = (const float*)d_in[0];
  const float* mask = (const float*)d_in[1];
  const float* Wc = (const float*)d_in[2];
  const float* bc = (const float*)d_in[3];
  float* out = (float*)d_out;
  float* att = out + (size_t)B_ * C_ * N_;

  float* wsf = (float*)d_ws;
  float* fq = wsf;                          // 32768
  float* fs = wsf + 32768;                  // 32768
  float* wv = wsf + 65536;                  // 32768
  int* idxv = (int*)(wsf + 98304);          // 32768
  float* partV = wsf + 131072;              // 262144 (legacy)
  int* partI = (int*)(wsf + 393216);        // 262144 (legacy)
  float* valid = wsf + 655360;              // 8
  int* need = (int*)(wsf + 655368);         // 8
  float* smx = wsf + 655376;                // 8
  float* sden = wsf + 655384;               // 8
  int* mark = (int*)(wsf + 655392);         // 4096 -> ends 659488
  float* partMax = wsf + 659488;            // 512 -> ends 660000
  float* p7V = wsf + 660000;                // 131072 -> ends 791072
  int* p7I = (int*)(wsf + 791072);          // 131072 -> ends 922144
  unsigned short* qhi = (unsigned short*)(wsf + 922144);   // 524288 floats (2MB) each
  unsigned short* qlo = (unsigned short*)(wsf + 1446432);
  unsigned short* shi = (unsigned short*)(wsf + 1970720);
  unsigned short* slo = (unsigned short*)(wsf + 2495008);  // end: 3019296 floats (~11.5MB)

  k_base<<<dim3(64, B_), 256, 0, stream>>>(x, mask, fq, fs, out, partMax);
  k_valid_fin<<<1, 512, 0, stream>>>(partMax, mask, valid, need);
  k_prep7<<<dim3(64, 4), 256, 0, stream>>>(x, fq, fs, qhi, qlo, shi, slo);
  k_sim7<<<dim3(32, 32), 256, 0, stream>>>(qhi, qlo, shi, slo, p7V, p7I);
  k_red7<<<16, 256, 0, stream>>>(p7V, p7I, wv, idxv);
  k_sim<<<dim3(8, 64, B_ - 1), 256, 0, stream>>>(x, fq, fs, need, partV, partI);
  k_red<<<112, 256, 0, stream>>>(partV, partI, need, wv, idxv);
  k_soft<<<B_, 256, 0, stream>>>(wv, valid, smx, sden);
  k_hybrid<<<dim3(16, 16, B_), 256, 0, stream>>>(x, mask, fq, fs, Wc, bc, idxv, wv, smx, sden, valid, out);
  k_mark<<<1, 256, 0, stream>>>(idxv, mark);
  k_att<<<2048, 256, 0, stream>>>(mark, att);
}

// Round 6
// 79.635 us; speedup vs baseline: 6.0680x; 1.0726x over previous
//
#include <hip/hip_runtime.h>
#include <cmath>

#define B_ 8
#define C_ 256
#define N_ 4096
#define EPS_ 1e-8f

typedef _Float16 half8 __attribute__((ext_vector_type(8)));
typedef float f32x4 __attribute__((ext_vector_type(4)));
typedef unsigned short ushort8 __attribute__((ext_vector_type(8)));

__device__ __forceinline__ void gload_lds16(const void* g, void* l) {
  __builtin_amdgcn_global_load_lds((const __attribute__((address_space(1))) unsigned int*)g,
                                   (__attribute__((address_space(3))) unsigned int*)l, 16, 0, 0);
}

// ---------------- K_base: fused norms + valid-partial + base output (512 threads) ----------------
__global__ __launch_bounds__(512) void k_base(const float* __restrict__ x, const float* __restrict__ mask,
                                              float* __restrict__ fq, float* __restrict__ fs,
                                              float* __restrict__ out, float* __restrict__ partMax) {
  int b = blockIdx.y, n0 = blockIdx.x << 6;
  int t = threadIdx.x;            // 0..511
  int ln = t & 63, cg = t >> 6;   // 8 groups x 32 channels
  __shared__ float sred[512];
  __shared__ float s0[256];
  __shared__ float rss[8][64], rdp[8][64];
  __shared__ float scaleS[64];
  __shared__ float bcast[2];
  const size_t xbase = ((size_t)b * C_) << 12;
  // norm of column 0 (redundant per block; cheap)
  float xc0 = 0.f;
  if (t < 256) xc0 = x[xbase + ((size_t)t << 12)];
  sred[t] = xc0 * xc0;
  __syncthreads();
  for (int s = 256; s; s >>= 1) { if (t < s) sred[t] += sred[t + s]; __syncthreads(); }
  if (t == 0) { bcast[0] = 1.f / (sqrtf(sred[0]) + EPS_); bcast[1] = mask[b << 12]; }
  __syncthreads();
  if (t < 256) s0[t] = xc0 * ((1.f - bcast[1]) * bcast[0]);
  __syncthreads();
  int n = n0 + ln;
  const float* xp = x + xbase + (((size_t)cg) << 17) + n;
  float xv[32];
  float ss = 0.f, dp = 0.f;
#pragma unroll
  for (int c = 0; c < 32; ++c) {
    float v = xp[(size_t)c << 12];
    xv[c] = v;
    ss += v * v;
    dp += v * s0[(cg << 5) + c];
  }
  rss[cg][ln] = ss; rdp[cg][ln] = dp;
  __syncthreads();
  if (t < 64) {
    float sst = 0.f, dpt = 0.f;
#pragma unroll
    for (int g = 0; g < 8; ++g) { sst += rss[g][t]; dpt += rdp[g][t]; }
    float inv = 1.f / (sqrtf(sst) + EPS_);
    float m = mask[(b << 12) + n0 + t];
    float fqv = m * inv;
    fq[(b << 12) + n0 + t] = fqv;
    fs[(b << 12) + n0 + t] = (1.f - m) * inv;
    scaleS[t] = (m != 0.f) ? inv : 1.f;
    // wave-0 shfl max of sim partial
    float val = dpt * fqv;  // masked rows -> exactly 0
#pragma unroll
    for (int d = 32; d; d >>= 1) val = fmaxf(val, __shfl_xor(val, d, 64));
    if (t == 0) partMax[(b << 6) + blockIdx.x] = val;
  }
  __syncthreads();
  float sc = scaleS[ln];
  float* op = out + xbase + (((size_t)cg) << 17) + n;
#pragma unroll
  for (int c = 0; c < 32; ++c) op[(size_t)c << 12] = xv[c] * sc;
}

// ---------------- K2b: finish valid/need + zero mark ----------------
__global__ __launch_bounds__(512) void k_valid_fin(const float* __restrict__ partMax, const float* __restrict__ mask,
                                                   float* __restrict__ valid, int* __restrict__ need,
                                                   int* __restrict__ mark) {
  int t = threadIdx.x;
#pragma unroll
  for (int i = 0; i < 8; ++i) mark[t + (i << 9)] = 0;
  __shared__ float red[512];
  red[t] = partMax[t];
  __syncthreads();
  for (int s = 32; s; s >>= 1) { if ((t & 63) < s) red[t] = fmaxf(red[t], red[t + s]); __syncthreads(); }
  if ((t & 63) == 0) {
    int b = t >> 6;
    float fore = red[t];
    float v = (fore > 0.5f) ? mask[b << 12] : 0.f;
    valid[b] = v;
    need[b] = (v != 0.f || b == B_ - 1) ? 1 : 0;
  }
}

// ---------------- K_prep7: scaled (x64), transposed, fp16 hi/lo-split, pre-swizzled arrays for b=7 ----
__global__ __launch_bounds__(256) void k_prep7(const float* __restrict__ x, const float* __restrict__ fq,
                                               const float* __restrict__ fs,
                                               unsigned short* __restrict__ qhi, unsigned short* __restrict__ qlo,
                                               unsigned short* __restrict__ shi, unsigned short* __restrict__ slo) {
  int nb = blockIdx.x, cb = blockIdx.y;
  int n0 = nb << 6, c0 = cb << 6;
  int t = threadIdx.x;
  __shared__ float xt[64][68];
  const float* xb = x + (((size_t)(7 * C_ + c0)) << 12) + n0;
  int cr = t >> 4, n4 = (t & 15) << 2;
#pragma unroll
  for (int p = 0; p < 4; ++p) {
    float4 v = *reinterpret_cast<const float4*>(xb + (((size_t)(p * 16 + cr)) << 12) + n4);
    *reinterpret_cast<float4*>(&xt[p * 16 + cr][n4]) = v;
  }
  __syncthreads();
  int nl = t >> 2;
  int cq = (t & 3) << 4;
  int n = n0 + nl;
  float fqn = fq[(7 << 12) + n] * 64.0f;
  float fsn = fs[(7 << 12) + n] * 64.0f;
  unsigned short oqh[16], oql[16], osh[16], osl[16];
#pragma unroll
  for (int i = 0; i < 16; ++i) {
    float xv = xt[cq + i][nl];
    float qv = xv * fqn;
    _Float16 qh = (_Float16)qv;
    _Float16 ql = (_Float16)((qv - (float)qh) * 2048.0f);
    float sv = xv * fsn;
    _Float16 sh = (_Float16)sv;
    _Float16 sl = (_Float16)((sv - (float)sh) * 2048.0f);
    oqh[i] = __builtin_bit_cast(unsigned short, qh);
    oql[i] = __builtin_bit_cast(unsigned short, ql);
    osh[i] = __builtin_bit_cast(unsigned short, sh);
    osl[i] = __builtin_bit_cast(unsigned short, sl);
  }
  int swz = (n >> 1) & 3;
  size_t rowbase = ((size_t)n) << 8;
#pragma unroll
  for (int j = 0; j < 2; ++j) {
    int c = c0 + cq + j * 8;
    size_t off = rowbase + (size_t)((c >> 5) << 5) + (size_t)((((c >> 3) & 3) ^ swz) << 3);
    *reinterpret_cast<ushort8*>(qhi + off) = *reinterpret_cast<const ushort8*>(&oqh[j * 8]);
    *reinterpret_cast<ushort8*>(qlo + off) = *reinterpret_cast<const ushort8*>(&oql[j * 8]);
    *reinterpret_cast<ushort8*>(shi + off) = *reinterpret_cast<const ushort8*>(&osh[j * 8]);
    *reinterpret_cast<ushort8*>(slo + off) = *reinterpret_cast<const ushort8*>(&osl[j * 8]);
  }
}

// ---------------- K_sim7: MFMA sim + row argmax for b=7 (2-phase dbuf, XCD-swizzled grid) ----------
__global__ __launch_bounds__(256, 2) void k_sim7(const unsigned short* __restrict__ qhi, const unsigned short* __restrict__ qlo,
                                                 const unsigned short* __restrict__ shi, const unsigned short* __restrict__ slo,
                                                 float* __restrict__ partV, int* __restrict__ partI) {
  int bid = blockIdx.x;
  int lin = ((bid & 7) << 7) + (bid >> 3);  // XCD-contiguous chunks (1024 % 8 == 0, bijective)
  int mt = lin & 31, nt = lin >> 5;
  int tid = threadIdx.x;
  int w = tid >> 6, lane = tid & 63;
  int wy = w >> 1, wx = w & 1;
  __shared__ __align__(16) unsigned short smem[2][16384];  // 2 x 32KB double buffer

  f32x4 acc_h[4][4], acc_c[4][4];
#pragma unroll
  for (int i = 0; i < 4; ++i)
#pragma unroll
    for (int j = 0; j < 4; ++j) {
      acc_h[i][j] = (f32x4){0.f, 0.f, 0.f, 0.f};
      acc_c[i][j] = (f32x4){0.f, 0.f, 0.f, 0.f};
    }

  const unsigned short* gsrc = (w == 0) ? qhi : (w == 1) ? qlo : (w == 2) ? shi : slo;
  int n0 = ((w < 2) ? nt : mt) << 7;
  int lrow = lane >> 2, lch = lane & 3;
  int s = lane >> 4, c16 = lane & 15;

#define STAGE7(buf, kt)                                                                              \
  _Pragma("unroll")                                                                                  \
  for (int seg = 0; seg < 8; ++seg) {                                                                \
    const unsigned short* g = gsrc + (((size_t)(n0 + (seg << 4) + lrow)) << 8) + ((kt) << 5) + (lch << 3); \
    gload_lds16(g, &smem[buf][(w << 12) + (seg << 9)]);                                              \
  }

  STAGE7(0, 0);
  asm volatile("s_waitcnt vmcnt(0)" ::: "memory");
  __builtin_amdgcn_s_barrier();
  __builtin_amdgcn_sched_barrier(0);

  int cur = 0;
  for (int kt = 0; kt < 8; ++kt) {
    if (kt < 7) { STAGE7(cur ^ 1, kt + 1); }
    const unsigned short* sm = &smem[cur][0];
    half8 ah[4], al[4], bh[4], bl[4];
#pragma unroll
    for (int f = 0; f < 4; ++f) {
      int ra = (wy << 6) + (f << 4) + c16;
      int oa = ra * 32 + ((s ^ ((ra >> 1) & 3)) << 3);
      ah[f] = *reinterpret_cast<const half8*>(&sm[oa]);
      al[f] = *reinterpret_cast<const half8*>(&sm[4096 + oa]);
      int rb = (wx << 6) + (f << 4) + c16;
      int ob = rb * 32 + ((s ^ ((rb >> 1) & 3)) << 3);
      bh[f] = *reinterpret_cast<const half8*>(&sm[8192 + ob]);
      bl[f] = *reinterpret_cast<const half8*>(&sm[12288 + ob]);
    }
#pragma unroll
    for (int fi = 0; fi < 4; ++fi)
#pragma unroll
      for (int fj = 0; fj < 4; ++fj) {
        acc_h[fi][fj] = __builtin_amdgcn_mfma_f32_16x16x32_f16(ah[fi], bh[fj], acc_h[fi][fj], 0, 0, 0);
        acc_c[fi][fj] = __builtin_amdgcn_mfma_f32_16x16x32_f16(ah[fi], bl[fj], acc_c[fi][fj], 0, 0, 0);
        acc_c[fi][fj] = __builtin_amdgcn_mfma_f32_16x16x32_f16(al[fi], bh[fj], acc_c[fi][fj], 0, 0, 0);
      }
    asm volatile("s_waitcnt vmcnt(0) lgkmcnt(0)" ::: "memory");
    __builtin_amdgcn_s_barrier();
    __builtin_amdgcn_sched_barrier(0);
    cur ^= 1;
  }
#undef STAGE7
  // per-row argmax: C/D layout col=lane&15, row=(lane>>4)*4+reg
  float* redV = reinterpret_cast<float*>(&smem[0][0]);       // [128][2]
  int* redI = reinterpret_cast<int*>(&smem[0][512]);         // [128][2]
  int g16 = lane >> 4;
#pragma unroll
  for (int fi = 0; fi < 4; ++fi)
#pragma unroll
    for (int r = 0; r < 4; ++r) {
      float bv = -INFINITY; int bi = 0x7fffffff;
#pragma unroll
      for (int fj = 0; fj < 4; ++fj) {
        float v = (acc_h[fi][fj][r] + acc_c[fi][fj][r] * (1.0f / 2048.0f)) * (1.0f / 4096.0f);
        int colg = (mt << 7) + (wx << 6) + (fj << 4) + c16;
        if (v > bv) { bv = v; bi = colg; }
      }
#pragma unroll
      for (int d = 1; d < 16; d <<= 1) {
        float ov = __shfl_xor(bv, d, 64);
        int oi = __shfl_xor(bi, d, 64);
        if (ov > bv || (ov == bv && oi < bi)) { bv = ov; bi = oi; }
      }
      if (c16 == 0) {
        int row = (wy << 6) + (fi << 4) + (g16 << 2) + r;
        redV[row * 2 + wx] = bv;
        redI[row * 2 + wx] = bi;
      }
    }
  __syncthreads();
  if (tid < 128) {
    float v0 = redV[tid * 2], v1 = redV[tid * 2 + 1];
    int i0 = redI[tid * 2], i1 = redI[tid * 2 + 1];
    if (v1 > v0 || (v1 == v0 && i1 < i0)) { v0 = v1; i0 = i1; }
    int n = (nt << 7) + tid;
    partV[(((size_t)n) << 5) + mt] = v0;
    partI[(((size_t)n) << 5) + mt] = i0;
  }
}

// ---------------- K3: legacy fp32 sim for b<7 (gated by need; ~never runs) ----------------
__global__ __launch_bounds__(256) void k_sim(const float* __restrict__ x, const float* __restrict__ fq,
                                             const float* __restrict__ fs, const int* __restrict__ need,
                                             float* __restrict__ partV, int* __restrict__ partI) {
  int b = blockIdx.z;
  if (!need[b]) return;
  int mc = blockIdx.x;
  int n0 = blockIdx.y << 6;
  int tid = threadIdx.x;
  int tx = tid & 15, ty = tid >> 4;
  int lk = ty, ln4 = tx << 2;

  __shared__ float As[16][68];
  __shared__ float Bs[16][68];
  __shared__ float fqs[64], fss[64];
  __shared__ float rv[64][17];
  __shared__ int ri[64][17];

  if (tid < 64) fqs[tid] = fq[(b << 12) + n0 + tid];

  float bestv[4]; int besti[4];
#pragma unroll
  for (int i = 0; i < 4; ++i) { bestv[i] = -INFINITY; besti[i] = 0; }

  const size_t xb = ((size_t)b * C_) << 12;

  for (int ms = 0; ms < 8; ++ms) {
    int m0 = (mc << 9) + (ms << 6);
    if (tid < 64) fss[tid] = fs[(b << 12) + m0 + tid];
    float cacc[4][4];
#pragma unroll
    for (int i = 0; i < 4; ++i)
#pragma unroll
      for (int j = 0; j < 4; ++j) cacc[i][j] = 0.f;
    __syncthreads();
    for (int kt = 0; kt < C_; kt += 16) {
      float4 va = *reinterpret_cast<const float4*>(x + xb + ((size_t)(kt + lk) << 12) + n0 + ln4);
      float4 vb = *reinterpret_cast<const float4*>(x + xb + ((size_t)(kt + lk) << 12) + m0 + ln4);
      va.x *= fqs[ln4]; va.y *= fqs[ln4 + 1]; va.z *= fqs[ln4 + 2]; va.w *= fqs[ln4 + 3];
      vb.x *= fss[ln4]; vb.y *= fss[ln4 + 1]; vb.z *= fss[ln4 + 2]; vb.w *= fss[ln4 + 3];
      *reinterpret_cast<float4*>(&As[lk][ln4]) = va;
      *reinterpret_cast<float4*>(&Bs[lk][ln4]) = vb;
      __syncthreads();
#pragma unroll
      for (int k = 0; k < 16; ++k) {
        float a0 = As[k][(ty << 2) + 0], a1 = As[k][(ty << 2) + 1], a2 = As[k][(ty << 2) + 2], a3 = As[k][(ty << 2) + 3];
        float b0 = Bs[k][(tx << 2) + 0], b1 = Bs[k][(tx << 2) + 1], b2 = Bs[k][(tx << 2) + 2], b3 = Bs[k][(tx << 2) + 3];
        cacc[0][0] += a0 * b0; cacc[0][1] += a0 * b1; cacc[0][2] += a0 * b2; cacc[0][3] += a0 * b3;
        cacc[1][0] += a1 * b0; cacc[1][1] += a1 * b1; cacc[1][2] += a1 * b2; cacc[1][3] += a1 * b3;
        cacc[2][0] += a2 * b0; cacc[2][1] += a2 * b1; cacc[2][2] += a2 * b2; cacc[2][3] += a2 * b3;
        cacc[3][0] += a3 * b0; cacc[3][1] += a3 * b1; cacc[3][2] += a3 * b2; cacc[3][3] += a3 * b3;
      }
      __syncthreads();
    }
#pragma unroll
    for (int j = 0; j < 4; ++j) {
      int col = m0 + (tx << 2) + j;
#pragma unroll
      for (int i = 0; i < 4; ++i) {
        float v = cacc[i][j];
        if (v > bestv[i] || (v == bestv[i] && col < besti[i])) { bestv[i] = v; besti[i] = col; }
      }
    }
  }
#pragma unroll
  for (int i = 0; i < 4; ++i) { rv[(ty << 2) + i][tx] = bestv[i]; ri[(ty << 2) + i][tx] = besti[i]; }
  __syncthreads();
  if (tid < 64) {
    float bv = rv[tid][0]; int bi = ri[tid][0];
#pragma unroll
    for (int t = 1; t < 16; ++t) {
      float v = rv[tid][t]; int ii = ri[tid][t];
      if (v > bv || (v == bv && ii < bi)) { bv = v; bi = ii; }
    }
    size_t po = (((size_t)((b << 6) + blockIdx.y)) << 9) + ((size_t)mc << 6) + tid;
    partV[po] = bv; partI[po] = bi;
  }
}

// ---------------- K_redall: reduce partials (b=7 from p7V/p7I + mark; b<7 legacy, gated) ---------
__global__ __launch_bounds__(256) void k_redall(const float* __restrict__ partV, const int* __restrict__ partI,
                                                const float* __restrict__ p7V, const int* __restrict__ p7I,
                                                const int* __restrict__ need, float* __restrict__ wv,
                                                int* __restrict__ idxv, int* __restrict__ mark) {
  int bn = blockIdx.x * 256 + threadIdx.x;  // B*N
  int b = bn >> 12, n = bn & 4095;
  if (b == B_ - 1) {
    float bv = -INFINITY; int bi = 0x7fffffff;
#pragma unroll 8
    for (int mtv = 0; mtv < 32; ++mtv) {
      float v = p7V[(((size_t)n) << 5) + mtv];
      int i = p7I[(((size_t)n) << 5) + mtv];
      if (v > bv || (v == bv && i < bi)) { bv = v; bi = i; }
    }
    wv[bn] = bv; idxv[bn] = bi;
    mark[bi] = 1;  // benign same-value race
  } else {
    if (!need[b]) return;
    int nt = n >> 6, r = n & 63;
    float bv = -INFINITY; int bi = 0;
    for (int mcn = 0; mcn < 8; ++mcn) {
      size_t po = (((size_t)((b << 6) + nt)) << 9) + ((size_t)mcn << 6) + r;
      float v = partV[po]; int ii = partI[po];
      if (v > bv || (v == bv && ii < bi)) { bv = v; bi = ii; }
    }
    wv[bn] = bv; idxv[bn] = bi;
  }
}

// ---------------- K4: softmax scalars per valid batch ----------------
__global__ __launch_bounds__(256) void k_soft(const float* __restrict__ wv, const float* __restrict__ valid,
                                              float* __restrict__ smx, float* __restrict__ sden) {
  int b = blockIdx.x;
  if (valid[b] == 0.f) return;
  int tid = threadIdx.x;
  __shared__ float red[256];
  float mx = -INFINITY;
  for (int n = tid; n < N_; n += 256) mx = fmaxf(mx, wv[(b << 12) + n]);
  red[tid] = mx; __syncthreads();
  for (int s = 128; s; s >>= 1) { if (tid < s) red[tid] = fmaxf(red[tid], red[tid + s]); __syncthreads(); }
  mx = red[0]; __syncthreads();
  float sm = 0.f;
  for (int n = tid; n < N_; n += 256) sm += expf(wv[(b << 12) + n] - mx);
  red[tid] = sm; __syncthreads();
  for (int s = 128; s; s >>= 1) { if (tid < s) red[tid] += red[tid + s]; __syncthreads(); }
  if (tid == 0) { smx[b] = mx; sden[b] = red[0]; }
}

// ---------------- K5b: 1x1-conv hybrid overwrite for valid batches (gated, rare) ----------------
__global__ __launch_bounds__(256) void k_hybrid(const float* __restrict__ x, const float* __restrict__ mask,
                                                const float* __restrict__ fq, const float* __restrict__ fs,
                                                const float* __restrict__ Wc, const float* __restrict__ bc,
                                                const int* __restrict__ idxv, const float* __restrict__ wv,
                                                const float* __restrict__ smx, const float* __restrict__ sden,
                                                const float* __restrict__ valid, float* __restrict__ out) {
  int b = blockIdx.z;
  if (valid[b] == 0.f) return;
  int n = blockIdx.x * 256 + threadIdx.x;
  int o0 = blockIdx.y * 16;
  int bn = (b << 12) + n;
  float mn = mask[bn];
  if (mn == 0.f) return;
  int j = idxv[bn];
  float w = expf(wv[bn] - smx[b]) / sden[b];
  float fsj = fs[(b << 12) + j];
  float fqn = fq[bn];
  const float* xb = x + (((size_t)b * C_) << 12);
  for (int oo = 0; oo < 16; ++oo) {
    int o = o0 + oo;
    const float* wr = Wc + o * 2 * C_;
    float a1 = 0.f, a2 = 0.f;
    for (int i = 0; i < C_; ++i) {
      a1 += wr[i] * xb[((size_t)i << 12) + j];
      a2 += wr[C_ + i] * xb[((size_t)i << 12) + n];
    }
    out[((size_t)(b * C_ + o) << 12) + n] = bc[o] + a1 * (fsj * w) + a2 * fqn;
  }
}

// ---------------- K6: attmap nearest x8 upsample (8 px / thread) ----------------
__global__ __launch_bounds__(256) void k_att(const int* __restrict__ mark, float* __restrict__ att) {
  int id = blockIdx.x * 256 + threadIdx.x;  // 262144 threads: 8 b x 512 y x 64 x8-groups
  int x8 = (id & 63) << 3;
  int y = (id >> 6) & 511;
  int b = id >> 15;
  float v = mark[((y >> 3) << 6) + (x8 >> 3)] ? 1.f : 0.f;
  float4 vv = make_float4(v, v, v, v);
  float* p = att + (((size_t)b) << 18) + (y << 9) + x8;
  *reinterpret_cast<float4*>(p) = vv;
  *reinterpret_cast<float4*>(p + 4) = vv;
}

extern "C" void kernel_launch(void* const* d_in, const int* in_sizes, int n_in,
                              void* d_out, int out_size, void* d_ws, size_t ws_size,
                              hipStream_t stream) {
  const float* x = (const float*)d_in[0];
  const float* mask = (const float*)d_in[1];
  const float* Wc = (const float*)d_in[2];
  const float* bc = (const float*)d_in[3];
  float* out = (float*)d_out;
  float* att = out + (size_t)B_ * C_ * N_;

  float* wsf = (float*)d_ws;
  float* fq = wsf;                          // 32768
  float* fs = wsf + 32768;                  // 32768
  float* wv = wsf + 65536;                  // 32768
  int* idxv = (int*)(wsf + 98304);          // 32768
  float* partV = wsf + 131072;              // 262144 (legacy)
  int* partI = (int*)(wsf + 393216);        // 262144 (legacy)
  float* valid = wsf + 655360;              // 8
  int* need = (int*)(wsf + 655368);         // 8
  float* smx = wsf + 655376;                // 8
  float* sden = wsf + 655384;               // 8
  int* mark = (int*)(wsf + 655392);         // 4096 -> ends 659488
  float* partMax = wsf + 659488;            // 512 -> ends 660000
  float* p7V = wsf + 660000;                // 131072 -> ends 791072
  int* p7I = (int*)(wsf + 791072);          // 131072 -> ends 922144
  unsigned short* qhi = (unsigned short*)(wsf + 922144);   // 524288 floats (2MB) each
  unsigned short* qlo = (unsigned short*)(wsf + 1446432);
  unsigned short* shi = (unsigned short*)(wsf + 1970720);
  unsigned short* slo = (unsigned short*)(wsf + 2495008);  // end: 3019296 floats (~11.5MB)

  k_base<<<dim3(64, B_), 512, 0, stream>>>(x, mask, fq, fs, out, partMax);
  k_valid_fin<<<1, 512, 0, stream>>>(partMax, mask, valid, need, mark);
  k_prep7<<<dim3(64, 4), 256, 0, stream>>>(x, fq, fs, qhi, qlo, shi, slo);
  k_sim7<<<1024, 256, 0, stream>>>(qhi, qlo, shi, slo, p7V, p7I);
  k_sim<<<dim3(8, 64, B_ - 1), 256, 0, stream>>>(x, fq, fs, need, partV, partI);
  k_redall<<<128, 256, 0, stream>>>(partV, partI, p7V, p7I, need, wv, idxv, mark);
  k_soft<<<B_, 256, 0, stream>>>(wv, valid, smx, sden);
  k_hybrid<<<dim3(16, 16, B_), 256, 0, stream>>>(x, mask, fq, fs, Wc, bc, idxv, wv, smx, sden, valid, out);
  k_att<<<1024, 256, 0, stream>>>(mark, att);
}

// Round 7
// 75.679 us; speedup vs baseline: 6.3852x; 1.0523x over previous
//
#include <hip/hip_runtime.h>
#include <cmath>

#define B_ 8
#define C_ 256
#define N_ 4096
#define EPS_ 1e-8f

typedef _Float16 half8 __attribute__((ext_vector_type(8)));
typedef float f32x4 __attribute__((ext_vector_type(4)));
typedef unsigned short ushort8 __attribute__((ext_vector_type(8)));

__device__ __forceinline__ void gload_lds16(const void* g, void* l) {
  __builtin_amdgcn_global_load_lds((const __attribute__((address_space(1))) unsigned int*)g,
                                   (__attribute__((address_space(3))) unsigned int*)l, 16, 0, 0);
}

// Block-uniform need/valid recompute from partMax (64 partials per batch).
__device__ __forceinline__ float block_fore(const float* __restrict__ partMax, int b) {
  int l = threadIdx.x & 63;
  float v = partMax[(b << 6) + l];
#pragma unroll
  for (int d = 32; d; d >>= 1) v = fmaxf(v, __shfl_xor(v, d, 64));
  return v;
}

// ---------------- K_base: fused norms + valid-partial + base output + b=7 fp16 prep + mark zero ----
__global__ __launch_bounds__(512) void k_base(const float* __restrict__ x, const float* __restrict__ mask,
                                              float* __restrict__ fq, float* __restrict__ fs,
                                              float* __restrict__ out, float* __restrict__ partMax,
                                              int* __restrict__ mark,
                                              unsigned short* __restrict__ qhi, unsigned short* __restrict__ qlo,
                                              unsigned short* __restrict__ shi, unsigned short* __restrict__ slo) {
  int b = blockIdx.y, n0 = blockIdx.x << 6;
  int t = threadIdx.x;            // 0..511
  int ln = t & 63, cg = t >> 6;   // 8 groups x 32 channels
  __shared__ float sred[512];
  __shared__ float s0[256];
  __shared__ float rss[8][64], rdp[8][64];
  __shared__ float scaleS[64], f64q[64], f64s[64];
  __shared__ float bcast[2];
  if (b == 0 && blockIdx.x == 0) {
#pragma unroll
    for (int i = 0; i < 8; ++i) mark[t + (i << 9)] = 0;
  }
  const size_t xbase = ((size_t)b * C_) << 12;
  // norm of column 0 (redundant per block; cheap)
  float xc0 = 0.f;
  if (t < 256) xc0 = x[xbase + ((size_t)t << 12)];
  sred[t] = xc0 * xc0;
  __syncthreads();
  for (int s = 256; s; s >>= 1) { if (t < s) sred[t] += sred[t + s]; __syncthreads(); }
  if (t == 0) { bcast[0] = 1.f / (sqrtf(sred[0]) + EPS_); bcast[1] = mask[b << 12]; }
  __syncthreads();
  if (t < 256) s0[t] = xc0 * ((1.f - bcast[1]) * bcast[0]);
  __syncthreads();
  int n = n0 + ln;
  const float* xp = x + xbase + (((size_t)cg) << 17) + n;
  float xv[32];
  float ss = 0.f, dp = 0.f;
#pragma unroll
  for (int c = 0; c < 32; ++c) {
    float v = xp[(size_t)c << 12];
    xv[c] = v;
    ss += v * v;
    dp += v * s0[(cg << 5) + c];
  }
  rss[cg][ln] = ss; rdp[cg][ln] = dp;
  __syncthreads();
  if (t < 64) {
    float sst = 0.f, dpt = 0.f;
#pragma unroll
    for (int g = 0; g < 8; ++g) { sst += rss[g][t]; dpt += rdp[g][t]; }
    float inv = 1.f / (sqrtf(sst) + EPS_);
    float m = mask[(b << 12) + n0 + t];
    float fqv = m * inv;
    fq[(b << 12) + n0 + t] = fqv;
    fs[(b << 12) + n0 + t] = (1.f - m) * inv;
    scaleS[t] = (m != 0.f) ? inv : 1.f;
    f64q[t] = fqv * 64.0f;
    f64s[t] = (1.f - m) * inv * 64.0f;
    // wave-0 shfl max of sim partial
    float val = dpt * fqv;  // masked rows -> exactly 0
#pragma unroll
    for (int d = 32; d; d >>= 1) val = fmaxf(val, __shfl_xor(val, d, 64));
    if (t == 0) partMax[(b << 6) + blockIdx.x] = val;
  }
  __syncthreads();
  float sc = scaleS[ln];
  float* op = out + xbase + (((size_t)cg) << 17) + n;
#pragma unroll
  for (int c = 0; c < 32; ++c) op[(size_t)c << 12] = xv[c] * sc;
  if (b == B_ - 1) {
    // fused prep: scaled (x64) fp16 hi/lo split, transposed, pre-swizzled
    float fqn = f64q[ln], fsn = f64s[ln];
    int swz = (n >> 1) & 3;
    size_t rowbase = ((size_t)n) << 8;  // 256 shorts per row
#pragma unroll
    for (int j = 0; j < 4; ++j) {
      ushort8 vqh, vql, vsh, vsl;
#pragma unroll
      for (int i = 0; i < 8; ++i) {
        float xvv = xv[j * 8 + i];
        float qv = xvv * fqn;
        _Float16 qh = (_Float16)qv;
        _Float16 ql = (_Float16)((qv - (float)qh) * 2048.0f);
        float sv = xvv * fsn;
        _Float16 sh = (_Float16)sv;
        _Float16 sl = (_Float16)((sv - (float)sh) * 2048.0f);
        vqh[i] = __builtin_bit_cast(unsigned short, qh);
        vql[i] = __builtin_bit_cast(unsigned short, ql);
        vsh[i] = __builtin_bit_cast(unsigned short, sh);
        vsl[i] = __builtin_bit_cast(unsigned short, sl);
      }
      size_t off = rowbase + ((size_t)cg << 5) + (size_t)((j ^ swz) << 3);
      *reinterpret_cast<ushort8*>(qhi + off) = vqh;
      *reinterpret_cast<ushort8*>(qlo + off) = vql;
      *reinterpret_cast<ushort8*>(shi + off) = vsh;
      *reinterpret_cast<ushort8*>(slo + off) = vsl;
    }
  }
}

// ---------------- K_sim7: MFMA sim + row argmax for b=7 (2-phase dbuf, XCD-swizzled grid) ----------
__global__ __launch_bounds__(256, 2) void k_sim7(const unsigned short* __restrict__ qhi, const unsigned short* __restrict__ qlo,
                                                 const unsigned short* __restrict__ shi, const unsigned short* __restrict__ slo,
                                                 float* __restrict__ partV, int* __restrict__ partI) {
  int bid = blockIdx.x;
  int lin = ((bid & 7) << 7) + (bid >> 3);  // XCD-contiguous chunks (1024 % 8 == 0, bijective)
  int mt = lin & 31, nt = lin >> 5;
  int tid = threadIdx.x;
  int w = tid >> 6, lane = tid & 63;
  int wy = w >> 1, wx = w & 1;
  __shared__ __align__(16) unsigned short smem[2][16384];  // 2 x 32KB double buffer

  f32x4 acc_h[4][4], acc_c[4][4];
#pragma unroll
  for (int i = 0; i < 4; ++i)
#pragma unroll
    for (int j = 0; j < 4; ++j) {
      acc_h[i][j] = (f32x4){0.f, 0.f, 0.f, 0.f};
      acc_c[i][j] = (f32x4){0.f, 0.f, 0.f, 0.f};
    }

  const unsigned short* gsrc = (w == 0) ? qhi : (w == 1) ? qlo : (w == 2) ? shi : slo;
  int n0 = ((w < 2) ? nt : mt) << 7;
  int lrow = lane >> 2, lch = lane & 3;
  int s = lane >> 4, c16 = lane & 15;

#define STAGE7(buf, kt)                                                                              \
  _Pragma("unroll")                                                                                  \
  for (int seg = 0; seg < 8; ++seg) {                                                                \
    const unsigned short* g = gsrc + (((size_t)(n0 + (seg << 4) + lrow)) << 8) + ((kt) << 5) + (lch << 3); \
    gload_lds16(g, &smem[buf][(w << 12) + (seg << 9)]);                                              \
  }

  STAGE7(0, 0);
  asm volatile("s_waitcnt vmcnt(0)" ::: "memory");
  __builtin_amdgcn_s_barrier();
  __builtin_amdgcn_sched_barrier(0);

  int cur = 0;
  for (int kt = 0; kt < 8; ++kt) {
    if (kt < 7) { STAGE7(cur ^ 1, kt + 1); }
    const unsigned short* sm = &smem[cur][0];
    half8 ah[4], al[4], bh[4], bl[4];
#pragma unroll
    for (int f = 0; f < 4; ++f) {
      int ra = (wy << 6) + (f << 4) + c16;
      int oa = ra * 32 + ((s ^ ((ra >> 1) & 3)) << 3);
      ah[f] = *reinterpret_cast<const half8*>(&sm[oa]);
      al[f] = *reinterpret_cast<const half8*>(&sm[4096 + oa]);
      int rb = (wx << 6) + (f << 4) + c16;
      int ob = rb * 32 + ((s ^ ((rb >> 1) & 3)) << 3);
      bh[f] = *reinterpret_cast<const half8*>(&sm[8192 + ob]);
      bl[f] = *reinterpret_cast<const half8*>(&sm[12288 + ob]);
    }
#pragma unroll
    for (int fi = 0; fi < 4; ++fi)
#pragma unroll
      for (int fj = 0; fj < 4; ++fj) {
        acc_h[fi][fj] = __builtin_amdgcn_mfma_f32_16x16x32_f16(ah[fi], bh[fj], acc_h[fi][fj], 0, 0, 0);
        acc_c[fi][fj] = __builtin_amdgcn_mfma_f32_16x16x32_f16(ah[fi], bl[fj], acc_c[fi][fj], 0, 0, 0);
        acc_c[fi][fj] = __builtin_amdgcn_mfma_f32_16x16x32_f16(al[fi], bh[fj], acc_c[fi][fj], 0, 0, 0);
      }
    asm volatile("s_waitcnt vmcnt(0) lgkmcnt(0)" ::: "memory");
    __builtin_amdgcn_s_barrier();
    __builtin_amdgcn_sched_barrier(0);
    cur ^= 1;
  }
#undef STAGE7
  // per-row argmax: C/D layout col=lane&15, row=(lane>>4)*4+reg
  float* redV = reinterpret_cast<float*>(&smem[0][0]);       // [128][2]
  int* redI = reinterpret_cast<int*>(&smem[0][512]);         // [128][2]
  int g16 = lane >> 4;
#pragma unroll
  for (int fi = 0; fi < 4; ++fi)
#pragma unroll
    for (int r = 0; r < 4; ++r) {
      float bv = -INFINITY; int bi = 0x7fffffff;
#pragma unroll
      for (int fj = 0; fj < 4; ++fj) {
        float v = (acc_h[fi][fj][r] + acc_c[fi][fj][r] * (1.0f / 2048.0f)) * (1.0f / 4096.0f);
        int colg = (mt << 7) + (wx << 6) + (fj << 4) + c16;
        if (v > bv) { bv = v; bi = colg; }
      }
#pragma unroll
      for (int d = 1; d < 16; d <<= 1) {
        float ov = __shfl_xor(bv, d, 64);
        int oi = __shfl_xor(bi, d, 64);
        if (ov > bv || (ov == bv && oi < bi)) { bv = ov; bi = oi; }
      }
      if (c16 == 0) {
        int row = (wy << 6) + (fi << 4) + (g16 << 2) + r;
        redV[row * 2 + wx] = bv;
        redI[row * 2 + wx] = bi;
      }
    }
  __syncthreads();
  if (tid < 128) {
    float v0 = redV[tid * 2], v1 = redV[tid * 2 + 1];
    int i0 = redI[tid * 2], i1 = redI[tid * 2 + 1];
    if (v1 > v0 || (v1 == v0 && i1 < i0)) { v0 = v1; i0 = i1; }
    int n = (nt << 7) + tid;
    partV[(((size_t)n) << 5) + mt] = v0;
    partI[(((size_t)n) << 5) + mt] = i0;
  }
}

// ---------------- K_simL: legacy fp32 sim for b<7, full-row argmax (gated inline; ~never runs) ----
__global__ __launch_bounds__(256) void k_simL(const float* __restrict__ x, const float* __restrict__ mask,
                                              const float* __restrict__ partMax,
                                              const float* __restrict__ fq, const float* __restrict__ fs,
                                              float* __restrict__ wv, int* __restrict__ idxv) {
  int b = blockIdx.y;
  float fore = block_fore(partMax, b);
  if (!(fore > 0.5f) || mask[b << 12] == 0.f) return;  // need==0 for b<7
  int n0 = blockIdx.x << 6;
  int tid = threadIdx.x;
  int tx = tid & 15, ty = tid >> 4;
  int lk = ty, ln4 = tx << 2;

  __shared__ float As[16][68];
  __shared__ float Bs[16][68];
  __shared__ float fqs[64], fss[64];
  __shared__ float rv[64][17];
  __shared__ int ri[64][17];

  if (tid < 64) fqs[tid] = fq[(b << 12) + n0 + tid];

  float bestv[4]; int besti[4];
#pragma unroll
  for (int i = 0; i < 4; ++i) { bestv[i] = -INFINITY; besti[i] = 0; }

  const size_t xb = ((size_t)b * C_) << 12;

  for (int m0 = 0; m0 < N_; m0 += 64) {
    if (tid < 64) fss[tid] = fs[(b << 12) + m0 + tid];
    float cacc[4][4];
#pragma unroll
    for (int i = 0; i < 4; ++i)
#pragma unroll
      for (int j = 0; j < 4; ++j) cacc[i][j] = 0.f;
    __syncthreads();
    for (int kt = 0; kt < C_; kt += 16) {
      float4 va = *reinterpret_cast<const float4*>(x + xb + ((size_t)(kt + lk) << 12) + n0 + ln4);
      float4 vb = *reinterpret_cast<const float4*>(x + xb + ((size_t)(kt + lk) << 12) + m0 + ln4);
      va.x *= fqs[ln4]; va.y *= fqs[ln4 + 1]; va.z *= fqs[ln4 + 2]; va.w *= fqs[ln4 + 3];
      vb.x *= fss[ln4]; vb.y *= fss[ln4 + 1]; vb.z *= fss[ln4 + 2]; vb.w *= fss[ln4 + 3];
      *reinterpret_cast<float4*>(&As[lk][ln4]) = va;
      *reinterpret_cast<float4*>(&Bs[lk][ln4]) = vb;
      __syncthreads();
#pragma unroll
      for (int k = 0; k < 16; ++k) {
        float a0 = As[k][(ty << 2) + 0], a1 = As[k][(ty << 2) + 1], a2 = As[k][(ty << 2) + 2], a3 = As[k][(ty << 2) + 3];
        float b0 = Bs[k][(tx << 2) + 0], b1 = Bs[k][(tx << 2) + 1], b2 = Bs[k][(tx << 2) + 2], b3 = Bs[k][(tx << 2) + 3];
        cacc[0][0] += a0 * b0; cacc[0][1] += a0 * b1; cacc[0][2] += a0 * b2; cacc[0][3] += a0 * b3;
        cacc[1][0] += a1 * b0; cacc[1][1] += a1 * b1; cacc[1][2] += a1 * b2; cacc[1][3] += a1 * b3;
        cacc[2][0] += a2 * b0; cacc[2][1] += a2 * b1; cacc[2][2] += a2 * b2; cacc[2][3] += a2 * b3;
        cacc[3][0] += a3 * b0; cacc[3][1] += a3 * b1; cacc[3][2] += a3 * b2; cacc[3][3] += a3 * b3;
      }
      __syncthreads();
    }
#pragma unroll
    for (int j = 0; j < 4; ++j) {
      int col = m0 + (tx << 2) + j;
#pragma unroll
      for (int i = 0; i < 4; ++i) {
        float v = cacc[i][j];
        if (v > bestv[i]) { bestv[i] = v; besti[i] = col; }  // ascending cols: strict > keeps first
      }
    }
  }
#pragma unroll
  for (int i = 0; i < 4; ++i) { rv[(ty << 2) + i][tx] = bestv[i]; ri[(ty << 2) + i][tx] = besti[i]; }
  __syncthreads();
  if (tid < 64) {
    float bv = rv[tid][0]; int bi = ri[tid][0];
#pragma unroll
    for (int t = 1; t < 16; ++t) {
      float v = rv[tid][t]; int ii = ri[tid][t];
      if (v > bv || (v == bv && ii < bi)) { bv = v; bi = ii; }
    }
    wv[(b << 12) + n0 + tid] = bv;
    idxv[(b << 12) + n0 + tid] = bi;
  }
}

// ---------------- K_red7m: reduce 32 m-tiles for b=7 + mark scatter ----------------
__global__ __launch_bounds__(256) void k_red7m(const float* __restrict__ p7V, const int* __restrict__ p7I,
                                               float* __restrict__ wv, int* __restrict__ idxv,
                                               int* __restrict__ mark) {
  int n = blockIdx.x * 256 + threadIdx.x;
  float bv = -INFINITY; int bi = 0x7fffffff;
#pragma unroll 8
  for (int mtv = 0; mtv < 32; ++mtv) {
    float v = p7V[(((size_t)n) << 5) + mtv];
    int i = p7I[(((size_t)n) << 5) + mtv];
    if (v > bv || (v == bv && i < bi)) { bv = v; bi = i; }
  }
  wv[((B_ - 1) << 12) + n] = bv;
  idxv[((B_ - 1) << 12) + n] = bi;
  mark[bi] = 1;  // benign same-value race
}

// ---------------- K_hybrid: gated 1x1-conv overwrite with inline valid + softmax scalars ----------
__global__ __launch_bounds__(256) void k_hybrid(const float* __restrict__ x, const float* __restrict__ mask,
                                                const float* __restrict__ partMax,
                                                const float* __restrict__ fq, const float* __restrict__ fs,
                                                const float* __restrict__ Wc, const float* __restrict__ bc,
                                                const int* __restrict__ idxv, const float* __restrict__ wv,
                                                float* __restrict__ out) {
  int b = blockIdx.y;
  float fore = block_fore(partMax, b);
  if (!(fore > 0.5f) || mask[b << 12] == 0.f) return;  // valid==0
  int tid = threadIdx.x;
  __shared__ float red[256];
  float mx = -INFINITY;
  for (int n = tid; n < N_; n += 256) mx = fmaxf(mx, wv[(b << 12) + n]);
  red[tid] = mx; __syncthreads();
  for (int s = 128; s; s >>= 1) { if (tid < s) red[tid] = fmaxf(red[tid], red[tid + s]); __syncthreads(); }
  mx = red[0]; __syncthreads();
  float sm = 0.f;
  for (int n = tid; n < N_; n += 256) sm += expf(wv[(b << 12) + n] - mx);
  red[tid] = sm; __syncthreads();
  for (int s = 128; s; s >>= 1) { if (tid < s) red[tid] += red[tid + s]; __syncthreads(); }
  float den = red[0];

  int n = blockIdx.x * 256 + tid;
  int bn = (b << 12) + n;
  float mn = mask[bn];
  if (mn == 0.f) return;  // unmasked positions keep out = x
  int j = idxv[bn];
  float w = expf(wv[bn] - mx) / den;
  float fsj = fs[(b << 12) + j];
  float fqn = fq[bn];
  const float* xb = x + (((size_t)b * C_) << 12);
  for (int o = 0; o < C_; ++o) {
    const float* wr = Wc + o * 2 * C_;
    float a1 = 0.f, a2 = 0.f;
    for (int i = 0; i < C_; ++i) {
      a1 += wr[i] * xb[((size_t)i << 12) + j];
      a2 += wr[C_ + i] * xb[((size_t)i << 12) + n];
    }
    out[((size_t)(b * C_ + o) << 12) + n] = bc[o] + a1 * (fsj * w) + a2 * fqn;
  }
}

// ---------------- K6: attmap nearest x8 upsample (8 px / thread) ----------------
__global__ __launch_bounds__(256) void k_att(const int* __restrict__ mark, float* __restrict__ att) {
  int id = blockIdx.x * 256 + threadIdx.x;  // 262144 threads: 8 b x 512 y x 64 x8-groups
  int x8 = (id & 63) << 3;
  int y = (id >> 6) & 511;
  int b = id >> 15;
  float v = mark[((y >> 3) << 6) + (x8 >> 3)] ? 1.f : 0.f;
  float4 vv = make_float4(v, v, v, v);
  float* p = att + (((size_t)b) << 18) + (y << 9) + x8;
  *reinterpret_cast<float4*>(p) = vv;
  *reinterpret_cast<float4*>(p + 4) = vv;
}

extern "C" void kernel_launch(void* const* d_in, const int* in_sizes, int n_in,
                              void* d_out, int out_size, void* d_ws, size_t ws_size,
                              hipStream_t stream) {
  const float* x = (const float*)d_in[0];
  const float* mask = (const float*)d_in[1];
  const float* Wc = (const float*)d_in[2];
  const float* bc = (const float*)d_in[3];
  float* out = (float*)d_out;
  float* att = out + (size_t)B_ * C_ * N_;

  float* wsf = (float*)d_ws;
  float* fq = wsf;                          // 32768
  float* fs = wsf + 32768;                  // 32768
  float* wv = wsf + 65536;                  // 32768
  int* idxv = (int*)(wsf + 98304);          // 32768 -> ends 131072
  int* mark = (int*)(wsf + 655392);         // 4096 -> ends 659488
  float* partMax = wsf + 659488;            // 512 -> ends 660000
  float* p7V = wsf + 660000;                // 131072 -> ends 791072
  int* p7I = (int*)(wsf + 791072);          // 131072 -> ends 922144
  unsigned short* qhi = (unsigned short*)(wsf + 922144);   // 524288 floats (2MB) each
  unsigned short* qlo = (unsigned short*)(wsf + 1446432);
  unsigned short* shi = (unsigned short*)(wsf + 1970720);
  unsigned short* slo = (unsigned short*)(wsf + 2495008);  // end: 3019296 floats (~11.5MB)

  k_base<<<dim3(64, B_), 512, 0, stream>>>(x, mask, fq, fs, out, partMax, mark, qhi, qlo, shi, slo);
  k_sim7<<<1024, 256, 0, stream>>>(qhi, qlo, shi, slo, p7V, p7I);
  k_simL<<<dim3(64, B_ - 1), 256, 0, stream>>>(x, mask, partMax, fq, fs, wv, idxv);
  k_red7m<<<16, 256, 0, stream>>>(p7V, p7I, wv, idxv, mark);
  k_hybrid<<<dim3(16, B_), 256, 0, stream>>>(x, mask, partMax, fq, fs, Wc, bc, idxv, wv, out);
  k_att<<<1024, 256, 0, stream>>>(mark, att);
}

// Round 8
// 74.693 us; speedup vs baseline: 6.4695x; 1.0132x over previous
//
#include <hip/hip_runtime.h>
#include <cmath>

#define B_ 8
#define C_ 256
#define N_ 4096
#define EPS_ 1e-8f

typedef _Float16 half8 __attribute__((ext_vector_type(8)));
typedef float f32x4 __attribute__((ext_vector_type(4)));
typedef unsigned short ushort8 __attribute__((ext_vector_type(8)));

__device__ __forceinline__ void gload_lds16(const void* g, void* l) {
  __builtin_amdgcn_global_load_lds((const __attribute__((address_space(1))) unsigned int*)g,
                                   (__attribute__((address_space(3))) unsigned int*)l, 16, 0, 0);
}

// Block-uniform need/valid recompute from partMax (64 partials per batch).
__device__ __forceinline__ float block_fore(const float* __restrict__ partMax, int b) {
  int l = threadIdx.x & 63;
  float v = partMax[(b << 6) + l];
#pragma unroll
  for (int d = 32; d; d >>= 1) v = fmaxf(v, __shfl_xor(v, d, 64));
  return v;
}

// ---------------- K_base: fused norms + valid-partial + base output + b=7 fp16 prep + mark zero ----
__global__ __launch_bounds__(512) void k_base(const float* __restrict__ x, const float* __restrict__ mask,
                                              float* __restrict__ fq, float* __restrict__ fs,
                                              float* __restrict__ out, float* __restrict__ partMax,
                                              int* __restrict__ mark,
                                              unsigned short* __restrict__ qhi, unsigned short* __restrict__ qlo,
                                              unsigned short* __restrict__ shi, unsigned short* __restrict__ slo) {
  int b = blockIdx.y, n0 = blockIdx.x << 6;
  int t = threadIdx.x;            // 0..511
  int ln = t & 63, cg = t >> 6;   // 8 groups x 32 channels
  __shared__ float sred[512];
  __shared__ float s0[256];
  __shared__ float rss[8][64], rdp[8][64];
  __shared__ float scaleS[64], f64q[64], f64s[64];
  __shared__ float bcast[2];
  if (b == 0 && blockIdx.x == 0) {
#pragma unroll
    for (int i = 0; i < 8; ++i) mark[t + (i << 9)] = 0;
  }
  const size_t xbase = ((size_t)b * C_) << 12;
  // norm of column 0 (redundant per block; cheap)
  float xc0 = 0.f;
  if (t < 256) xc0 = x[xbase + ((size_t)t << 12)];
  sred[t] = xc0 * xc0;
  __syncthreads();
  for (int s = 256; s; s >>= 1) { if (t < s) sred[t] += sred[t + s]; __syncthreads(); }
  if (t == 0) { bcast[0] = 1.f / (sqrtf(sred[0]) + EPS_); bcast[1] = mask[b << 12]; }
  __syncthreads();
  if (t < 256) s0[t] = xc0 * ((1.f - bcast[1]) * bcast[0]);
  __syncthreads();
  int n = n0 + ln;
  const float* xp = x + xbase + (((size_t)cg) << 17) + n;
  float xv[32];
  float ss = 0.f, dp = 0.f;
#pragma unroll
  for (int c = 0; c < 32; ++c) {
    float v = xp[(size_t)c << 12];
    xv[c] = v;
    ss += v * v;
    dp += v * s0[(cg << 5) + c];
  }
  rss[cg][ln] = ss; rdp[cg][ln] = dp;
  __syncthreads();
  if (t < 64) {
    float sst = 0.f, dpt = 0.f;
#pragma unroll
    for (int g = 0; g < 8; ++g) { sst += rss[g][t]; dpt += rdp[g][t]; }
    float inv = 1.f / (sqrtf(sst) + EPS_);
    float m = mask[(b << 12) + n0 + t];
    float fqv = m * inv;
    fq[(b << 12) + n0 + t] = fqv;
    fs[(b << 12) + n0 + t] = (1.f - m) * inv;
    scaleS[t] = (m != 0.f) ? inv : 1.f;
    f64q[t] = fqv * 64.0f;
    f64s[t] = (1.f - m) * inv * 64.0f;
    // wave-0 shfl max of sim partial
    float val = dpt * fqv;  // masked rows -> exactly 0
#pragma unroll
    for (int d = 32; d; d >>= 1) val = fmaxf(val, __shfl_xor(val, d, 64));
    if (t == 0) partMax[(b << 6) + blockIdx.x] = val;
  }
  __syncthreads();
  float sc = scaleS[ln];
  float* op = out + xbase + (((size_t)cg) << 17) + n;
#pragma unroll
  for (int c = 0; c < 32; ++c) op[(size_t)c << 12] = xv[c] * sc;
  if (b == B_ - 1) {
    // fused prep: scaled (x64) fp16 hi/lo split, transposed, pre-swizzled
    float fqn = f64q[ln], fsn = f64s[ln];
    int swz = (n >> 1) & 3;
    size_t rowbase = ((size_t)n) << 8;  // 256 shorts per row
#pragma unroll
    for (int j = 0; j < 4; ++j) {
      ushort8 vqh, vql, vsh, vsl;
#pragma unroll
      for (int i = 0; i < 8; ++i) {
        float xvv = xv[j * 8 + i];
        float qv = xvv * fqn;
        _Float16 qh = (_Float16)qv;
        _Float16 ql = (_Float16)((qv - (float)qh) * 2048.0f);
        float sv = xvv * fsn;
        _Float16 sh = (_Float16)sv;
        _Float16 sl = (_Float16)((sv - (float)sh) * 2048.0f);
        vqh[i] = __builtin_bit_cast(unsigned short, qh);
        vql[i] = __builtin_bit_cast(unsigned short, ql);
        vsh[i] = __builtin_bit_cast(unsigned short, sh);
        vsl[i] = __builtin_bit_cast(unsigned short, sl);
      }
      size_t off = rowbase + ((size_t)cg << 5) + (size_t)((j ^ swz) << 3);
      *reinterpret_cast<ushort8*>(qhi + off) = vqh;
      *reinterpret_cast<ushort8*>(qlo + off) = vql;
      *reinterpret_cast<ushort8*>(shi + off) = vsh;
      *reinterpret_cast<ushort8*>(slo + off) = vsl;
    }
  }
}

// ---------------- K_sim7: MFMA sim + row argmax for b=7 (2-phase dbuf, super-tile XCD mapping) -----
// Block mapping: each XCD owns 4 nt-rows and walks 8 super-tiles of 4nt x 4mt (16 blocks each).
// Per-XCD concurrent L2 working set ~2.5MB < 4MB -> staged loads are L2 hits.
__global__ __launch_bounds__(256, 2) void k_sim7(const unsigned short* __restrict__ qhi, const unsigned short* __restrict__ qlo,
                                                 const unsigned short* __restrict__ shi, const unsigned short* __restrict__ slo,
                                                 float* __restrict__ partV, int* __restrict__ partI) {
  int bid = blockIdx.x;
  int xcd = bid & 7;
  int r = bid >> 3;               // 0..127
  int scol = r >> 4;              // 0..7 super-col
  int w16 = r & 15;               // 0..15 within 4x4 super-tile
  int nt = (xcd << 2) + (w16 >> 2);
  int mt = (scol << 2) + (w16 & 3);
  int tid = threadIdx.x;
  int w = tid >> 6, lane = tid & 63;
  int wy = w >> 1, wx = w & 1;
  __shared__ __align__(16) unsigned short smem[2][16384];  // 2 x 32KB double buffer

  f32x4 acc_h[4][4], acc_c[4][4];
#pragma unroll
  for (int i = 0; i < 4; ++i)
#pragma unroll
    for (int j = 0; j < 4; ++j) {
      acc_h[i][j] = (f32x4){0.f, 0.f, 0.f, 0.f};
      acc_c[i][j] = (f32x4){0.f, 0.f, 0.f, 0.f};
    }

  const unsigned short* gsrc = (w == 0) ? qhi : (w == 1) ? qlo : (w == 2) ? shi : slo;
  int n0 = ((w < 2) ? nt : mt) << 7;
  int lrow = lane >> 2, lch = lane & 3;
  int s = lane >> 4, c16 = lane & 15;

#define STAGE7(buf, kt)                                                                              \
  _Pragma("unroll")                                                                                  \
  for (int seg = 0; seg < 8; ++seg) {                                                                \
    const unsigned short* g = gsrc + (((size_t)(n0 + (seg << 4) + lrow)) << 8) + ((kt) << 5) + (lch << 3); \
    gload_lds16(g, &smem[buf][(w << 12) + (seg << 9)]);                                              \
  }

  STAGE7(0, 0);
  asm volatile("s_waitcnt vmcnt(0)" ::: "memory");
  __builtin_amdgcn_s_barrier();
  __builtin_amdgcn_sched_barrier(0);

  int cur = 0;
  for (int kt = 0; kt < 8; ++kt) {
    if (kt < 7) { STAGE7(cur ^ 1, kt + 1); }
    const unsigned short* sm = &smem[cur][0];
    half8 ah[4], al[4], bh[4], bl[4];
#pragma unroll
    for (int f = 0; f < 4; ++f) {
      int ra = (wy << 6) + (f << 4) + c16;
      int oa = ra * 32 + ((s ^ ((ra >> 1) & 3)) << 3);
      ah[f] = *reinterpret_cast<const half8*>(&sm[oa]);
      al[f] = *reinterpret_cast<const half8*>(&sm[4096 + oa]);
      int rb = (wx << 6) + (f << 4) + c16;
      int ob = rb * 32 + ((s ^ ((rb >> 1) & 3)) << 3);
      bh[f] = *reinterpret_cast<const half8*>(&sm[8192 + ob]);
      bl[f] = *reinterpret_cast<const half8*>(&sm[12288 + ob]);
    }
#pragma unroll
    for (int fi = 0; fi < 4; ++fi)
#pragma unroll
      for (int fj = 0; fj < 4; ++fj) {
        acc_h[fi][fj] = __builtin_amdgcn_mfma_f32_16x16x32_f16(ah[fi], bh[fj], acc_h[fi][fj], 0, 0, 0);
        acc_c[fi][fj] = __builtin_amdgcn_mfma_f32_16x16x32_f16(ah[fi], bl[fj], acc_c[fi][fj], 0, 0, 0);
        acc_c[fi][fj] = __builtin_amdgcn_mfma_f32_16x16x32_f16(al[fi], bh[fj], acc_c[fi][fj], 0, 0, 0);
      }
    asm volatile("s_waitcnt vmcnt(0) lgkmcnt(0)" ::: "memory");
    __builtin_amdgcn_s_barrier();
    __builtin_amdgcn_sched_barrier(0);
    cur ^= 1;
  }
#undef STAGE7
  // per-row argmax: C/D layout col=lane&15, row=(lane>>4)*4+reg
  float* redV = reinterpret_cast<float*>(&smem[0][0]);       // [128][2]
  int* redI = reinterpret_cast<int*>(&smem[0][512]);         // [128][2]
  int g16 = lane >> 4;
#pragma unroll
  for (int fi = 0; fi < 4; ++fi)
#pragma unroll
    for (int r2 = 0; r2 < 4; ++r2) {
      float bv = -INFINITY; int bi = 0x7fffffff;
#pragma unroll
      for (int fj = 0; fj < 4; ++fj) {
        float v = (acc_h[fi][fj][r2] + acc_c[fi][fj][r2] * (1.0f / 2048.0f)) * (1.0f / 4096.0f);
        int colg = (mt << 7) + (wx << 6) + (fj << 4) + c16;
        if (v > bv) { bv = v; bi = colg; }
      }
#pragma unroll
      for (int d = 1; d < 16; d <<= 1) {
        float ov = __shfl_xor(bv, d, 64);
        int oi = __shfl_xor(bi, d, 64);
        if (ov > bv || (ov == bv && oi < bi)) { bv = ov; bi = oi; }
      }
      if (c16 == 0) {
        int row = (wy << 6) + (fi << 4) + (g16 << 2) + r2;
        redV[row * 2 + wx] = bv;
        redI[row * 2 + wx] = bi;
      }
    }
  __syncthreads();
  if (tid < 128) {
    float v0 = redV[tid * 2], v1 = redV[tid * 2 + 1];
    int i0 = redI[tid * 2], i1 = redI[tid * 2 + 1];
    if (v1 > v0 || (v1 == v0 && i1 < i0)) { v0 = v1; i0 = i1; }
    int n = (nt << 7) + tid;
    partV[(((size_t)n) << 5) + mt] = v0;
    partI[(((size_t)n) << 5) + mt] = i0;
  }
}

// ---------------- K_simL: legacy fp32 sim for b<7, full-row argmax (gated inline; ~never runs) ----
__global__ __launch_bounds__(256) void k_simL(const float* __restrict__ x, const float* __restrict__ mask,
                                              const float* __restrict__ partMax,
                                              const float* __restrict__ fq, const float* __restrict__ fs,
                                              float* __restrict__ wv, int* __restrict__ idxv) {
  int b = blockIdx.y;
  float fore = block_fore(partMax, b);
  if (!(fore > 0.5f) || mask[b << 12] == 0.f) return;  // need==0 for b<7
  int n0 = blockIdx.x << 6;
  int tid = threadIdx.x;
  int tx = tid & 15, ty = tid >> 4;
  int lk = ty, ln4 = tx << 2;

  __shared__ float As[16][68];
  __shared__ float Bs[16][68];
  __shared__ float fqs[64], fss[64];
  __shared__ float rv[64][17];
  __shared__ int ri[64][17];

  if (tid < 64) fqs[tid] = fq[(b << 12) + n0 + tid];

  float bestv[4]; int besti[4];
#pragma unroll
  for (int i = 0; i < 4; ++i) { bestv[i] = -INFINITY; besti[i] = 0; }

  const size_t xb = ((size_t)b * C_) << 12;

  for (int m0 = 0; m0 < N_; m0 += 64) {
    if (tid < 64) fss[tid] = fs[(b << 12) + m0 + tid];
    float cacc[4][4];
#pragma unroll
    for (int i = 0; i < 4; ++i)
#pragma unroll
      for (int j = 0; j < 4; ++j) cacc[i][j] = 0.f;
    __syncthreads();
    for (int kt = 0; kt < C_; kt += 16) {
      float4 va = *reinterpret_cast<const float4*>(x + xb + ((size_t)(kt + lk) << 12) + n0 + ln4);
      float4 vb = *reinterpret_cast<const float4*>(x + xb + ((size_t)(kt + lk) << 12) + m0 + ln4);
      va.x *= fqs[ln4]; va.y *= fqs[ln4 + 1]; va.z *= fqs[ln4 + 2]; va.w *= fqs[ln4 + 3];
      vb.x *= fss[ln4]; vb.y *= fss[ln4 + 1]; vb.z *= fss[ln4 + 2]; vb.w *= fss[ln4 + 3];
      *reinterpret_cast<float4*>(&As[lk][ln4]) = va;
      *reinterpret_cast<float4*>(&Bs[lk][ln4]) = vb;
      __syncthreads();
#pragma unroll
      for (int k = 0; k < 16; ++k) {
        float a0 = As[k][(ty << 2) + 0], a1 = As[k][(ty << 2) + 1], a2 = As[k][(ty << 2) + 2], a3 = As[k][(ty << 2) + 3];
        float b0 = Bs[k][(tx << 2) + 0], b1 = Bs[k][(tx << 2) + 1], b2 = Bs[k][(tx << 2) + 2], b3 = Bs[k][(tx << 2) + 3];
        cacc[0][0] += a0 * b0; cacc[0][1] += a0 * b1; cacc[0][2] += a0 * b2; cacc[0][3] += a0 * b3;
        cacc[1][0] += a1 * b0; cacc[1][1] += a1 * b1; cacc[1][2] += a1 * b2; cacc[1][3] += a1 * b3;
        cacc[2][0] += a2 * b0; cacc[2][1] += a2 * b1; cacc[2][2] += a2 * b2; cacc[2][3] += a2 * b3;
        cacc[3][0] += a3 * b0; cacc[3][1] += a3 * b1; cacc[3][2] += a3 * b2; cacc[3][3] += a3 * b3;
      }
      __syncthreads();
    }
#pragma unroll
    for (int j = 0; j < 4; ++j) {
      int col = m0 + (tx << 2) + j;
#pragma unroll
      for (int i = 0; i < 4; ++i) {
        float v = cacc[i][j];
        if (v > bestv[i]) { bestv[i] = v; besti[i] = col; }  // ascending cols: strict > keeps first
      }
    }
  }
#pragma unroll
  for (int i = 0; i < 4; ++i) { rv[(ty << 2) + i][tx] = bestv[i]; ri[(ty << 2) + i][tx] = besti[i]; }
  __syncthreads();
  if (tid < 64) {
    float bv = rv[tid][0]; int bi = ri[tid][0];
#pragma unroll
    for (int t = 1; t < 16; ++t) {
      float v = rv[tid][t]; int ii = ri[tid][t];
      if (v > bv || (v == bv && ii < bi)) { bv = v; bi = ii; }
    }
    wv[(b << 12) + n0 + tid] = bv;
    idxv[(b << 12) + n0 + tid] = bi;
  }
}

// ---------------- K_red7m: reduce 32 m-tiles for b=7 + mark scatter ----------------
__global__ __launch_bounds__(256) void k_red7m(const float* __restrict__ p7V, const int* __restrict__ p7I,
                                               float* __restrict__ wv, int* __restrict__ idxv,
                                               int* __restrict__ mark) {
  int n = blockIdx.x * 256 + threadIdx.x;
  float bv = -INFINITY; int bi = 0x7fffffff;
#pragma unroll 8
  for (int mtv = 0; mtv < 32; ++mtv) {
    float v = p7V[(((size_t)n) << 5) + mtv];
    int i = p7I[(((size_t)n) << 5) + mtv];
    if (v > bv || (v == bv && i < bi)) { bv = v; bi = i; }
  }
  wv[((B_ - 1) << 12) + n] = bv;
  idxv[((B_ - 1) << 12) + n] = bi;
  mark[bi] = 1;  // benign same-value race
}

// ---------------- K_hybrid: gated 1x1-conv overwrite with inline valid + softmax scalars ----------
__global__ __launch_bounds__(256) void k_hybrid(const float* __restrict__ x, const float* __restrict__ mask,
                                                const float* __restrict__ partMax,
                                                const float* __restrict__ fq, const float* __restrict__ fs,
                                                const float* __restrict__ Wc, const float* __restrict__ bc,
                                                const int* __restrict__ idxv, const float* __restrict__ wv,
                                                float* __restrict__ out) {
  int b = blockIdx.y;
  float fore = block_fore(partMax, b);
  if (!(fore > 0.5f) || mask[b << 12] == 0.f) return;  // valid==0
  int tid = threadIdx.x;
  __shared__ float red[256];
  float mx = -INFINITY;
  for (int n = tid; n < N_; n += 256) mx = fmaxf(mx, wv[(b << 12) + n]);
  red[tid] = mx; __syncthreads();
  for (int s = 128; s; s >>= 1) { if (tid < s) red[tid] = fmaxf(red[tid], red[tid + s]); __syncthreads(); }
  mx = red[0]; __syncthreads();
  float sm = 0.f;
  for (int n = tid; n < N_; n += 256) sm += expf(wv[(b << 12) + n] - mx);
  red[tid] = sm; __syncthreads();
  for (int s = 128; s; s >>= 1) { if (tid < s) red[tid] += red[tid + s]; __syncthreads(); }
  float den = red[0];

  int n = blockIdx.x * 256 + tid;
  int bn = (b << 12) + n;
  float mn = mask[bn];
  if (mn == 0.f) return;  // unmasked positions keep out = x
  int j = idxv[bn];
  float w = expf(wv[bn] - mx) / den;
  float fsj = fs[(b << 12) + j];
  float fqn = fq[bn];
  const float* xb = x + (((size_t)b * C_) << 12);
  for (int o = 0; o < C_; ++o) {
    const float* wr = Wc + o * 2 * C_;
    float a1 = 0.f, a2 = 0.f;
    for (int i = 0; i < C_; ++i) {
      a1 += wr[i] * xb[((size_t)i << 12) + j];
      a2 += wr[C_ + i] * xb[((size_t)i << 12) + n];
    }
    out[((size_t)(b * C_ + o) << 12) + n] = bc[o] + a1 * (fsj * w) + a2 * fqn;
  }
}

// ---------------- K6: attmap nearest x8 upsample (8 px / thread) ----------------
__global__ __launch_bounds__(256) void k_att(const int* __restrict__ mark, float* __restrict__ att) {
  int id = blockIdx.x * 256 + threadIdx.x;  // 262144 threads: 8 b x 512 y x 64 x8-groups
  int x8 = (id & 63) << 3;
  int y = (id >> 6) & 511;
  int b = id >> 15;
  float v = mark[((y >> 3) << 6) + (x8 >> 3)] ? 1.f : 0.f;
  float4 vv = make_float4(v, v, v, v);
  float* p = att + (((size_t)b) << 18) + (y << 9) + x8;
  *reinterpret_cast<float4*>(p) = vv;
  *reinterpret_cast<float4*>(p + 4) = vv;
}

extern "C" void kernel_launch(void* const* d_in, const int* in_sizes, int n_in,
                              void* d_out, int out_size, void* d_ws, size_t ws_size,
                              hipStream_t stream) {
  const float* x = (const float*)d_in[0];
  const float* mask = (const float*)d_in[1];
  const float* Wc = (const float*)d_in[2];
  const float* bc = (const float*)d_in[3];
  float* out = (float*)d_out;
  float* att = out + (size_t)B_ * C_ * N_;

  float* wsf = (float*)d_ws;
  float* fq = wsf;                          // 32768
  float* fs = wsf + 32768;                  // 32768
  float* wv = wsf + 65536;                  // 32768
  int* idxv = (int*)(wsf + 98304);          // 32768 -> ends 131072
  int* mark = (int*)(wsf + 655392);         // 4096 -> ends 659488
  float* partMax = wsf + 659488;            // 512 -> ends 660000
  float* p7V = wsf + 660000;                // 131072 -> ends 791072
  int* p7I = (int*)(wsf + 791072);          // 131072 -> ends 922144
  unsigned short* qhi = (unsigned short*)(wsf + 922144);   // 524288 floats (2MB) each
  unsigned short* qlo = (unsigned short*)(wsf + 1446432);
  unsigned short* shi = (unsigned short*)(wsf + 1970720);
  unsigned short* slo = (unsigned short*)(wsf + 2495008);  // end: 3019296 floats (~11.5MB)

  k_base<<<dim3(64, B_), 512, 0, stream>>>(x, mask, fq, fs, out, partMax, mark, qhi, qlo, shi, slo);
  k_sim7<<<1024, 256, 0, stream>>>(qhi, qlo, shi, slo, p7V, p7I);
  k_simL<<<dim3(64, B_ - 1), 256, 0, stream>>>(x, mask, partMax, fq, fs, wv, idxv);
  k_red7m<<<16, 256, 0, stream>>>(p7V, p7I, wv, idxv, mark);
  k_hybrid<<<dim3(16, B_), 256, 0, stream>>>(x, mask, partMax, fq, fs, Wc, bc, idxv, wv, out);
  k_att<<<1024, 256, 0, stream>>>(mark, att);
}

// Round 9
// 74.559 us; speedup vs baseline: 6.4811x; 1.0018x over previous
//
#include <hip/hip_runtime.h>
#include <cmath>

#define B_ 8
#define C_ 256
#define N_ 4096
#define EPS_ 1e-8f

typedef _Float16 half8 __attribute__((ext_vector_type(8)));
typedef float f32x4 __attribute__((ext_vector_type(4)));
typedef unsigned short ushort8 __attribute__((ext_vector_type(8)));

__device__ __forceinline__ void gload_lds16(const void* g, void* l) {
  __builtin_amdgcn_global_load_lds((const __attribute__((address_space(1))) unsigned int*)g,
                                   (__attribute__((address_space(3))) unsigned int*)l, 16, 0, 0);
}

// Block-uniform need/valid recompute from partMax (64 partials per batch).
__device__ __forceinline__ float block_fore(const float* __restrict__ partMax, int b) {
  int l = threadIdx.x & 63;
  float v = partMax[(b << 6) + l];
#pragma unroll
  for (int d = 32; d; d >>= 1) v = fmaxf(v, __shfl_xor(v, d, 64));
  return v;
}

// ---------------- K_base: fused norms + valid-partial + base output + b=7 fp16 prep + mark zero ----
__global__ __launch_bounds__(512) void k_base(const float* __restrict__ x, const float* __restrict__ mask,
                                              float* __restrict__ fq, float* __restrict__ fs,
                                              float* __restrict__ out, float* __restrict__ partMax,
                                              int* __restrict__ mark,
                                              unsigned short* __restrict__ qhi, unsigned short* __restrict__ qlo,
                                              unsigned short* __restrict__ shi, unsigned short* __restrict__ slo) {
  int b = blockIdx.y, n0 = blockIdx.x << 6;
  int t = threadIdx.x;            // 0..511
  int ln = t & 63, cg = t >> 6;   // 8 groups x 32 channels
  __shared__ float sred[512];
  __shared__ float s0[256];
  __shared__ float rss[8][64], rdp[8][64];
  __shared__ float scaleS[64], f64q[64], f64s[64];
  __shared__ float bcast[2];
  if (b == 0 && blockIdx.x == 0) {
#pragma unroll
    for (int i = 0; i < 8; ++i) mark[t + (i << 9)] = 0;
  }
  const size_t xbase = ((size_t)b * C_) << 12;
  // norm of column 0 (redundant per block; cheap)
  float xc0 = 0.f;
  if (t < 256) xc0 = x[xbase + ((size_t)t << 12)];
  sred[t] = xc0 * xc0;
  __syncthreads();
  for (int s = 256; s; s >>= 1) { if (t < s) sred[t] += sred[t + s]; __syncthreads(); }
  if (t == 0) { bcast[0] = 1.f / (sqrtf(sred[0]) + EPS_); bcast[1] = mask[b << 12]; }
  __syncthreads();
  if (t < 256) s0[t] = xc0 * ((1.f - bcast[1]) * bcast[0]);
  __syncthreads();
  int n = n0 + ln;
  const float* xp = x + xbase + (((size_t)cg) << 17) + n;
  float xv[32];
  float ss = 0.f, dp = 0.f;
#pragma unroll
  for (int c = 0; c < 32; ++c) {
    float v = xp[(size_t)c << 12];
    xv[c] = v;
    ss += v * v;
    dp += v * s0[(cg << 5) + c];
  }
  rss[cg][ln] = ss; rdp[cg][ln] = dp;
  __syncthreads();
  if (t < 64) {
    float sst = 0.f, dpt = 0.f;
#pragma unroll
    for (int g = 0; g < 8; ++g) { sst += rss[g][t]; dpt += rdp[g][t]; }
    float inv = 1.f / (sqrtf(sst) + EPS_);
    float m = mask[(b << 12) + n0 + t];
    float fqv = m * inv;
    fq[(b << 12) + n0 + t] = fqv;
    fs[(b << 12) + n0 + t] = (1.f - m) * inv;
    scaleS[t] = (m != 0.f) ? inv : 1.f;
    f64q[t] = fqv * 64.0f;
    f64s[t] = (1.f - m) * inv * 64.0f;
    // wave-0 shfl max of sim partial
    float val = dpt * fqv;  // masked rows -> exactly 0
#pragma unroll
    for (int d = 32; d; d >>= 1) val = fmaxf(val, __shfl_xor(val, d, 64));
    if (t == 0) partMax[(b << 6) + blockIdx.x] = val;
  }
  __syncthreads();
  float sc = scaleS[ln];
  float* op = out + xbase + (((size_t)cg) << 17) + n;
#pragma unroll
  for (int c = 0; c < 32; ++c) op[(size_t)c << 12] = xv[c] * sc;
  if (b == B_ - 1) {
    // fused prep: scaled (x64) fp16 hi/lo split, transposed, pre-swizzled
    float fqn = f64q[ln], fsn = f64s[ln];
    int swz = (n >> 1) & 3;
    size_t rowbase = ((size_t)n) << 8;  // 256 shorts per row
#pragma unroll
    for (int j = 0; j < 4; ++j) {
      ushort8 vqh, vql, vsh, vsl;
#pragma unroll
      for (int i = 0; i < 8; ++i) {
        float xvv = xv[j * 8 + i];
        float qv = xvv * fqn;
        _Float16 qh = (_Float16)qv;
        _Float16 ql = (_Float16)((qv - (float)qh) * 2048.0f);
        float sv = xvv * fsn;
        _Float16 sh = (_Float16)sv;
        _Float16 sl = (_Float16)((sv - (float)sh) * 2048.0f);
        vqh[i] = __builtin_bit_cast(unsigned short, qh);
        vql[i] = __builtin_bit_cast(unsigned short, ql);
        vsh[i] = __builtin_bit_cast(unsigned short, sh);
        vsl[i] = __builtin_bit_cast(unsigned short, sl);
      }
      size_t off = rowbase + ((size_t)cg << 5) + (size_t)((j ^ swz) << 3);
      *reinterpret_cast<ushort8*>(qhi + off) = vqh;
      *reinterpret_cast<ushort8*>(qlo + off) = vql;
      *reinterpret_cast<ushort8*>(shi + off) = vsh;
      *reinterpret_cast<ushort8*>(slo + off) = vsl;
    }
  }
}

// ---------------- K_sim7: MFMA sim + row argmax for b=7 (counted-vmcnt 2-phase pipeline) ----------
// Per kt: STAGE(next) -> vmcnt(8) [own prev-buffer loads retired] -> barrier [all waves' cur ready]
//         -> ds_read+MFMA on cur -> lgkmcnt(0) -> barrier [cur free to overwrite]. No in-loop drain.
__global__ __launch_bounds__(256, 2) void k_sim7(const unsigned short* __restrict__ qhi, const unsigned short* __restrict__ qlo,
                                                 const unsigned short* __restrict__ shi, const unsigned short* __restrict__ slo,
                                                 float* __restrict__ partV, int* __restrict__ partI) {
  int bid = blockIdx.x;
  int xcd = bid & 7;
  int r = bid >> 3;               // 0..127
  int scol = r >> 4;              // 0..7 super-col
  int w16 = r & 15;               // 0..15 within 4x4 super-tile
  int nt = (xcd << 2) + (w16 >> 2);
  int mt = (scol << 2) + (w16 & 3);
  int tid = threadIdx.x;
  int w = tid >> 6, lane = tid & 63;
  int wy = w >> 1, wx = w & 1;
  __shared__ __align__(16) unsigned short smem[2][16384];  // 2 x 32KB double buffer

  f32x4 acc_h[4][4], acc_c[4][4];
#pragma unroll
  for (int i = 0; i < 4; ++i)
#pragma unroll
    for (int j = 0; j < 4; ++j) {
      acc_h[i][j] = (f32x4){0.f, 0.f, 0.f, 0.f};
      acc_c[i][j] = (f32x4){0.f, 0.f, 0.f, 0.f};
    }

  const unsigned short* gsrc = (w == 0) ? qhi : (w == 1) ? qlo : (w == 2) ? shi : slo;
  int n0 = ((w < 2) ? nt : mt) << 7;
  int lrow = lane >> 2, lch = lane & 3;
  int s = lane >> 4, c16 = lane & 15;

#define STAGE7(buf, kt)                                                                              \
  _Pragma("unroll")                                                                                  \
  for (int seg = 0; seg < 8; ++seg) {                                                                \
    const unsigned short* g = gsrc + (((size_t)(n0 + (seg << 4) + lrow)) << 8) + ((kt) << 5) + (lch << 3); \
    gload_lds16(g, &smem[buf][(w << 12) + (seg << 9)]);                                              \
  }

  STAGE7(0, 0);

  int cur = 0;
  for (int kt = 0; kt < 8; ++kt) {
    if (kt < 7) {
      STAGE7(cur ^ 1, kt + 1);
      asm volatile("s_waitcnt vmcnt(8)" ::: "memory");   // own cur-buffer loads (oldest 8) retired
    } else {
      asm volatile("s_waitcnt vmcnt(0)" ::: "memory");   // final tile: full drain once
    }
    __builtin_amdgcn_s_barrier();                        // all waves' cur-buffer loads retired
    __builtin_amdgcn_sched_barrier(0);
    const unsigned short* sm = &smem[cur][0];
    half8 ah[4], al[4], bh[4], bl[4];
#pragma unroll
    for (int f = 0; f < 4; ++f) {
      int ra = (wy << 6) + (f << 4) + c16;
      int oa = ra * 32 + ((s ^ ((ra >> 1) & 3)) << 3);
      ah[f] = *reinterpret_cast<const half8*>(&sm[oa]);
      al[f] = *reinterpret_cast<const half8*>(&sm[4096 + oa]);
      int rb = (wx << 6) + (f << 4) + c16;
      int ob = rb * 32 + ((s ^ ((rb >> 1) & 3)) << 3);
      bh[f] = *reinterpret_cast<const half8*>(&sm[8192 + ob]);
      bl[f] = *reinterpret_cast<const half8*>(&sm[12288 + ob]);
    }
#pragma unroll
    for (int fi = 0; fi < 4; ++fi)
#pragma unroll
      for (int fj = 0; fj < 4; ++fj) {
        acc_h[fi][fj] = __builtin_amdgcn_mfma_f32_16x16x32_f16(ah[fi], bh[fj], acc_h[fi][fj], 0, 0, 0);
        acc_c[fi][fj] = __builtin_amdgcn_mfma_f32_16x16x32_f16(ah[fi], bl[fj], acc_c[fi][fj], 0, 0, 0);
        acc_c[fi][fj] = __builtin_amdgcn_mfma_f32_16x16x32_f16(al[fi], bh[fj], acc_c[fi][fj], 0, 0, 0);
      }
    asm volatile("s_waitcnt lgkmcnt(0)" ::: "memory");   // reads of cur landed in registers
    __builtin_amdgcn_s_barrier();                        // cur free for next STAGE overwrite
    __builtin_amdgcn_sched_barrier(0);
    cur ^= 1;
  }
#undef STAGE7
  // per-row argmax: C/D layout col=lane&15, row=(lane>>4)*4+reg
  float* redV = reinterpret_cast<float*>(&smem[0][0]);       // [128][2]
  int* redI = reinterpret_cast<int*>(&smem[0][512]);         // [128][2]
  int g16 = lane >> 4;
#pragma unroll
  for (int fi = 0; fi < 4; ++fi)
#pragma unroll
    for (int r2 = 0; r2 < 4; ++r2) {
      float bv = -INFINITY; int bi = 0x7fffffff;
#pragma unroll
      for (int fj = 0; fj < 4; ++fj) {
        float v = (acc_h[fi][fj][r2] + acc_c[fi][fj][r2] * (1.0f / 2048.0f)) * (1.0f / 4096.0f);
        int colg = (mt << 7) + (wx << 6) + (fj << 4) + c16;
        if (v > bv) { bv = v; bi = colg; }
      }
#pragma unroll
      for (int d = 1; d < 16; d <<= 1) {
        float ov = __shfl_xor(bv, d, 64);
        int oi = __shfl_xor(bi, d, 64);
        if (ov > bv || (ov == bv && oi < bi)) { bv = ov; bi = oi; }
      }
      if (c16 == 0) {
        int row = (wy << 6) + (fi << 4) + (g16 << 2) + r2;
        redV[row * 2 + wx] = bv;
        redI[row * 2 + wx] = bi;
      }
    }
  __syncthreads();
  if (tid < 128) {
    float v0 = redV[tid * 2], v1 = redV[tid * 2 + 1];
    int i0 = redI[tid * 2], i1 = redI[tid * 2 + 1];
    if (v1 > v0 || (v1 == v0 && i1 < i0)) { v0 = v1; i0 = i1; }
    int n = (nt << 7) + tid;
    partV[(((size_t)n) << 5) + mt] = v0;
    partI[(((size_t)n) << 5) + mt] = i0;
  }
}

// ---------------- K_simL: legacy fp32 sim for b<7, full-row argmax (gated inline; ~never runs) ----
__global__ __launch_bounds__(256) void k_simL(const float* __restrict__ x, const float* __restrict__ mask,
                                              const float* __restrict__ partMax,
                                              const float* __restrict__ fq, const float* __restrict__ fs,
                                              float* __restrict__ wv, int* __restrict__ idxv) {
  int b = blockIdx.y;
  float fore = block_fore(partMax, b);
  if (!(fore > 0.5f) || mask[b << 12] == 0.f) return;  // need==0 for b<7
  int n0 = blockIdx.x << 6;
  int tid = threadIdx.x;
  int tx = tid & 15, ty = tid >> 4;
  int lk = ty, ln4 = tx << 2;

  __shared__ float As[16][68];
  __shared__ float Bs[16][68];
  __shared__ float fqs[64], fss[64];
  __shared__ float rv[64][17];
  __shared__ int ri[64][17];

  if (tid < 64) fqs[tid] = fq[(b << 12) + n0 + tid];

  float bestv[4]; int besti[4];
#pragma unroll
  for (int i = 0; i < 4; ++i) { bestv[i] = -INFINITY; besti[i] = 0; }

  const size_t xb = ((size_t)b * C_) << 12;

  for (int m0 = 0; m0 < N_; m0 += 64) {
    if (tid < 64) fss[tid] = fs[(b << 12) + m0 + tid];
    float cacc[4][4];
#pragma unroll
    for (int i = 0; i < 4; ++i)
#pragma unroll
      for (int j = 0; j < 4; ++j) cacc[i][j] = 0.f;
    __syncthreads();
    for (int kt = 0; kt < C_; kt += 16) {
      float4 va = *reinterpret_cast<const float4*>(x + xb + ((size_t)(kt + lk) << 12) + n0 + ln4);
      float4 vb = *reinterpret_cast<const float4*>(x + xb + ((size_t)(kt + lk) << 12) + m0 + ln4);
      va.x *= fqs[ln4]; va.y *= fqs[ln4 + 1]; va.z *= fqs[ln4 + 2]; va.w *= fqs[ln4 + 3];
      vb.x *= fss[ln4]; vb.y *= fss[ln4 + 1]; vb.z *= fss[ln4 + 2]; vb.w *= fss[ln4 + 3];
      *reinterpret_cast<float4*>(&As[lk][ln4]) = va;
      *reinterpret_cast<float4*>(&Bs[lk][ln4]) = vb;
      __syncthreads();
#pragma unroll
      for (int k = 0; k < 16; ++k) {
        float a0 = As[k][(ty << 2) + 0], a1 = As[k][(ty << 2) + 1], a2 = As[k][(ty << 2) + 2], a3 = As[k][(ty << 2) + 3];
        float b0 = Bs[k][(tx << 2) + 0], b1 = Bs[k][(tx << 2) + 1], b2 = Bs[k][(tx << 2) + 2], b3 = Bs[k][(tx << 2) + 3];
        cacc[0][0] += a0 * b0; cacc[0][1] += a0 * b1; cacc[0][2] += a0 * b2; cacc[0][3] += a0 * b3;
        cacc[1][0] += a1 * b0; cacc[1][1] += a1 * b1; cacc[1][2] += a1 * b2; cacc[1][3] += a1 * b3;
        cacc[2][0] += a2 * b0; cacc[2][1] += a2 * b1; cacc[2][2] += a2 * b2; cacc[2][3] += a2 * b3;
        cacc[3][0] += a3 * b0; cacc[3][1] += a3 * b1; cacc[3][2] += a3 * b2; cacc[3][3] += a3 * b3;
      }
      __syncthreads();
    }
#pragma unroll
    for (int j = 0; j < 4; ++j) {
      int col = m0 + (tx << 2) + j;
#pragma unroll
      for (int i = 0; i < 4; ++i) {
        float v = cacc[i][j];
        if (v > bestv[i]) { bestv[i] = v; besti[i] = col; }  // ascending cols: strict > keeps first
      }
    }
  }
#pragma unroll
  for (int i = 0; i < 4; ++i) { rv[(ty << 2) + i][tx] = bestv[i]; ri[(ty << 2) + i][tx] = besti[i]; }
  __syncthreads();
  if (tid < 64) {
    float bv = rv[tid][0]; int bi = ri[tid][0];
#pragma unroll
    for (int t = 1; t < 16; ++t) {
      float v = rv[tid][t]; int ii = ri[tid][t];
      if (v > bv || (v == bv && ii < bi)) { bv = v; bi = ii; }
    }
    wv[(b << 12) + n0 + tid] = bv;
    idxv[(b << 12) + n0 + tid] = bi;
  }
}

// ---------------- K_red7m: reduce 32 m-tiles for b=7 + mark scatter ----------------
__global__ __launch_bounds__(256) void k_red7m(const float* __restrict__ p7V, const int* __restrict__ p7I,
                                               float* __restrict__ wv, int* __restrict__ idxv,
                                               int* __restrict__ mark) {
  int n = blockIdx.x * 256 + threadIdx.x;
  float bv = -INFINITY; int bi = 0x7fffffff;
#pragma unroll 8
  for (int mtv = 0; mtv < 32; ++mtv) {
    float v = p7V[(((size_t)n) << 5) + mtv];
    int i = p7I[(((size_t)n) << 5) + mtv];
    if (v > bv || (v == bv && i < bi)) { bv = v; bi = i; }
  }
  wv[((B_ - 1) << 12) + n] = bv;
  idxv[((B_ - 1) << 12) + n] = bi;
  mark[bi] = 1;  // benign same-value race
}

// ---------------- K_hybrid: gated 1x1-conv overwrite with inline valid + softmax scalars ----------
__global__ __launch_bounds__(256) void k_hybrid(const float* __restrict__ x, const float* __restrict__ mask,
                                                const float* __restrict__ partMax,
                                                const float* __restrict__ fq, const float* __restrict__ fs,
                                                const float* __restrict__ Wc, const float* __restrict__ bc,
                                                const int* __restrict__ idxv, const float* __restrict__ wv,
                                                float* __restrict__ out) {
  int b = blockIdx.y;
  float fore = block_fore(partMax, b);
  if (!(fore > 0.5f) || mask[b << 12] == 0.f) return;  // valid==0
  int tid = threadIdx.x;
  __shared__ float red[256];
  float mx = -INFINITY;
  for (int n = tid; n < N_; n += 256) mx = fmaxf(mx, wv[(b << 12) + n]);
  red[tid] = mx; __syncthreads();
  for (int s = 128; s; s >>= 1) { if (tid < s) red[tid] = fmaxf(red[tid], red[tid + s]); __syncthreads(); }
  mx = red[0]; __syncthreads();
  float sm = 0.f;
  for (int n = tid; n < N_; n += 256) sm += expf(wv[(b << 12) + n] - mx);
  red[tid] = sm; __syncthreads();
  for (int s = 128; s; s >>= 1) { if (tid < s) red[tid] += red[tid + s]; __syncthreads(); }
  float den = red[0];

  int n = blockIdx.x * 256 + tid;
  int bn = (b << 12) + n;
  float mn = mask[bn];
  if (mn == 0.f) return;  // unmasked positions keep out = x
  int j = idxv[bn];
  float w = expf(wv[bn] - mx) / den;
  float fsj = fs[(b << 12) + j];
  float fqn = fq[bn];
  const float* xb = x + (((size_t)b * C_) << 12);
  for (int o = 0; o < C_; ++o) {
    const float* wr = Wc + o * 2 * C_;
    float a1 = 0.f, a2 = 0.f;
    for (int i = 0; i < C_; ++i) {
      a1 += wr[i] * xb[((size_t)i << 12) + j];
      a2 += wr[C_ + i] * xb[((size_t)i << 12) + n];
    }
    out[((size_t)(b * C_ + o) << 12) + n] = bc[o] + a1 * (fsj * w) + a2 * fqn;
  }
}

// ---------------- K6: attmap nearest x8 upsample (8 px / thread) ----------------
__global__ __launch_bounds__(256) void k_att(const int* __restrict__ mark, float* __restrict__ att) {
  int id = blockIdx.x * 256 + threadIdx.x;  // 262144 threads: 8 b x 512 y x 64 x8-groups
  int x8 = (id & 63) << 3;
  int y = (id >> 6) & 511;
  int b = id >> 15;
  float v = mark[((y >> 3) << 6) + (x8 >> 3)] ? 1.f : 0.f;
  float4 vv = make_float4(v, v, v, v);
  float* p = att + (((size_t)b) << 18) + (y << 9) + x8;
  *reinterpret_cast<float4*>(p) = vv;
  *reinterpret_cast<float4*>(p + 4) = vv;
}

extern "C" void kernel_launch(void* const* d_in, const int* in_sizes, int n_in,
                              void* d_out, int out_size, void* d_ws, size_t ws_size,
                              hipStream_t stream) {
  const float* x = (const float*)d_in[0];
  const float* mask = (const float*)d_in[1];
  const float* Wc = (const float*)d_in[2];
  const float* bc = (const float*)d_in[3];
  float* out = (float*)d_out;
  float* att = out + (size_t)B_ * C_ * N_;

  float* wsf = (float*)d_ws;
  float* fq = wsf;                          // 32768
  float* fs = wsf + 32768;                  // 32768
  float* wv = wsf + 65536;                  // 32768
  int* idxv = (int*)(wsf + 98304);          // 32768 -> ends 131072
  int* mark = (int*)(wsf + 655392);         // 4096 -> ends 659488
  float* partMax = wsf + 659488;            // 512 -> ends 660000
  float* p7V = wsf + 660000;                // 131072 -> ends 791072
  int* p7I = (int*)(wsf + 791072);          // 131072 -> ends 922144
  unsigned short* qhi = (unsigned short*)(wsf + 922144);   // 524288 floats (2MB) each
  unsigned short* qlo = (unsigned short*)(wsf + 1446432);
  unsigned short* shi = (unsigned short*)(wsf + 1970720);
  unsigned short* slo = (unsigned short*)(wsf + 2495008);  // end: 3019296 floats (~11.5MB)

  k_base<<<dim3(64, B_), 512, 0, stream>>>(x, mask, fq, fs, out, partMax, mark, qhi, qlo, shi, slo);
  k_sim7<<<1024, 256, 0, stream>>>(qhi, qlo, shi, slo, p7V, p7I);
  k_simL<<<dim3(64, B_ - 1), 256, 0, stream>>>(x, mask, partMax, fq, fs, wv, idxv);
  k_red7m<<<16, 256, 0, stream>>>(p7V, p7I, wv, idxv, mark);
  k_hybrid<<<dim3(16, B_), 256, 0, stream>>>(x, mask, partMax, fq, fs, Wc, bc, idxv, wv, out);
  k_att<<<1024, 256, 0, stream>>>(mark, att);
}

// Round 10
// 71.944 us; speedup vs baseline: 6.7168x; 1.0364x over previous
//
#include <hip/hip_runtime.h>
#include <cmath>

#define B_ 8
#define C_ 256
#define N_ 4096
#define EPS_ 1e-8f

typedef _Float16 half8 __attribute__((ext_vector_type(8)));
typedef float f32x4 __attribute__((ext_vector_type(4)));
typedef unsigned short ushort8 __attribute__((ext_vector_type(8)));

__device__ __forceinline__ void gload_lds16(const void* g, void* l) {
  __builtin_amdgcn_global_load_lds((const __attribute__((address_space(1))) unsigned int*)g,
                                   (__attribute__((address_space(3))) unsigned int*)l, 16, 0, 0);
}

// Block-uniform need/valid recompute from partMax (64 partials per batch).
__device__ __forceinline__ float block_fore(const float* __restrict__ partMax, int b) {
  int l = threadIdx.x & 63;
  float v = partMax[(b << 6) + l];
#pragma unroll
  for (int d = 32; d; d >>= 1) v = fmaxf(v, __shfl_xor(v, d, 64));
  return v;
}

// ---------------- K_cmp7: stable compaction of b=7 active q-rows (m=1) and s-cols (m=0) ----------
__global__ __launch_bounds__(1024) void k_cmp7(const float* __restrict__ mask,
                                               int* __restrict__ rowsrc, int* __restrict__ rowrank,
                                               int* __restrict__ colsrc, int* __restrict__ colmapG,
                                               int* __restrict__ cnt) {
  int t = threadIdx.x;
#pragma unroll
  for (int i = 0; i < 4; ++i) {
    rowsrc[t + (i << 10)] = 0;
    colsrc[t + (i << 10)] = 0;
    colmapG[t + (i << 10)] = 0x3fffffff;  // tail slots: huge but monotone col index
  }
  __syncthreads();
  int n0 = t << 2;
  int f[4]; int pk = 0;
#pragma unroll
  for (int i = 0; i < 4; ++i) {
    int m = (mask[(7 << 12) + n0 + i] != 0.f) ? 1 : 0;
    f[i] = m;
    pk += m ? 1 : (1 << 16);  // low 16: row count (m=1), high 16: col count (m=0)
  }
  int incl = pk;
#pragma unroll
  for (int d = 1; d < 64; d <<= 1) {
    int o = __shfl_up(incl, d, 64);
    if ((t & 63) >= d) incl += o;
  }
  __shared__ int wtot[16], wbase[16], stot;
  if ((t & 63) == 63) wtot[t >> 6] = incl;
  __syncthreads();
  if (t < 16) {
    int s = 0;
    for (int i = 0; i < t; ++i) s += wtot[i];
    wbase[t] = s;
    if (t == 15) stot = s + wtot[15];
  }
  __syncthreads();
  int excl = wbase[t >> 6] + incl - pk;   // packed exclusive prefix (no cross-field borrow)
  int rslot = excl & 0xffff, cslot = excl >> 16;
#pragma unroll
  for (int i = 0; i < 4; ++i) {
    int n = n0 + i;
    if (f[i]) { rowsrc[rslot] = n; rowrank[n] = rslot; ++rslot; }
    else      { rowrank[n] = -1; colsrc[cslot] = n; colmapG[cslot] = n; ++cslot; }
  }
  __syncthreads();
  if (t == 0) {
    int tot = stot;
    int nr = tot & 0xffff;
    cnt[0] = nr;            // active q rows
    cnt[1] = tot >> 16;     // active s cols
    cnt[2] = (nr > 0) ? rowsrc[0] : 0x7fffffff;  // j0 = first inactive support col (= first m==1)
  }
}

// ---------------- K_base: fused norms + valid-partial + base output + b=7 fp16 prep (linear) -----
__global__ __launch_bounds__(512) void k_base(const float* __restrict__ x, const float* __restrict__ mask,
                                              float* __restrict__ fq, float* __restrict__ fs,
                                              float* __restrict__ out, float* __restrict__ partMax,
                                              int* __restrict__ mark,
                                              unsigned short* __restrict__ qhi, unsigned short* __restrict__ qlo,
                                              unsigned short* __restrict__ shi, unsigned short* __restrict__ slo) {
  int b = blockIdx.y, n0 = blockIdx.x << 6;
  int t = threadIdx.x;            // 0..511
  int ln = t & 63, cg = t >> 6;   // 8 groups x 32 channels
  __shared__ float sred[512];
  __shared__ float s0[256];
  __shared__ float rss[8][64], rdp[8][64];
  __shared__ float scaleS[64], f64q[64], f64s[64];
  __shared__ float bcast[2];
  if (b == 0 && blockIdx.x == 0) {
#pragma unroll
    for (int i = 0; i < 8; ++i) mark[t + (i << 9)] = 0;
  }
  const size_t xbase = ((size_t)b * C_) << 12;
  float xc0 = 0.f;
  if (t < 256) xc0 = x[xbase + ((size_t)t << 12)];
  sred[t] = xc0 * xc0;
  __syncthreads();
  for (int s = 256; s; s >>= 1) { if (t < s) sred[t] += sred[t + s]; __syncthreads(); }
  if (t == 0) { bcast[0] = 1.f / (sqrtf(sred[0]) + EPS_); bcast[1] = mask[b << 12]; }
  __syncthreads();
  if (t < 256) s0[t] = xc0 * ((1.f - bcast[1]) * bcast[0]);
  __syncthreads();
  int n = n0 + ln;
  const float* xp = x + xbase + (((size_t)cg) << 17) + n;
  float xv[32];
  float ss = 0.f, dp = 0.f;
#pragma unroll
  for (int c = 0; c < 32; ++c) {
    float v = xp[(size_t)c << 12];
    xv[c] = v;
    ss += v * v;
    dp += v * s0[(cg << 5) + c];
  }
  rss[cg][ln] = ss; rdp[cg][ln] = dp;
  __syncthreads();
  if (t < 64) {
    float sst = 0.f, dpt = 0.f;
#pragma unroll
    for (int g = 0; g < 8; ++g) { sst += rss[g][t]; dpt += rdp[g][t]; }
    float inv = 1.f / (sqrtf(sst) + EPS_);
    float m = mask[(b << 12) + n0 + t];
    float fqv = m * inv;
    fq[(b << 12) + n0 + t] = fqv;
    fs[(b << 12) + n0 + t] = (1.f - m) * inv;
    scaleS[t] = (m != 0.f) ? inv : 1.f;
    f64q[t] = fqv * 64.0f;
    f64s[t] = (1.f - m) * inv * 64.0f;
    float val = dpt * fqv;  // masked rows -> exactly 0
#pragma unroll
    for (int d = 32; d; d >>= 1) val = fmaxf(val, __shfl_xor(val, d, 64));
    if (t == 0) partMax[(b << 6) + blockIdx.x] = val;
  }
  __syncthreads();
  float sc = scaleS[ln];
  float* op = out + xbase + (((size_t)cg) << 17) + n;
#pragma unroll
  for (int c = 0; c < 32; ++c) op[(size_t)c << 12] = xv[c] * sc;
  if (b == B_ - 1) {
    // fused prep: scaled (x64) fp16 hi/lo split, transposed, LINEAR layout (swizzle now at staging)
    float fqn = f64q[ln], fsn = f64s[ln];
    size_t rowbase = ((size_t)n) << 8;  // 256 shorts per row
#pragma unroll
    for (int j = 0; j < 4; ++j) {
      ushort8 vqh, vql, vsh, vsl;
#pragma unroll
      for (int i = 0; i < 8; ++i) {
        float xvv = xv[j * 8 + i];
        float qv = xvv * fqn;
        _Float16 qh = (_Float16)qv;
        _Float16 ql = (_Float16)((qv - (float)qh) * 2048.0f);
        float sv = xvv * fsn;
        _Float16 sh = (_Float16)sv;
        _Float16 sl = (_Float16)((sv - (float)sh) * 2048.0f);
        vqh[i] = __builtin_bit_cast(unsigned short, qh);
        vql[i] = __builtin_bit_cast(unsigned short, ql);
        vsh[i] = __builtin_bit_cast(unsigned short, sh);
        vsl[i] = __builtin_bit_cast(unsigned short, sl);
      }
      size_t off = rowbase + ((size_t)cg << 5) + ((size_t)j << 3);
      *reinterpret_cast<ushort8*>(qhi + off) = vqh;
      *reinterpret_cast<ushort8*>(qlo + off) = vql;
      *reinterpret_cast<ushort8*>(shi + off) = vsh;
      *reinterpret_cast<ushort8*>(slo + off) = vsl;
    }
  }
}

// ---------------- K_sim7: compacted MFMA sim + row argmax for b=7 ----------------
// Compaction via per-lane indirect global source (gload_lds global addr IS per-lane);
// LDS dest linear; chunk-XOR swizzle keyed by SLOT row matches ds_read side (ra>>1)&3.
__global__ __launch_bounds__(256, 2) void k_sim7(const unsigned short* __restrict__ qhi, const unsigned short* __restrict__ qlo,
                                                 const unsigned short* __restrict__ shi, const unsigned short* __restrict__ slo,
                                                 const int* __restrict__ rowsrc, const int* __restrict__ colsrc,
                                                 const int* __restrict__ colmapG, const int* __restrict__ cnt,
                                                 float* __restrict__ partV, int* __restrict__ partI) {
  int nrows = cnt[0], ncols = cnt[1];
  int bid = blockIdx.x;
  int mt = bid & 31, nt = bid >> 5;
  if ((nt << 7) >= nrows || (mt << 7) >= ncols) return;  // data-dependent tile cull (~3/4 exit)
  int tid = threadIdx.x;
  int w = tid >> 6, lane = tid & 63;
  int wy = w >> 1, wx = w & 1;
  __shared__ __align__(16) unsigned short smem[2][16384];  // 2 x 32KB double buffer

  f32x4 acc_h[4][4], acc_c[4][4];
#pragma unroll
  for (int i = 0; i < 4; ++i)
#pragma unroll
    for (int j = 0; j < 4; ++j) {
      acc_h[i][j] = (f32x4){0.f, 0.f, 0.f, 0.f};
      acc_c[i][j] = (f32x4){0.f, 0.f, 0.f, 0.f};
    }

  const unsigned short* gsrc = (w == 0) ? qhi : (w == 1) ? qlo : (w == 2) ? shi : slo;
  const int* srcmap = (w < 2) ? rowsrc : colsrc;
  int n0 = ((w < 2) ? nt : mt) << 7;
  int lrow = lane >> 2, lch = lane & 3;
  int chx = (lch ^ ((lrow >> 1) & 3)) << 3;   // slot-keyed chunk swizzle (slot row mod 16 = lrow)
  int s = lane >> 4, c16 = lane & 15;
  int srco[8];
#pragma unroll
  for (int seg = 0; seg < 8; ++seg)
    srco[seg] = (srcmap[n0 + (seg << 4) + lrow] << 8) + chx;

#define STAGE7(buf, kt)                                                                \
  _Pragma("unroll")                                                                    \
  for (int seg = 0; seg < 8; ++seg) {                                                  \
    const unsigned short* g = gsrc + (size_t)(srco[seg] + ((kt) << 5));                \
    gload_lds16(g, &smem[buf][(w << 12) + (seg << 9)]);                                \
  }

  STAGE7(0, 0);

  int cur = 0;
  for (int kt = 0; kt < 8; ++kt) {
    if (kt < 7) {
      STAGE7(cur ^ 1, kt + 1);
      asm volatile("s_waitcnt vmcnt(8)" ::: "memory");
    } else {
      asm volatile("s_waitcnt vmcnt(0)" ::: "memory");
    }
    __builtin_amdgcn_s_barrier();
    __builtin_amdgcn_sched_barrier(0);
    const unsigned short* sm = &smem[cur][0];
    half8 ah[4], al[4], bh[4], bl[4];
#pragma unroll
    for (int f = 0; f < 4; ++f) {
      int ra = (wy << 6) + (f << 4) + c16;
      int oa = ra * 32 + ((s ^ ((ra >> 1) & 3)) << 3);
      ah[f] = *reinterpret_cast<const half8*>(&sm[oa]);
      al[f] = *reinterpret_cast<const half8*>(&sm[4096 + oa]);
      int rb = (wx << 6) + (f << 4) + c16;
      int ob = rb * 32 + ((s ^ ((rb >> 1) & 3)) << 3);
      bh[f] = *reinterpret_cast<const half8*>(&sm[8192 + ob]);
      bl[f] = *reinterpret_cast<const half8*>(&sm[12288 + ob]);
    }
#pragma unroll
    for (int fi = 0; fi < 4; ++fi)
#pragma unroll
      for (int fj = 0; fj < 4; ++fj) {
        acc_h[fi][fj] = __builtin_amdgcn_mfma_f32_16x16x32_f16(ah[fi], bh[fj], acc_h[fi][fj], 0, 0, 0);
        acc_c[fi][fj] = __builtin_amdgcn_mfma_f32_16x16x32_f16(ah[fi], bl[fj], acc_c[fi][fj], 0, 0, 0);
        acc_c[fi][fj] = __builtin_amdgcn_mfma_f32_16x16x32_f16(al[fi], bh[fj], acc_c[fi][fj], 0, 0, 0);
      }
    asm volatile("s_waitcnt lgkmcnt(0)" ::: "memory");
    __builtin_amdgcn_s_barrier();
    __builtin_amdgcn_sched_barrier(0);
    cur ^= 1;
  }
#undef STAGE7
  // per-row argmax over compact cols; colg via colmapG (monotone incl. tail), tail forced -inf
  int cg4[4], cok[4];
#pragma unroll
  for (int fj = 0; fj < 4; ++fj) {
    int slotg = (mt << 7) + (wx << 6) + (fj << 4) + c16;
    cg4[fj] = colmapG[slotg];
    cok[fj] = slotg < ncols;
  }
  float* redV = reinterpret_cast<float*>(&smem[0][0]);       // [128][2]
  int* redI = reinterpret_cast<int*>(&smem[0][512]);         // [128][2]
  int g16 = lane >> 4;
#pragma unroll
  for (int fi = 0; fi < 4; ++fi)
#pragma unroll
    for (int r2 = 0; r2 < 4; ++r2) {
      float bv = -INFINITY; int bi = 0x7fffffff;
#pragma unroll
      for (int fj = 0; fj < 4; ++fj) {
        float v = cok[fj] ? (acc_h[fi][fj][r2] + acc_c[fi][fj][r2] * (1.0f / 2048.0f)) * (1.0f / 4096.0f)
                          : -INFINITY;
        int colg = cg4[fj];
        if (v > bv) { bv = v; bi = colg; }  // colg ascending with fj: strict > keeps first
      }
#pragma unroll
      for (int d = 1; d < 16; d <<= 1) {
        float ov = __shfl_xor(bv, d, 64);
        int oi = __shfl_xor(bi, d, 64);
        if (ov > bv || (ov == bv && oi < bi)) { bv = ov; bi = oi; }
      }
      if (c16 == 0) {
        int row = (wy << 6) + (fi << 4) + (g16 << 2) + r2;
        redV[row * 2 + wx] = bv;
        redI[row * 2 + wx] = bi;
      }
    }
  __syncthreads();
  if (tid < 128) {
    float v0 = redV[tid * 2], v1 = redV[tid * 2 + 1];
    int i0 = redI[tid * 2], i1 = redI[tid * 2 + 1];
    if (v1 > v0 || (v1 == v0 && i1 < i0)) { v0 = v1; i0 = i1; }
    int n = (nt << 7) + tid;   // compact slot row
    partV[(((size_t)n) << 5) + mt] = v0;
    partI[(((size_t)n) << 5) + mt] = i0;
  }
}

// ---------------- K_simL: legacy fp32 sim for b<7, full-row argmax (gated inline; ~never runs) ----
__global__ __launch_bounds__(256) void k_simL(const float* __restrict__ x, const float* __restrict__ mask,
                                              const float* __restrict__ partMax,
                                              const float* __restrict__ fq, const float* __restrict__ fs,
                                              float* __restrict__ wv, int* __restrict__ idxv) {
  int b = blockIdx.y;
  float fore = block_fore(partMax, b);
  if (!(fore > 0.5f) || mask[b << 12] == 0.f) return;  // need==0 for b<7
  int n0 = blockIdx.x << 6;
  int tid = threadIdx.x;
  int tx = tid & 15, ty = tid >> 4;
  int lk = ty, ln4 = tx << 2;

  __shared__ float As[16][68];
  __shared__ float Bs[16][68];
  __shared__ float fqs[64], fss[64];
  __shared__ float rv[64][17];
  __shared__ int ri[64][17];

  if (tid < 64) fqs[tid] = fq[(b << 12) + n0 + tid];

  float bestv[4]; int besti[4];
#pragma unroll
  for (int i = 0; i < 4; ++i) { bestv[i] = -INFINITY; besti[i] = 0; }

  const size_t xb = ((size_t)b * C_) << 12;

  for (int m0 = 0; m0 < N_; m0 += 64) {
    if (tid < 64) fss[tid] = fs[(b << 12) + m0 + tid];
    float cacc[4][4];
#pragma unroll
    for (int i = 0; i < 4; ++i)
#pragma unroll
      for (int j = 0; j < 4; ++j) cacc[i][j] = 0.f;
    __syncthreads();
    for (int kt = 0; kt < C_; kt += 16) {
      float4 va = *reinterpret_cast<const float4*>(x + xb + ((size_t)(kt + lk) << 12) + n0 + ln4);
      float4 vb = *reinterpret_cast<const float4*>(x + xb + ((size_t)(kt + lk) << 12) + m0 + ln4);
      va.x *= fqs[ln4]; va.y *= fqs[ln4 + 1]; va.z *= fqs[ln4 + 2]; va.w *= fqs[ln4 + 3];
      vb.x *= fss[ln4]; vb.y *= fss[ln4 + 1]; vb.z *= fss[ln4 + 2]; vb.w *= fss[ln4 + 3];
      *reinterpret_cast<float4*>(&As[lk][ln4]) = va;
      *reinterpret_cast<float4*>(&Bs[lk][ln4]) = vb;
      __syncthreads();
#pragma unroll
      for (int k = 0; k < 16; ++k) {
        float a0 = As[k][(ty << 2) + 0], a1 = As[k][(ty << 2) + 1], a2 = As[k][(ty << 2) + 2], a3 = As[k][(ty << 2) + 3];
        float b0 = Bs[k][(tx << 2) + 0], b1 = Bs[k][(tx << 2) + 1], b2 = Bs[k][(tx << 2) + 2], b3 = Bs[k][(tx << 2) + 3];
        cacc[0][0] += a0 * b0; cacc[0][1] += a0 * b1; cacc[0][2] += a0 * b2; cacc[0][3] += a0 * b3;
        cacc[1][0] += a1 * b0; cacc[1][1] += a1 * b1; cacc[1][2] += a1 * b2; cacc[1][3] += a1 * b3;
        cacc[2][0] += a2 * b0; cacc[2][1] += a2 * b1; cacc[2][2] += a2 * b2; cacc[2][3] += a2 * b3;
        cacc[3][0] += a3 * b0; cacc[3][1] += a3 * b1; cacc[3][2] += a3 * b2; cacc[3][3] += a3 * b3;
      }
      __syncthreads();
    }
#pragma unroll
    for (int j = 0; j < 4; ++j) {
      int col = m0 + (tx << 2) + j;
#pragma unroll
      for (int i = 0; i < 4; ++i) {
        float v = cacc[i][j];
        if (v > bestv[i]) { bestv[i] = v; besti[i] = col; }
      }
    }
  }
#pragma unroll
  for (int i = 0; i < 4; ++i) { rv[(ty << 2) + i][tx] = bestv[i]; ri[(ty << 2) + i][tx] = besti[i]; }
  __syncthreads();
  if (tid < 64) {
    float bv = rv[tid][0]; int bi = ri[tid][0];
#pragma unroll
    for (int t = 1; t < 16; ++t) {
      float v = rv[tid][t]; int ii = ri[tid][t];
      if (v > bv || (v == bv && ii < bi)) { bv = v; bi = ii; }
    }
    wv[(b << 12) + n0 + tid] = bv;
    idxv[(b << 12) + n0 + tid] = bi;
  }
}

// ---------------- K_red7m: de-compact reduce for b=7 + inactive-col candidate + mark -------------
__global__ __launch_bounds__(256) void k_red7m(const float* __restrict__ p7V, const int* __restrict__ p7I,
                                               const int* __restrict__ rowrank, const int* __restrict__ cnt,
                                               float* __restrict__ wv, int* __restrict__ idxv,
                                               int* __restrict__ mark) {
  int n = blockIdx.x * 256 + threadIdx.x;   // orig row
  int ncols = cnt[1], j0 = cnt[2];
  int rk = rowrank[n];
  float bv; int bi;
  if (rk < 0) {
    bv = 0.f; bi = 0;   // inactive q-row: sim row exactly zero, argmax = 0
  } else {
    bv = -INFINITY; bi = 0x7fffffff;
    int mtmax = (ncols + 127) >> 7;
    for (int mt = 0; mt < mtmax; ++mt) {
      float v = p7V[(((size_t)rk) << 5) + mt];
      int i = p7I[(((size_t)rk) << 5) + mt];
      if (v > bv || (v == bv && i < bi)) { bv = v; bi = i; }
    }
    if (j0 < N_) {  // inactive support cols all have sim exactly 0; first index j0
      if (0.f > bv) { bv = 0.f; bi = j0; }
      else if (0.f == bv && j0 < bi) bi = j0;
    }
  }
  wv[((B_ - 1) << 12) + n] = bv;
  idxv[((B_ - 1) << 12) + n] = bi;
  mark[bi] = 1;  // benign same-value race
}

// ---------------- K_hybrid: gated 1x1-conv overwrite with inline valid + softmax scalars ----------
__global__ __launch_bounds__(256) void k_hybrid(const float* __restrict__ x, const float* __restrict__ mask,
                                                const float* __restrict__ partMax,
                                                const float* __restrict__ fq, const float* __restrict__ fs,
                                                const float* __restrict__ Wc, const float* __restrict__ bc,
                                                const int* __restrict__ idxv, const float* __restrict__ wv,
                                                float* __restrict__ out) {
  int b = blockIdx.y;
  float fore = block_fore(partMax, b);
  if (!(fore > 0.5f) || mask[b << 12] == 0.f) return;  // valid==0
  int tid = threadIdx.x;
  __shared__ float red[256];
  float mx = -INFINITY;
  for (int n = tid; n < N_; n += 256) mx = fmaxf(mx, wv[(b << 12) + n]);
  red[tid] = mx; __syncthreads();
  for (int s = 128; s; s >>= 1) { if (tid < s) red[tid] = fmaxf(red[tid], red[tid + s]); __syncthreads(); }
  mx = red[0]; __syncthreads();
  float sm = 0.f;
  for (int n = tid; n < N_; n += 256) sm += expf(wv[(b << 12) + n] - mx);
  red[tid] = sm; __syncthreads();
  for (int s = 128; s; s >>= 1) { if (tid < s) red[tid] += red[tid + s]; __syncthreads(); }
  float den = red[0];

  int n = blockIdx.x * 256 + tid;
  int bn = (b << 12) + n;
  float mn = mask[bn];
  if (mn == 0.f) return;
  int j = idxv[bn];
  float w = expf(wv[bn] - mx) / den;
  float fsj = fs[(b << 12) + j];
  float fqn = fq[bn];
  const float* xb = x + (((size_t)b * C_) << 12);
  for (int o = 0; o < C_; ++o) {
    const float* wr = Wc + o * 2 * C_;
    float a1 = 0.f, a2 = 0.f;
    for (int i = 0; i < C_; ++i) {
      a1 += wr[i] * xb[((size_t)i << 12) + j];
      a2 += wr[C_ + i] * xb[((size_t)i << 12) + n];
    }
    out[((size_t)(b * C_ + o) << 12) + n] = bc[o] + a1 * (fsj * w) + a2 * fqn;
  }
}

// ---------------- K6: attmap nearest x8 upsample (8 px / thread) ----------------
__global__ __launch_bounds__(256) void k_att(const int* __restrict__ mark, float* __restrict__ att) {
  int id = blockIdx.x * 256 + threadIdx.x;
  int x8 = (id & 63) << 3;
  int y = (id >> 6) & 511;
  int b = id >> 15;
  float v = mark[((y >> 3) << 6) + (x8 >> 3)] ? 1.f : 0.f;
  float4 vv = make_float4(v, v, v, v);
  float* p = att + (((size_t)b) << 18) + (y << 9) + x8;
  *reinterpret_cast<float4*>(p) = vv;
  *reinterpret_cast<float4*>(p + 4) = vv;
}

extern "C" void kernel_launch(void* const* d_in, const int* in_sizes, int n_in,
                              void* d_out, int out_size, void* d_ws, size_t ws_size,
                              hipStream_t stream) {
  const float* x = (const float*)d_in[0];
  const float* mask = (const float*)d_in[1];
  const float* Wc = (const float*)d_in[2];
  const float* bc = (const float*)d_in[3];
  float* out = (float*)d_out;
  float* att = out + (size_t)B_ * C_ * N_;

  float* wsf = (float*)d_ws;
  float* fq = wsf;                          // 32768
  float* fs = wsf + 32768;                  // 32768
  float* wv = wsf + 65536;                  // 32768
  int* idxv = (int*)(wsf + 98304);          // 32768 -> ends 131072
  int* rowsrc = (int*)(wsf + 131072);       // 4096
  int* rowrank = (int*)(wsf + 135168);      // 4096
  int* colsrc = (int*)(wsf + 139264);       // 4096
  int* colmapG = (int*)(wsf + 143360);      // 4096
  int* cnt = (int*)(wsf + 147456);          // 8 -> ends 147464
  int* mark = (int*)(wsf + 655392);         // 4096 -> ends 659488
  float* partMax = wsf + 659488;            // 512 -> ends 660000
  float* p7V = wsf + 660000;                // 131072 -> ends 791072
  int* p7I = (int*)(wsf + 791072);          // 131072 -> ends 922144
  unsigned short* qhi = (unsigned short*)(wsf + 922144);   // 524288 floats (2MB) each
  unsigned short* qlo = (unsigned short*)(wsf + 1446432);
  unsigned short* shi = (unsigned short*)(wsf + 1970720);
  unsigned short* slo = (unsigned short*)(wsf + 2495008);  // end: 3019296 floats (~11.5MB)

  k_cmp7<<<1, 1024, 0, stream>>>(mask, rowsrc, rowrank, colsrc, colmapG, cnt);
  k_base<<<dim3(64, B_), 512, 0, stream>>>(x, mask, fq, fs, out, partMax, mark, qhi, qlo, shi, slo);
  k_sim7<<<1024, 256, 0, stream>>>(qhi, qlo, shi, slo, rowsrc, colsrc, colmapG, cnt, p7V, p7I);
  k_simL<<<dim3(64, B_ - 1), 256, 0, stream>>>(x, mask, partMax, fq, fs, wv, idxv);
  k_red7m<<<16, 256, 0, stream>>>(p7V, p7I, rowrank, cnt, wv, idxv, mark);
  k_hybrid<<<dim3(16, B_), 256, 0, stream>>>(x, mask, partMax, fq, fs, Wc, bc, idxv, wv, out);
  k_att<<<1024, 256, 0, stream>>>(mark, att);
}

// Round 11
// 62.415 us; speedup vs baseline: 7.7423x; 1.1527x over previous
//
#include <hip/hip_runtime.h>
#include <cmath>

#define B_ 8
#define C_ 256
#define N_ 4096
#define EPS_ 1e-8f

typedef _Float16 half8 __attribute__((ext_vector_type(8)));
typedef float f32x4 __attribute__((ext_vector_type(4)));
typedef unsigned short ushort8 __attribute__((ext_vector_type(8)));

__device__ __forceinline__ void gload_lds16(const void* g, void* l) {
  __builtin_amdgcn_global_load_lds((const __attribute__((address_space(1))) unsigned int*)g,
                                   (__attribute__((address_space(3))) unsigned int*)l, 16, 0, 0);
}

// Block-uniform need/valid recompute from partMax (64 partials per batch).
__device__ __forceinline__ float block_fore(const float* __restrict__ partMax, int b) {
  int l = threadIdx.x & 63;
  float v = partMax[(b << 6) + l];
#pragma unroll
  for (int d = 32; d; d >>= 1) v = fmaxf(v, __shfl_xor(v, d, 64));
  return v;
}

// ---------------- K_base: fused norms + valid-partial + base out + b=7 fp16 prep + cmp7 (b==8 row) ----
__global__ __launch_bounds__(512) void k_base(const float* __restrict__ x, const float* __restrict__ mask,
                                              float* __restrict__ fq, float* __restrict__ fs,
                                              float* __restrict__ out, float* __restrict__ partMax,
                                              int* __restrict__ mark,
                                              unsigned short* __restrict__ qhi, unsigned short* __restrict__ qlo,
                                              unsigned short* __restrict__ shi, unsigned short* __restrict__ slo,
                                              int* __restrict__ rowsrc, int* __restrict__ rowrank,
                                              int* __restrict__ colsrc, int* __restrict__ colmapG,
                                              int* __restrict__ cnt) {
  int b = blockIdx.y, n0 = blockIdx.x << 6;
  int t = threadIdx.x;            // 0..511
  if (b == B_) {
    // ---- compaction scan for b=7 (1 block of 512 threads, 8 elements each; stable order) ----
    if (blockIdx.x != 0) return;
    __shared__ int wtot[8], wbase[8], stot_s;
    int n0c = t << 3;
#pragma unroll
    for (int i = 0; i < 8; ++i) {
      rowsrc[t + (i << 9)] = 0;
      colsrc[t + (i << 9)] = 0;
      colmapG[t + (i << 9)] = 0x3fffffff;  // tail slots: huge but monotone col index
    }
    __syncthreads();
    int f[8]; int pk = 0;
#pragma unroll
    for (int i = 0; i < 8; ++i) {
      int m = (mask[(7 << 12) + n0c + i] != 0.f) ? 1 : 0;
      f[i] = m;
      pk += m ? 1 : (1 << 16);  // low 16: rows (m=1), high 16: cols (m=0)
    }
    int incl = pk;
#pragma unroll
    for (int d = 1; d < 64; d <<= 1) {
      int o = __shfl_up(incl, d, 64);
      if ((t & 63) >= d) incl += o;
    }
    if ((t & 63) == 63) wtot[t >> 6] = incl;
    __syncthreads();
    if (t < 8) {
      int s2 = 0;
      for (int i = 0; i < t; ++i) s2 += wtot[i];
      wbase[t] = s2;
      if (t == 7) stot_s = s2 + wtot[7];
    }
    __syncthreads();
    int excl = wbase[t >> 6] + incl - pk;   // packed exclusive prefix
    int rslot = excl & 0xffff, cslot = excl >> 16;
#pragma unroll
    for (int i = 0; i < 8; ++i) {
      int n2 = n0c + i;
      if (f[i]) { rowsrc[rslot] = n2; rowrank[n2] = rslot; ++rslot; }
      else      { rowrank[n2] = -1; colsrc[cslot] = n2; colmapG[cslot] = n2; ++cslot; }
    }
    __syncthreads();
    if (t == 0) {
      int tot = stot_s;
      int nr = tot & 0xffff;
      cnt[0] = nr;
      cnt[1] = tot >> 16;
      cnt[2] = (nr > 0) ? rowsrc[0] : 0x7fffffff;  // j0 = first inactive support col
    }
    return;
  }
  int ln = t & 63, cg = t >> 6;   // 8 groups x 32 channels
  __shared__ float sred[512];
  __shared__ float s0[256];
  __shared__ float rss[8][64], rdp[8][64];
  __shared__ float scaleS[64], f64q[64], f64s[64];
  __shared__ float bcast[2];
  if (b == 0 && blockIdx.x == 0) {
#pragma unroll
    for (int i = 0; i < 8; ++i) mark[t + (i << 9)] = 0;
  }
  const size_t xbase = ((size_t)b * C_) << 12;
  float xc0 = 0.f;
  if (t < 256) xc0 = x[xbase + ((size_t)t << 12)];
  sred[t] = xc0 * xc0;
  __syncthreads();
  for (int s = 256; s; s >>= 1) { if (t < s) sred[t] += sred[t + s]; __syncthreads(); }
  if (t == 0) { bcast[0] = 1.f / (sqrtf(sred[0]) + EPS_); bcast[1] = mask[b << 12]; }
  __syncthreads();
  if (t < 256) s0[t] = xc0 * ((1.f - bcast[1]) * bcast[0]);
  __syncthreads();
  int n = n0 + ln;
  const float* xp = x + xbase + (((size_t)cg) << 17) + n;
  float xv[32];
  float ss = 0.f, dp = 0.f;
#pragma unroll
  for (int c = 0; c < 32; ++c) {
    float v = xp[(size_t)c << 12];
    xv[c] = v;
    ss += v * v;
    dp += v * s0[(cg << 5) + c];
  }
  rss[cg][ln] = ss; rdp[cg][ln] = dp;
  __syncthreads();
  if (t < 64) {
    float sst = 0.f, dpt = 0.f;
#pragma unroll
    for (int g = 0; g < 8; ++g) { sst += rss[g][t]; dpt += rdp[g][t]; }
    float inv = 1.f / (sqrtf(sst) + EPS_);
    float m = mask[(b << 12) + n0 + t];
    float fqv = m * inv;
    fq[(b << 12) + n0 + t] = fqv;
    fs[(b << 12) + n0 + t] = (1.f - m) * inv;
    scaleS[t] = (m != 0.f) ? inv : 1.f;
    f64q[t] = fqv * 64.0f;
    f64s[t] = (1.f - m) * inv * 64.0f;
    float val = dpt * fqv;  // masked rows -> exactly 0
#pragma unroll
    for (int d = 32; d; d >>= 1) val = fmaxf(val, __shfl_xor(val, d, 64));
    if (t == 0) partMax[(b << 6) + blockIdx.x] = val;
  }
  __syncthreads();
  float sc = scaleS[ln];
  float* op = out + xbase + (((size_t)cg) << 17) + n;
#pragma unroll
  for (int c = 0; c < 32; ++c) op[(size_t)c << 12] = xv[c] * sc;
  if (b == B_ - 1) {
    // fused prep: scaled (x64) fp16 hi/lo split, transposed, LINEAR layout (swizzle at staging)
    float fqn = f64q[ln], fsn = f64s[ln];
    size_t rowbase = ((size_t)n) << 8;  // 256 shorts per row
#pragma unroll
    for (int j = 0; j < 4; ++j) {
      ushort8 vqh, vql, vsh, vsl;
#pragma unroll
      for (int i = 0; i < 8; ++i) {
        float xvv = xv[j * 8 + i];
        float qv = xvv * fqn;
        _Float16 qh = (_Float16)qv;
        _Float16 ql = (_Float16)((qv - (float)qh) * 2048.0f);
        float sv = xvv * fsn;
        _Float16 sh = (_Float16)sv;
        _Float16 sl = (_Float16)((sv - (float)sh) * 2048.0f);
        vqh[i] = __builtin_bit_cast(unsigned short, qh);
        vql[i] = __builtin_bit_cast(unsigned short, ql);
        vsh[i] = __builtin_bit_cast(unsigned short, sh);
        vsl[i] = __builtin_bit_cast(unsigned short, sl);
      }
      size_t off = rowbase + ((size_t)cg << 5) + ((size_t)j << 3);
      *reinterpret_cast<ushort8*>(qhi + off) = vqh;
      *reinterpret_cast<ushort8*>(qlo + off) = vql;
      *reinterpret_cast<ushort8*>(shi + off) = vsh;
      *reinterpret_cast<ushort8*>(slo + off) = vsl;
    }
  }
}

// ---------------- K_sim7: compacted MFMA sim + row argmax for b=7 (unchanged) ----------------
__global__ __launch_bounds__(256, 2) void k_sim7(const unsigned short* __restrict__ qhi, const unsigned short* __restrict__ qlo,
                                                 const unsigned short* __restrict__ shi, const unsigned short* __restrict__ slo,
                                                 const int* __restrict__ rowsrc, const int* __restrict__ colsrc,
                                                 const int* __restrict__ colmapG, const int* __restrict__ cnt,
                                                 float* __restrict__ partV, int* __restrict__ partI) {
  int nrows = cnt[0], ncols = cnt[1];
  int bid = blockIdx.x;
  int mt = bid & 31, nt = bid >> 5;
  if ((nt << 7) >= nrows || (mt << 7) >= ncols) return;  // data-dependent tile cull
  int tid = threadIdx.x;
  int w = tid >> 6, lane = tid & 63;
  int wy = w >> 1, wx = w & 1;
  __shared__ __align__(16) unsigned short smem[2][16384];  // 2 x 32KB double buffer

  f32x4 acc_h[4][4], acc_c[4][4];
#pragma unroll
  for (int i = 0; i < 4; ++i)
#pragma unroll
    for (int j = 0; j < 4; ++j) {
      acc_h[i][j] = (f32x4){0.f, 0.f, 0.f, 0.f};
      acc_c[i][j] = (f32x4){0.f, 0.f, 0.f, 0.f};
    }

  const unsigned short* gsrc = (w == 0) ? qhi : (w == 1) ? qlo : (w == 2) ? shi : slo;
  const int* srcmap = (w < 2) ? rowsrc : colsrc;
  int n0 = ((w < 2) ? nt : mt) << 7;
  int lrow = lane >> 2, lch = lane & 3;
  int chx = (lch ^ ((lrow >> 1) & 3)) << 3;   // slot-keyed chunk swizzle
  int s = lane >> 4, c16 = lane & 15;
  int srco[8];
#pragma unroll
  for (int seg = 0; seg < 8; ++seg)
    srco[seg] = (srcmap[n0 + (seg << 4) + lrow] << 8) + chx;

#define STAGE7(buf, kt)                                                                \
  _Pragma("unroll")                                                                    \
  for (int seg = 0; seg < 8; ++seg) {                                                  \
    const unsigned short* g = gsrc + (size_t)(srco[seg] + ((kt) << 5));                \
    gload_lds16(g, &smem[buf][(w << 12) + (seg << 9)]);                                \
  }

  STAGE7(0, 0);

  int cur = 0;
  for (int kt = 0; kt < 8; ++kt) {
    if (kt < 7) {
      STAGE7(cur ^ 1, kt + 1);
      asm volatile("s_waitcnt vmcnt(8)" ::: "memory");
    } else {
      asm volatile("s_waitcnt vmcnt(0)" ::: "memory");
    }
    __builtin_amdgcn_s_barrier();
    __builtin_amdgcn_sched_barrier(0);
    const unsigned short* sm = &smem[cur][0];
    half8 ah[4], al[4], bh[4], bl[4];
#pragma unroll
    for (int f = 0; f < 4; ++f) {
      int ra = (wy << 6) + (f << 4) + c16;
      int oa = ra * 32 + ((s ^ ((ra >> 1) & 3)) << 3);
      ah[f] = *reinterpret_cast<const half8*>(&sm[oa]);
      al[f] = *reinterpret_cast<const half8*>(&sm[4096 + oa]);
      int rb = (wx << 6) + (f << 4) + c16;
      int ob = rb * 32 + ((s ^ ((rb >> 1) & 3)) << 3);
      bh[f] = *reinterpret_cast<const half8*>(&sm[8192 + ob]);
      bl[f] = *reinterpret_cast<const half8*>(&sm[12288 + ob]);
    }
#pragma unroll
    for (int fi = 0; fi < 4; ++fi)
#pragma unroll
      for (int fj = 0; fj < 4; ++fj) {
        acc_h[fi][fj] = __builtin_amdgcn_mfma_f32_16x16x32_f16(ah[fi], bh[fj], acc_h[fi][fj], 0, 0, 0);
        acc_c[fi][fj] = __builtin_amdgcn_mfma_f32_16x16x32_f16(ah[fi], bl[fj], acc_c[fi][fj], 0, 0, 0);
        acc_c[fi][fj] = __builtin_amdgcn_mfma_f32_16x16x32_f16(al[fi], bh[fj], acc_c[fi][fj], 0, 0, 0);
      }
    asm volatile("s_waitcnt lgkmcnt(0)" ::: "memory");
    __builtin_amdgcn_s_barrier();
    __builtin_amdgcn_sched_barrier(0);
    cur ^= 1;
  }
#undef STAGE7
  int cg4[4], cok[4];
#pragma unroll
  for (int fj = 0; fj < 4; ++fj) {
    int slotg = (mt << 7) + (wx << 6) + (fj << 4) + c16;
    cg4[fj] = colmapG[slotg];
    cok[fj] = slotg < ncols;
  }
  float* redV = reinterpret_cast<float*>(&smem[0][0]);       // [128][2]
  int* redI = reinterpret_cast<int*>(&smem[0][512]);         // [128][2]
  int g16 = lane >> 4;
#pragma unroll
  for (int fi = 0; fi < 4; ++fi)
#pragma unroll
    for (int r2 = 0; r2 < 4; ++r2) {
      float bv = -INFINITY; int bi = 0x7fffffff;
#pragma unroll
      for (int fj = 0; fj < 4; ++fj) {
        float v = cok[fj] ? (acc_h[fi][fj][r2] + acc_c[fi][fj][r2] * (1.0f / 2048.0f)) * (1.0f / 4096.0f)
                          : -INFINITY;
        int colg = cg4[fj];
        if (v > bv) { bv = v; bi = colg; }
      }
#pragma unroll
      for (int d = 1; d < 16; d <<= 1) {
        float ov = __shfl_xor(bv, d, 64);
        int oi = __shfl_xor(bi, d, 64);
        if (ov > bv || (ov == bv && oi < bi)) { bv = ov; bi = oi; }
      }
      if (c16 == 0) {
        int row = (wy << 6) + (fi << 4) + (g16 << 2) + r2;
        redV[row * 2 + wx] = bv;
        redI[row * 2 + wx] = bi;
      }
    }
  __syncthreads();
  if (tid < 128) {
    float v0 = redV[tid * 2], v1 = redV[tid * 2 + 1];
    int i0 = redI[tid * 2], i1 = redI[tid * 2 + 1];
    if (v1 > v0 || (v1 == v0 && i1 < i0)) { v0 = v1; i0 = i1; }
    int n = (nt << 7) + tid;   // compact slot row
    partV[(((size_t)n) << 5) + mt] = v0;
    partI[(((size_t)n) << 5) + mt] = i0;
  }
}

// ---------------- K_mid: red7m (bid<16) + legacy simL (bid>=16, gated ~never runs) ----------------
__global__ __launch_bounds__(256) void k_mid(const float* __restrict__ x, const float* __restrict__ mask,
                                             const float* __restrict__ partMax,
                                             const float* __restrict__ fq, const float* __restrict__ fs,
                                             const float* __restrict__ p7V, const int* __restrict__ p7I,
                                             const int* __restrict__ rowrank, const int* __restrict__ cnt,
                                             float* __restrict__ wv, int* __restrict__ idxv,
                                             int* __restrict__ mark) {
  int bid = blockIdx.x;
  int tid = threadIdx.x;
  if (bid < 16) {
    // ---- de-compact reduce for b=7 + inactive-col candidate + mark ----
    int n = bid * 256 + tid;   // orig row
    int ncols = cnt[1], j0 = cnt[2];
    int rk = rowrank[n];
    float bv; int bi;
    if (rk < 0) {
      bv = 0.f; bi = 0;
    } else {
      bv = -INFINITY; bi = 0x7fffffff;
      int mtmax = (ncols + 127) >> 7;
      for (int mt = 0; mt < mtmax; ++mt) {
        float v = p7V[(((size_t)rk) << 5) + mt];
        int i = p7I[(((size_t)rk) << 5) + mt];
        if (v > bv || (v == bv && i < bi)) { bv = v; bi = i; }
      }
      if (j0 < N_) {
        if (0.f > bv) { bv = 0.f; bi = j0; }
        else if (0.f == bv && j0 < bi) bi = j0;
      }
    }
    wv[((B_ - 1) << 12) + n] = bv;
    idxv[((B_ - 1) << 12) + n] = bi;
    mark[bi] = 1;  // benign same-value race
    return;
  }
  // ---- legacy fp32 sim for b<7, full-row argmax ----
  int rr = bid - 16;
  int b = rr >> 6;
  float fore = block_fore(partMax, b);
  if (!(fore > 0.5f) || mask[b << 12] == 0.f) return;  // need==0 for b<7
  int n0 = (rr & 63) << 6;
  int tx = tid & 15, ty = tid >> 4;
  int lk = ty, ln4 = tx << 2;

  __shared__ float As[16][68];
  __shared__ float Bs[16][68];
  __shared__ float fqs[64], fss[64];
  __shared__ float rv[64][17];
  __shared__ int ri[64][17];

  if (tid < 64) fqs[tid] = fq[(b << 12) + n0 + tid];

  float bestv[4]; int besti[4];
#pragma unroll
  for (int i = 0; i < 4; ++i) { bestv[i] = -INFINITY; besti[i] = 0; }

  const size_t xb = ((size_t)b * C_) << 12;

  for (int m0 = 0; m0 < N_; m0 += 64) {
    if (tid < 64) fss[tid] = fs[(b << 12) + m0 + tid];
    float cacc[4][4];
#pragma unroll
    for (int i = 0; i < 4; ++i)
#pragma unroll
      for (int j = 0; j < 4; ++j) cacc[i][j] = 0.f;
    __syncthreads();
    for (int kt = 0; kt < C_; kt += 16) {
      float4 va = *reinterpret_cast<const float4*>(x + xb + ((size_t)(kt + lk) << 12) + n0 + ln4);
      float4 vb = *reinterpret_cast<const float4*>(x + xb + ((size_t)(kt + lk) << 12) + m0 + ln4);
      va.x *= fqs[ln4]; va.y *= fqs[ln4 + 1]; va.z *= fqs[ln4 + 2]; va.w *= fqs[ln4 + 3];
      vb.x *= fss[ln4]; vb.y *= fss[ln4 + 1]; vb.z *= fss[ln4 + 2]; vb.w *= fss[ln4 + 3];
      *reinterpret_cast<float4*>(&As[lk][ln4]) = va;
      *reinterpret_cast<float4*>(&Bs[lk][ln4]) = vb;
      __syncthreads();
#pragma unroll
      for (int k = 0; k < 16; ++k) {
        float a0 = As[k][(ty << 2) + 0], a1 = As[k][(ty << 2) + 1], a2 = As[k][(ty << 2) + 2], a3 = As[k][(ty << 2) + 3];
        float b0 = Bs[k][(tx << 2) + 0], b1 = Bs[k][(tx << 2) + 1], b2 = Bs[k][(tx << 2) + 2], b3 = Bs[k][(tx << 2) + 3];
        cacc[0][0] += a0 * b0; cacc[0][1] += a0 * b1; cacc[0][2] += a0 * b2; cacc[0][3] += a0 * b3;
        cacc[1][0] += a1 * b0; cacc[1][1] += a1 * b1; cacc[1][2] += a1 * b2; cacc[1][3] += a1 * b3;
        cacc[2][0] += a2 * b0; cacc[2][1] += a2 * b1; cacc[2][2] += a2 * b2; cacc[2][3] += a2 * b3;
        cacc[3][0] += a3 * b0; cacc[3][1] += a3 * b1; cacc[3][2] += a3 * b2; cacc[3][3] += a3 * b3;
      }
      __syncthreads();
    }
#pragma unroll
    for (int j = 0; j < 4; ++j) {
      int col = m0 + (tx << 2) + j;
#pragma unroll
      for (int i = 0; i < 4; ++i) {
        float v = cacc[i][j];
        if (v > bestv[i]) { bestv[i] = v; besti[i] = col; }
      }
    }
  }
#pragma unroll
  for (int i = 0; i < 4; ++i) { rv[(ty << 2) + i][tx] = bestv[i]; ri[(ty << 2) + i][tx] = besti[i]; }
  __syncthreads();
  if (tid < 64) {
    float bv = rv[tid][0]; int bi = ri[tid][0];
#pragma unroll
    for (int t2 = 1; t2 < 16; ++t2) {
      float v = rv[tid][t2]; int ii = ri[tid][t2];
      if (v > bv || (v == bv && ii < bi)) { bv = v; bi = ii; }
    }
    wv[(b << 12) + n0 + tid] = bv;
    idxv[(b << 12) + n0 + tid] = bi;
  }
}

// ---------------- K_epi: attmap upsample (bid<1024) + gated hybrid conv (bid>=1024) ----------------
__global__ __launch_bounds__(256) void k_epi(const int* __restrict__ mark, float* __restrict__ att,
                                             const float* __restrict__ x, const float* __restrict__ mask,
                                             const float* __restrict__ partMax,
                                             const float* __restrict__ fq, const float* __restrict__ fs,
                                             const float* __restrict__ Wc, const float* __restrict__ bc,
                                             const int* __restrict__ idxv, const float* __restrict__ wv,
                                             float* __restrict__ out) {
  int bid = blockIdx.x;
  int tid = threadIdx.x;
  if (bid < 1024) {
    int id = bid * 256 + tid;
    int x8 = (id & 63) << 3;
    int y = (id >> 6) & 511;
    int b = id >> 15;
    float v = mark[((y >> 3) << 6) + (x8 >> 3)] ? 1.f : 0.f;
    float4 vv = make_float4(v, v, v, v);
    float* p = att + (((size_t)b) << 18) + (y << 9) + x8;
    *reinterpret_cast<float4*>(p) = vv;
    *reinterpret_cast<float4*>(p + 4) = vv;
    return;
  }
  // ---- gated 1x1-conv hybrid overwrite (inline valid + softmax scalars) ----
  int rr = bid - 1024;      // 0..127
  int b = rr >> 4;
  int bx = rr & 15;
  float fore = block_fore(partMax, b);
  if (!(fore > 0.5f) || mask[b << 12] == 0.f) return;  // valid==0
  __shared__ float red[256];
  float mx = -INFINITY;
  for (int n = tid; n < N_; n += 256) mx = fmaxf(mx, wv[(b << 12) + n]);
  red[tid] = mx; __syncthreads();
  for (int s = 128; s; s >>= 1) { if (tid < s) red[tid] = fmaxf(red[tid], red[tid + s]); __syncthreads(); }
  mx = red[0]; __syncthreads();
  float sm = 0.f;
  for (int n = tid; n < N_; n += 256) sm += expf(wv[(b << 12) + n] - mx);
  red[tid] = sm; __syncthreads();
  for (int s = 128; s; s >>= 1) { if (tid < s) red[tid] += red[tid + s]; __syncthreads(); }
  float den = red[0];

  int n = bx * 256 + tid;
  int bn = (b << 12) + n;
  float mn = mask[bn];
  if (mn == 0.f) return;
  int j = idxv[bn];
  float w = expf(wv[bn] - mx) / den;
  float fsj = fs[(b << 12) + j];
  float fqn = fq[bn];
  const float* xb = x + (((size_t)b * C_) << 12);
  for (int o = 0; o < C_; ++o) {
    const float* wr = Wc + o * 2 * C_;
    float a1 = 0.f, a2 = 0.f;
    for (int i = 0; i < C_; ++i) {
      a1 += wr[i] * xb[((size_t)i << 12) + j];
      a2 += wr[C_ + i] * xb[((size_t)i << 12) + n];
    }
    out[((size_t)(b * C_ + o) << 12) + n] = bc[o] + a1 * (fsj * w) + a2 * fqn;
  }
}

extern "C" void kernel_launch(void* const* d_in, const int* in_sizes, int n_in,
                              void* d_out, int out_size, void* d_ws, size_t ws_size,
                              hipStream_t stream) {
  const float* x = (const float*)d_in[0];
  const float* mask = (const float*)d_in[1];
  const float* Wc = (const float*)d_in[2];
  const float* bc = (const float*)d_in[3];
  float* out = (float*)d_out;
  float* att = out + (size_t)B_ * C_ * N_;

  float* wsf = (float*)d_ws;
  float* fq = wsf;                          // 32768
  float* fs = wsf + 32768;                  // 32768
  float* wv = wsf + 65536;                  // 32768
  int* idxv = (int*)(wsf + 98304);          // 32768 -> ends 131072
  int* rowsrc = (int*)(wsf + 131072);       // 4096
  int* rowrank = (int*)(wsf + 135168);      // 4096
  int* colsrc = (int*)(wsf + 139264);       // 4096
  int* colmapG = (int*)(wsf + 143360);      // 4096
  int* cnt = (int*)(wsf + 147456);          // 8 -> ends 147464
  int* mark = (int*)(wsf + 655392);         // 4096 -> ends 659488
  float* partMax = wsf + 659488;            // 512 -> ends 660000
  float* p7V = wsf + 660000;                // 131072 -> ends 791072
  int* p7I = (int*)(wsf + 791072);          // 131072 -> ends 922144
  unsigned short* qhi = (unsigned short*)(wsf + 922144);   // 524288 floats (2MB) each
  unsigned short* qlo = (unsigned short*)(wsf + 1446432);
  unsigned short* shi = (unsigned short*)(wsf + 1970720);
  unsigned short* slo = (unsigned short*)(wsf + 2495008);  // end: 3019296 floats (~11.5MB)

  k_base<<<dim3(64, B_ + 1), 512, 0, stream>>>(x, mask, fq, fs, out, partMax, mark,
                                               qhi, qlo, shi, slo,
                                               rowsrc, rowrank, colsrc, colmapG, cnt);
  k_sim7<<<1024, 256, 0, stream>>>(qhi, qlo, shi, slo, rowsrc, colsrc, colmapG, cnt, p7V, p7I);
  k_mid<<<464, 256, 0, stream>>>(x, mask, partMax, fq, fs, p7V, p7I, rowrank, cnt, wv, idxv, mark);
  k_epi<<<1152, 256, 0, stream>>>(mark, att, x, mask, partMax, fq, fs, Wc, bc, idxv, wv, out);
}